// Round 15
// baseline (444.826 us; speedup 1.0000x reference)
//
#include <hip/hip_runtime.h>

#define N_NODES 100000
#define N_EDGES 3200000
#define BN_EPS 1e-5f
#define SCAN_BLOCKS 391   // ceil(100000/256)
#define STATS_BLOCKS 64
#define CONV_BLOCKS 2048
#define NGROUPS (N_EDGES / 64)        // 50000
#define GSTRIDE (CONV_BLOCKS * 4)     // 8192

typedef __attribute__((ext_vector_type(8))) short short8;
typedef __attribute__((ext_vector_type(4))) float f32x4;
typedef __attribute__((ext_vector_type(4))) unsigned int uint32x4;

// workspace layout (4-byte units)
// cnt16: 16 ints per node (64B stride). word0=degree count, word1=conv1 slot ctr,
// word2=conv2 slot ctr. Padding spreads atomics across cache lines.
constexpr int O_STATS = 0;                       // 8 f
constexpr int O_CNT16 = 8;                       // N*16 int
constexpr int O_OFFS  = O_CNT16 + 16 * N_NODES;  // N int
constexpr int O_BSUM  = O_OFFS + N_NODES;        // 512 int
constexpr int O_H     = O_BSUM + 512;            // N*4 f
constexpr int O_H2    = O_H + 4 * N_NODES;       // N*2 f
constexpr int O_MSG   = O_H2 + 2 * N_NODES;      // E*4 f
constexpr int ZERO_WORDS = 8 + 16 * N_NODES;     // stats + cnt16

__device__ __forceinline__ unsigned short bf16_rne(float f) {
    unsigned u = __float_as_uint(f);
    unsigned r = (u + 0x7fff + ((u >> 16) & 1)) >> 16;
    return (unsigned short)r;
}
__device__ __forceinline__ float bf16_f32(unsigned short h) {
    return __uint_as_float(((unsigned)h) << 16);
}
__device__ __forceinline__ unsigned cvtpk_bf16(float a, float b) {
    unsigned r;
    asm("v_cvt_pk_bf16_f32 %0, %1, %2" : "=v"(r) : "v"(a), "v"(b));
    return r;
}
union PackU { uint32x4 u; short8 s; };

__global__ __launch_bounds__(256) void bn_stats_kernel(const float* __restrict__ x,
                                                       float* __restrict__ stats) {
    __shared__ float red[4][8];
    int tid = threadIdx.x;
    float s0=0.f,s1=0.f,s2=0.f,s3=0.f,q0=0.f,q1=0.f,q2=0.f,q3=0.f;
    for (int i = blockIdx.x * 256 + tid; i < N_NODES; i += STATS_BLOCKS * 256) {
        float4 v = reinterpret_cast<const float4*>(x)[i];
        s0+=v.x; s1+=v.y; s2+=v.z; s3+=v.w;
        q0=fmaf(v.x,v.x,q0); q1=fmaf(v.y,v.y,q1); q2=fmaf(v.z,v.z,q2); q3=fmaf(v.w,v.w,q3);
    }
    #pragma unroll
    for (int off = 32; off > 0; off >>= 1) {
        s0 += __shfl_down(s0, off); s1 += __shfl_down(s1, off);
        s2 += __shfl_down(s2, off); s3 += __shfl_down(s3, off);
        q0 += __shfl_down(q0, off); q1 += __shfl_down(q1, off);
        q2 += __shfl_down(q2, off); q3 += __shfl_down(q3, off);
    }
    int wave = tid >> 6, lane = tid & 63;
    if (lane == 0) {
        red[wave][0]=s0; red[wave][1]=s1; red[wave][2]=s2; red[wave][3]=s3;
        red[wave][4]=q0; red[wave][5]=q1; red[wave][6]=q2; red[wave][7]=q3;
    }
    __syncthreads();
    if (tid < 8) {
        float v = red[0][tid] + red[1][tid] + red[2][tid] + red[3][tid];
        atomicAdd(&stats[tid], v);
    }
}

__global__ void bn_apply_kernel(const float* __restrict__ x,
                                const float* __restrict__ stats,
                                const float* __restrict__ gamma,
                                const float* __restrict__ beta,
                                float* __restrict__ h) {
    int i = blockIdx.x * blockDim.x + threadIdx.x;
    if (i >= N_NODES) return;
    const float inv_n = 1.0f / (float)N_NODES;
    float m0 = stats[0]*inv_n, m1 = stats[1]*inv_n, m2 = stats[2]*inv_n, m3 = stats[3]*inv_n;
    float sc0 = rsqrtf(stats[4]*inv_n - m0*m0 + BN_EPS) * gamma[0];
    float sc1 = rsqrtf(stats[5]*inv_n - m1*m1 + BN_EPS) * gamma[1];
    float sc2 = rsqrtf(stats[6]*inv_n - m2*m2 + BN_EPS) * gamma[2];
    float sc3 = rsqrtf(stats[7]*inv_n - m3*m3 + BN_EPS) * gamma[3];
    float4 v = reinterpret_cast<const float4*>(x)[i];
    float4 o;
    o.x = (v.x - m0) * sc0 + beta[0];
    o.y = (v.y - m1) * sc1 + beta[1];
    o.z = (v.z - m2) * sc2 + beta[2];
    o.w = (v.w - m3) * sc3 + beta[3];
    reinterpret_cast<float4*>(h)[i] = o;
}

// count only (no return value) into padded word0
__global__ void count_kernel(const int* __restrict__ ei, int* __restrict__ cnt16) {
    int e = blockIdx.x * 256 + threadIdx.x;
    if (e >= N_EDGES) return;
    int d = ei[N_EDGES + e];
    atomicAdd(&cnt16[d << 4], 1);
}

__global__ void scan_block_kernel(const int* __restrict__ cnt16, int* __restrict__ offs,
                                  int* __restrict__ bsums) {
    __shared__ int sd[256];
    int t = threadIdx.x;
    int i = blockIdx.x * 256 + t;
    int v = (i < N_NODES) ? cnt16[i << 4] : 0;
    sd[t] = v; __syncthreads();
    for (int o = 1; o < 256; o <<= 1) {
        int x = (t >= o) ? sd[t - o] : 0;
        __syncthreads();
        sd[t] += x;
        __syncthreads();
    }
    if (i < N_NODES) offs[i] = sd[t] - v;
    if (t == 255) bsums[blockIdx.x] = sd[255];
}

__global__ void scan_mid_kernel(int* __restrict__ bsums) {
    __shared__ int sd[512];
    int t = threadIdx.x;
    int v = (t < SCAN_BLOCKS) ? bsums[t] : 0;
    sd[t] = v; __syncthreads();
    for (int o = 1; o < 512; o <<= 1) {
        int x = (t >= o) ? sd[t - o] : 0;
        __syncthreads();
        sd[t] += x;
        __syncthreads();
    }
    if (t < SCAN_BLOCKS) bsums[t] = sd[t] - v;
}

__global__ void scan_add_kernel(int* __restrict__ offs, const int* __restrict__ bsums) {
    int i = blockIdx.x * 256 + threadIdx.x;
    if (i < N_NODES) offs[i] += bsums[blockIdx.x];
}

// conv1: PERSISTENT waves; slot allocated in-kernel (atomic on padded word1,
// latency hidden under compute). a2 packed-bf16 LDS (17.4 KB).
__global__ __launch_bounds__(256) void conv1_mfma_kernel(
    const float* __restrict__ h,
    const int* __restrict__ ei, int* __restrict__ cnt16, const int* __restrict__ offs,
    const float* __restrict__ w1, const float* __restrict__ b1,
    const float* __restrict__ w2, const float* __restrict__ b2,
    const float* __restrict__ w3, const float* __restrict__ b3,
    float* __restrict__ msg)
{
    __shared__ unsigned a2lds[4][64 * 17];
    int tid = threadIdx.x;
    int wave = tid >> 6, lane = tid & 63;
    int kg = lane >> 4, fr = lane & 15;
    unsigned* lds = &a2lds[wave][0];
    const float4* h4 = reinterpret_cast<const float4*>(h);

    float al[4][8], be[4][8], b1v[8];
    #pragma unroll
    for (int i = 0; i < 8; i++) {
        int k = kg * 8 + i;
        #pragma unroll
        for (int c = 0; c < 4; c++) {
            float wa = w1[c * 32 + k];
            float wb = w1[(4 + c) * 32 + k];
            al[c][i] = wa - wb;
            be[c][i] = wb;
        }
        b1v[i] = b1[k];
    }
    short8 bhi0, blo0, bhi1, blo1;
    #pragma unroll
    for (int i = 0; i < 8; i++) {
        int k = kg * 8 + i;
        float w0 = w2[k * 32 + fr];
        float w1c = w2[k * 32 + fr + 16];
        unsigned short h0 = bf16_rne(w0);
        bhi0[i] = (short)h0; blo0[i] = (short)bf16_rne(w0 - bf16_f32(h0));
        unsigned short h1 = bf16_rne(w1c);
        bhi1[i] = (short)h1; blo1[i] = (short)bf16_rne(w1c - bf16_f32(h1));
    }
    float b2v0 = b2[fr], b2v1 = b2[fr + 16];

    int g = blockIdx.x * 4 + wave;
    if (g >= NGROUPS) return;

    int base = g * 64;
    int dd0, dd1, dd2, dd3, ss0, ss1, ss2, ss3;
    {
        int e0 = base + fr, e1 = base + 16 + fr, e2 = base + 32 + fr, e3 = base + 48 + fr;
        dd0 = ei[N_EDGES + e0]; dd1 = ei[N_EDGES + e1];
        dd2 = ei[N_EDGES + e2]; dd3 = ei[N_EDGES + e3];
        ss0 = ei[e0]; ss1 = ei[e1]; ss2 = ei[e2]; ss3 = ei[e3];
    }
    int dsv = kg == 0 ? dd0 : kg == 1 ? dd1 : kg == 2 ? dd2 : dd3;
    int slot = offs[dsv] + atomicAdd(&cnt16[(dsv << 4) + 1], 1);
    float4 xi0 = h4[dd0], xj0 = h4[ss0];
    float4 xi1 = h4[dd1], xj1 = h4[ss1];
    float4 xi2 = h4[dd2], xj2 = h4[ss2];
    float4 xi3 = h4[dd3], xj3 = h4[ss3];

    while (true) {
        int gn = g + GSTRIDE;
        bool hn = gn < NGROUPS;
        int basen = gn * 64;
        int nslot = 0;
        int ndd0=0,ndd1=0,ndd2=0,ndd3=0,nss0=0,nss1=0,nss2=0,nss3=0;
        if (hn) {
            int f0 = basen + fr, f1 = basen + 16 + fr, f2 = basen + 32 + fr, f3 = basen + 48 + fr;
            ndd0 = ei[N_EDGES + f0]; ndd1 = ei[N_EDGES + f1];
            ndd2 = ei[N_EDGES + f2]; ndd3 = ei[N_EDGES + f3];
            nss0 = ei[f0]; nss1 = ei[f1]; nss2 = ei[f2]; nss3 = ei[f3];
        }

        #pragma unroll
        for (int t = 0; t < 4; t++) {
            float4 xi = t == 0 ? xi0 : t == 1 ? xi1 : t == 2 ? xi2 : xi3;
            float4 xj = t == 0 ? xj0 : t == 1 ? xj1 : t == 2 ? xj2 : xj3;
            float a[8];
            #pragma unroll
            for (int i = 0; i < 8; i++) {
                float pre = b1v[i];
                pre = fmaf(al[0][i], xi.x, pre);
                pre = fmaf(al[1][i], xi.y, pre);
                pre = fmaf(al[2][i], xi.z, pre);
                pre = fmaf(al[3][i], xi.w, pre);
                pre = fmaf(be[0][i], xj.x, pre);
                pre = fmaf(be[1][i], xj.y, pre);
                pre = fmaf(be[2][i], xj.z, pre);
                pre = fmaf(be[3][i], xj.w, pre);
                a[i] = fmaxf(pre, 0.f);
            }
            PackU pu;
            #pragma unroll
            for (int j = 0; j < 4; j++) pu.u[j] = cvtpk_bf16(a[2*j], a[2*j+1]);
            short8 ahi = pu.s;

            f32x4 acc0 = {0.f, 0.f, 0.f, 0.f}, acc1 = {0.f, 0.f, 0.f, 0.f};
            acc0 = __builtin_amdgcn_mfma_f32_16x16x32_bf16(ahi, blo0, acc0, 0, 0, 0);
            acc0 = __builtin_amdgcn_mfma_f32_16x16x32_bf16(ahi, bhi0, acc0, 0, 0, 0);
            acc1 = __builtin_amdgcn_mfma_f32_16x16x32_bf16(ahi, blo1, acc1, 0, 0, 0);
            acc1 = __builtin_amdgcn_mfma_f32_16x16x32_bf16(ahi, bhi1, acc1, 0, 0, 0);
            #pragma unroll
            for (int r = 0; r < 4; r++) {
                int er = t * 16 + kg * 4 + r;
                float a20 = fmaxf(acc0[r] + b2v0, 0.f);
                float a21 = fmaxf(acc1[r] + b2v1, 0.f);
                lds[er * 17 + fr] = cvtpk_bf16(a20, a21);
            }
        }

        if (hn) {
            xi0 = h4[ndd0]; xj0 = h4[nss0];
            xi1 = h4[ndd1]; xj1 = h4[nss1];
            xi2 = h4[ndd2]; xj2 = h4[nss2];
            xi3 = h4[ndd3]; xj3 = h4[nss3];
            int ndsv = kg == 0 ? ndd0 : kg == 1 ? ndd1 : kg == 2 ? ndd2 : ndd3;
            nslot = offs[ndsv] + atomicAdd(&cnt16[(ndsv << 4) + 1], 1);
        }

        asm volatile("s_waitcnt lgkmcnt(0)" ::: "memory");

        float m0 = b3[0], m1 = b3[1];
        #pragma unroll
        for (int j = 0; j < 16; j++) {
            unsigned u = lds[lane * 17 + j];
            float flo = __uint_as_float(u << 16);
            float fhi = __uint_as_float(u & 0xffff0000u);
            m0 = fmaf(flo, w3[2 * j],        m0);
            m1 = fmaf(flo, w3[2 * j + 1],    m1);
            m0 = fmaf(fhi, w3[2 * (j + 16)],     m0);
            m1 = fmaf(fhi, w3[2 * (j + 16) + 1], m1);
        }
        m0 = fmaxf(m0, 0.f); m1 = fmaxf(m1, 0.f);
        reinterpret_cast<float2*>(msg)[slot] = make_float2(m0, m1);

        if (!hn) break;
        slot = nslot; g = gn;
    }
}

__global__ void agg1_kernel(const float* __restrict__ msg, const int* __restrict__ offs,
                            const int* __restrict__ cnt16, float* __restrict__ h2) {
    int lane = threadIdx.x & 63;
    int wave = threadIdx.x >> 6;
    int node = blockIdx.x * 8 + wave * 2 + (lane >> 5);
    int sub = lane & 31;
    if (node >= N_NODES) return;
    int base = offs[node];
    int deg  = cnt16[node << 4];
    float s0 = 0.f, s1 = 0.f;
    for (int k = sub; k < deg; k += 32) {
        float2 m = reinterpret_cast<const float2*>(msg)[base + k];
        s0 += m.x; s1 += m.y;
    }
    #pragma unroll
    for (int o = 16; o > 0; o >>= 1) {
        s0 += __shfl_down(s0, o, 32);
        s1 += __shfl_down(s1, o, 32);
    }
    if (sub == 0) {
        float c = fmaxf((float)deg, 1.f);
        reinterpret_cast<float2*>(h2)[node] = make_float2(s0 / c, s1 / c);
    }
}

// conv2: persistent, slot via padded word2; f32 LDS epilogue; A full hi/lo split.
__global__ __launch_bounds__(256) void conv2_mfma_kernel(
    const float* __restrict__ h2,
    const int* __restrict__ ei, int* __restrict__ cnt16, const int* __restrict__ offs,
    const float* __restrict__ w1, const float* __restrict__ b1,
    const float* __restrict__ w2, const float* __restrict__ b2,
    const float* __restrict__ w3, const float* __restrict__ b3,
    float* __restrict__ msg)
{
    __shared__ float a2lds[4][64 * 33];
    int tid = threadIdx.x;
    int wave = tid >> 6, lane = tid & 63;
    int kg = lane >> 4, fr = lane & 15;
    float* lds = &a2lds[wave][0];
    const float2* h2v = reinterpret_cast<const float2*>(h2);

    float al0[8], al1[8], be0[8], be1[8], b1v[8];
    #pragma unroll
    for (int i = 0; i < 8; i++) {
        int k = kg * 8 + i;
        float c0a = w1[k], c1a = w1[32 + k];
        float c0b = w1[64 + k], c1b = w1[96 + k];
        al0[i] = c0a - c0b; al1[i] = c1a - c1b;
        be0[i] = c0b; be1[i] = c1b;
        b1v[i] = b1[k];
    }
    short8 bhi0, blo0, bhi1, blo1;
    #pragma unroll
    for (int i = 0; i < 8; i++) {
        int k = kg * 8 + i;
        float w0 = w2[k * 32 + fr];
        float w1c = w2[k * 32 + fr + 16];
        unsigned short h0 = bf16_rne(w0);
        bhi0[i] = (short)h0; blo0[i] = (short)bf16_rne(w0 - bf16_f32(h0));
        unsigned short h1 = bf16_rne(w1c);
        bhi1[i] = (short)h1; blo1[i] = (short)bf16_rne(w1c - bf16_f32(h1));
    }
    float b2v0 = b2[fr], b2v1 = b2[fr + 16];

    int g = blockIdx.x * 4 + wave;
    if (g >= NGROUPS) return;
    int base = g * 64;
    int dd0, dd1, dd2, dd3, ss0, ss1, ss2, ss3;
    {
        int e0 = base + fr, e1 = base + 16 + fr, e2 = base + 32 + fr, e3 = base + 48 + fr;
        dd0 = ei[N_EDGES + e0]; dd1 = ei[N_EDGES + e1];
        dd2 = ei[N_EDGES + e2]; dd3 = ei[N_EDGES + e3];
        ss0 = ei[e0]; ss1 = ei[e1]; ss2 = ei[e2]; ss3 = ei[e3];
    }
    int dsv = kg == 0 ? dd0 : kg == 1 ? dd1 : kg == 2 ? dd2 : dd3;
    int slot = offs[dsv] + atomicAdd(&cnt16[(dsv << 4) + 2], 1);
    float2 yd0 = h2v[dd0], ys0 = h2v[ss0];
    float2 yd1 = h2v[dd1], ys1 = h2v[ss1];
    float2 yd2 = h2v[dd2], ys2 = h2v[ss2];
    float2 yd3 = h2v[dd3], ys3 = h2v[ss3];

    while (true) {
        int gn = g + GSTRIDE;
        bool hn = gn < NGROUPS;
        int basen = gn * 64;
        int nslot = 0;
        int ndd0=0,ndd1=0,ndd2=0,ndd3=0,nss0=0,nss1=0,nss2=0,nss3=0;
        if (hn) {
            int f0 = basen + fr, f1 = basen + 16 + fr, f2 = basen + 32 + fr, f3 = basen + 48 + fr;
            ndd0 = ei[N_EDGES + f0]; ndd1 = ei[N_EDGES + f1];
            ndd2 = ei[N_EDGES + f2]; ndd3 = ei[N_EDGES + f3];
            nss0 = ei[f0]; nss1 = ei[f1]; nss2 = ei[f2]; nss3 = ei[f3];
        }

        #pragma unroll
        for (int t = 0; t < 4; t++) {
            float2 yd = t == 0 ? yd0 : t == 1 ? yd1 : t == 2 ? yd2 : yd3;
            float2 ys = t == 0 ? ys0 : t == 1 ? ys1 : t == 2 ? ys2 : ys3;
            float a[8];
            #pragma unroll
            for (int i = 0; i < 8; i++) {
                float pre = b1v[i];
                pre = fmaf(al0[i], yd.x, pre);
                pre = fmaf(al1[i], yd.y, pre);
                pre = fmaf(be0[i], ys.x, pre);
                pre = fmaf(be1[i], ys.y, pre);
                a[i] = fmaxf(pre, 0.f);
            }
            PackU ph, pl;
            #pragma unroll
            for (int j = 0; j < 4; j++) ph.u[j] = cvtpk_bf16(a[2*j], a[2*j+1]);
            #pragma unroll
            for (int j = 0; j < 4; j++) {
                float hlo = __uint_as_float(ph.u[j] << 16);
                float hhi = __uint_as_float(ph.u[j] & 0xffff0000u);
                pl.u[j] = cvtpk_bf16(a[2*j] - hlo, a[2*j+1] - hhi);
            }
            short8 ahi = ph.s, alo = pl.s;

            f32x4 acc0 = {0.f, 0.f, 0.f, 0.f}, acc1 = {0.f, 0.f, 0.f, 0.f};
            acc0 = __builtin_amdgcn_mfma_f32_16x16x32_bf16(alo, bhi0, acc0, 0, 0, 0);
            acc0 = __builtin_amdgcn_mfma_f32_16x16x32_bf16(ahi, blo0, acc0, 0, 0, 0);
            acc0 = __builtin_amdgcn_mfma_f32_16x16x32_bf16(ahi, bhi0, acc0, 0, 0, 0);
            acc1 = __builtin_amdgcn_mfma_f32_16x16x32_bf16(alo, bhi1, acc1, 0, 0, 0);
            acc1 = __builtin_amdgcn_mfma_f32_16x16x32_bf16(ahi, blo1, acc1, 0, 0, 0);
            acc1 = __builtin_amdgcn_mfma_f32_16x16x32_bf16(ahi, bhi1, acc1, 0, 0, 0);
            #pragma unroll
            for (int r = 0; r < 4; r++) {
                int er = t * 16 + kg * 4 + r;
                lds[er * 33 + fr]      = fmaxf(acc0[r] + b2v0, 0.f);
                lds[er * 33 + fr + 16] = fmaxf(acc1[r] + b2v1, 0.f);
            }
        }

        if (hn) {
            yd0 = h2v[ndd0]; ys0 = h2v[nss0];
            yd1 = h2v[ndd1]; ys1 = h2v[nss1];
            yd2 = h2v[ndd2]; ys2 = h2v[nss2];
            yd3 = h2v[ndd3]; ys3 = h2v[nss3];
            int ndsv = kg == 0 ? ndd0 : kg == 1 ? ndd1 : kg == 2 ? ndd2 : ndd3;
            nslot = offs[ndsv] + atomicAdd(&cnt16[(ndsv << 4) + 2], 1);
        }

        asm volatile("s_waitcnt lgkmcnt(0)" ::: "memory");

        float o0 = b3[0], o1 = b3[1], o2 = b3[2], o3 = b3[3];
        #pragma unroll
        for (int j = 0; j < 32; j++) {
            float aj = lds[lane * 33 + j];
            o0 = fmaf(aj, w3[4 * j],     o0);
            o1 = fmaf(aj, w3[4 * j + 1], o1);
            o2 = fmaf(aj, w3[4 * j + 2], o2);
            o3 = fmaf(aj, w3[4 * j + 3], o3);
        }
        reinterpret_cast<float4*>(msg)[slot] = make_float4(o0, o1, o2, o3);

        if (!hn) break;
        slot = nslot; g = gn;
    }
}

__global__ void agg2_kernel(const float* __restrict__ msg, const int* __restrict__ offs,
                            const int* __restrict__ cnt16, float* __restrict__ out) {
    int lane = threadIdx.x & 63;
    int wave = threadIdx.x >> 6;
    int node = blockIdx.x * 8 + wave * 2 + (lane >> 5);
    int sub = lane & 31;
    if (node >= N_NODES) return;
    int base = offs[node];
    int deg  = cnt16[node << 4];
    float s0 = 0.f, s1 = 0.f, s2 = 0.f, s3 = 0.f;
    for (int k = sub; k < deg; k += 32) {
        float4 m = reinterpret_cast<const float4*>(msg)[base + k];
        s0 += m.x; s1 += m.y; s2 += m.z; s3 += m.w;
    }
    #pragma unroll
    for (int o = 16; o > 0; o >>= 1) {
        s0 += __shfl_down(s0, o, 32); s1 += __shfl_down(s1, o, 32);
        s2 += __shfl_down(s2, o, 32); s3 += __shfl_down(s3, o, 32);
    }
    if (sub == 0) {
        float c = fmaxf((float)deg, 1.f);
        reinterpret_cast<float4*>(out)[node] = make_float4(s0/c, s1/c, s2/c, s3/c);
    }
}

extern "C" void kernel_launch(void* const* d_in, const int* in_sizes, int n_in,
                              void* d_out, int out_size, void* d_ws, size_t ws_size,
                              hipStream_t stream) {
    const float* x        = (const float*)d_in[0];
    const int*   ei       = (const int*)  d_in[1];
    const float* bn_gamma = (const float*)d_in[2];
    const float* bn_beta  = (const float*)d_in[3];
    const float* enc_w1   = (const float*)d_in[4];
    const float* enc_b1   = (const float*)d_in[5];
    const float* enc_w2   = (const float*)d_in[6];
    const float* enc_b2   = (const float*)d_in[7];
    const float* enc_w3   = (const float*)d_in[8];
    const float* enc_b3   = (const float*)d_in[9];
    const float* dec_w1   = (const float*)d_in[10];
    const float* dec_b1   = (const float*)d_in[11];
    const float* dec_w2   = (const float*)d_in[12];
    const float* dec_b2   = (const float*)d_in[13];
    const float* dec_w3   = (const float*)d_in[14];
    const float* dec_b3   = (const float*)d_in[15];

    float* wsf   = (float*)d_ws;
    int*   wsi   = (int*)d_ws;
    float* stats = wsf + O_STATS;
    int*   cnt16 = wsi + O_CNT16;
    int*   offs  = wsi + O_OFFS;
    int*   bsums = wsi + O_BSUM;
    float* h     = wsf + O_H;
    float* h2    = wsf + O_H2;
    float* msg   = wsf + O_MSG;
    float* out   = (float*)d_out;

    hipMemsetAsync(d_ws, 0, (size_t)ZERO_WORDS * sizeof(float), stream);

    const int nodeBlocks = (N_NODES + 255) / 256;
    const int edgeBlocks = (N_EDGES + 255) / 256;
    const int aggBlocks  = (N_NODES + 7) / 8;

    bn_stats_kernel<<<STATS_BLOCKS, 256, 0, stream>>>(x, stats);
    bn_apply_kernel<<<nodeBlocks, 256, 0, stream>>>(x, stats, bn_gamma, bn_beta, h);
    count_kernel<<<edgeBlocks, 256, 0, stream>>>(ei, cnt16);
    scan_block_kernel<<<SCAN_BLOCKS, 256, 0, stream>>>(cnt16, offs, bsums);
    scan_mid_kernel<<<1, 512, 0, stream>>>(bsums);
    scan_add_kernel<<<SCAN_BLOCKS, 256, 0, stream>>>(offs, bsums);
    conv1_mfma_kernel<<<CONV_BLOCKS, 256, 0, stream>>>(h, ei, cnt16, offs,
                                                       enc_w1, enc_b1, enc_w2, enc_b2,
                                                       enc_w3, enc_b3, msg);
    agg1_kernel<<<aggBlocks, 256, 0, stream>>>(msg, offs, cnt16, h2);
    conv2_mfma_kernel<<<CONV_BLOCKS, 256, 0, stream>>>(h2, ei, cnt16, offs,
                                                       dec_w1, dec_b1, dec_w2, dec_b2,
                                                       dec_w3, dec_b3, msg);
    agg2_kernel<<<aggBlocks, 256, 0, stream>>>(msg, offs, cnt16, out);
}

// Round 16
// 306.043 us; speedup vs baseline: 1.4535x; 1.4535x over previous
//
#include <hip/hip_runtime.h>

#define N_NODES 100000
#define N_EDGES 3200000
#define BN_EPS 1e-5f
#define STATS_BLOCKS 64
#define CONV_BLOCKS 2048
#define NGROUPS (N_EDGES / 64)        // 50000
#define GSTRIDE (CONV_BLOCKS * 4)     // 8192
#define NBKT 196                      // ceil(100000/512)
#define SCAT_BLOCKS 1024
#define EDGES_PER_SCAT (N_EDGES / SCAT_BLOCKS)   // 3125

typedef __attribute__((ext_vector_type(8))) short short8;
typedef __attribute__((ext_vector_type(4))) float f32x4;
typedef __attribute__((ext_vector_type(4))) unsigned int uint32x4;

// workspace layout (4-byte units)
constexpr int O_STATS   = 0;                        // 8 f
constexpr int O_BKTCNT  = 8;                        // 256 int (zeroed)
constexpr int O_BKTCTR  = 264;                      // 256 int (zeroed)
constexpr int O_BKTBASE = 520;                      // 256 int (written by scan)
constexpr int O_CNT     = 776;                      // N int (written by fine_rank)
constexpr int O_OFFS    = O_CNT + N_NODES;          // N int (written by fine_rank)
constexpr int O_POS     = O_OFFS + N_NODES;         // E int
constexpr int O_SBK     = O_POS + N_EDGES;          // 2E int (int2 pairs)
constexpr int O_H       = O_SBK + 2 * N_EDGES;      // 4N f
constexpr int O_H2      = O_H + 4 * N_NODES;        // 2N f
constexpr int O_MSG     = O_H2 + 2 * N_NODES;       // 4E f
constexpr int ZERO_WORDS = 520;                     // stats + bktcnt + bktctr

__device__ __forceinline__ unsigned short bf16_rne(float f) {
    unsigned u = __float_as_uint(f);
    unsigned r = (u + 0x7fff + ((u >> 16) & 1)) >> 16;
    return (unsigned short)r;
}
__device__ __forceinline__ float bf16_f32(unsigned short h) {
    return __uint_as_float(((unsigned)h) << 16);
}
__device__ __forceinline__ unsigned cvtpk_bf16(float a, float b) {
    unsigned r;
    asm("v_cvt_pk_bf16_f32 %0, %1, %2" : "=v"(r) : "v"(a), "v"(b));
    return r;
}
union PackU { uint32x4 u; short8 s; };

__global__ __launch_bounds__(256) void bn_stats_kernel(const float* __restrict__ x,
                                                       float* __restrict__ stats) {
    __shared__ float red[4][8];
    int tid = threadIdx.x;
    float s0=0.f,s1=0.f,s2=0.f,s3=0.f,q0=0.f,q1=0.f,q2=0.f,q3=0.f;
    for (int i = blockIdx.x * 256 + tid; i < N_NODES; i += STATS_BLOCKS * 256) {
        float4 v = reinterpret_cast<const float4*>(x)[i];
        s0+=v.x; s1+=v.y; s2+=v.z; s3+=v.w;
        q0=fmaf(v.x,v.x,q0); q1=fmaf(v.y,v.y,q1); q2=fmaf(v.z,v.z,q2); q3=fmaf(v.w,v.w,q3);
    }
    #pragma unroll
    for (int off = 32; off > 0; off >>= 1) {
        s0 += __shfl_down(s0, off); s1 += __shfl_down(s1, off);
        s2 += __shfl_down(s2, off); s3 += __shfl_down(s3, off);
        q0 += __shfl_down(q0, off); q1 += __shfl_down(q1, off);
        q2 += __shfl_down(q2, off); q3 += __shfl_down(q3, off);
    }
    int wave = tid >> 6, lane = tid & 63;
    if (lane == 0) {
        red[wave][0]=s0; red[wave][1]=s1; red[wave][2]=s2; red[wave][3]=s3;
        red[wave][4]=q0; red[wave][5]=q1; red[wave][6]=q2; red[wave][7]=q3;
    }
    __syncthreads();
    if (tid < 8) {
        float v = red[0][tid] + red[1][tid] + red[2][tid] + red[3][tid];
        atomicAdd(&stats[tid], v);
    }
}

__global__ void bn_apply_kernel(const float* __restrict__ x,
                                const float* __restrict__ stats,
                                const float* __restrict__ gamma,
                                const float* __restrict__ beta,
                                float* __restrict__ h) {
    int i = blockIdx.x * blockDim.x + threadIdx.x;
    if (i >= N_NODES) return;
    const float inv_n = 1.0f / (float)N_NODES;
    float m0 = stats[0]*inv_n, m1 = stats[1]*inv_n, m2 = stats[2]*inv_n, m3 = stats[3]*inv_n;
    float sc0 = rsqrtf(stats[4]*inv_n - m0*m0 + BN_EPS) * gamma[0];
    float sc1 = rsqrtf(stats[5]*inv_n - m1*m1 + BN_EPS) * gamma[1];
    float sc2 = rsqrtf(stats[6]*inv_n - m2*m2 + BN_EPS) * gamma[2];
    float sc3 = rsqrtf(stats[7]*inv_n - m3*m3 + BN_EPS) * gamma[3];
    float4 v = reinterpret_cast<const float4*>(x)[i];
    float4 o;
    o.x = (v.x - m0) * sc0 + beta[0];
    o.y = (v.y - m1) * sc1 + beta[1];
    o.z = (v.z - m2) * sc2 + beta[2];
    o.w = (v.w - m3) * sc3 + beta[3];
    reinterpret_cast<float4*>(h)[i] = o;
}

// coarse bucket histogram: LDS per-block, ~256 global adds per block
__global__ __launch_bounds__(256) void bucket_count_kernel(const int* __restrict__ ei,
                                                           int* __restrict__ bktcnt) {
    __shared__ int lh[256];
    int t = threadIdx.x;
    lh[t] = 0;
    __syncthreads();
    for (int e = blockIdx.x * 256 + t; e < N_EDGES; e += SCAT_BLOCKS * 256) {
        int d = ei[N_EDGES + e];
        atomicAdd(&lh[d >> 9], 1);
    }
    __syncthreads();
    int v = lh[t];
    if (v) atomicAdd(&bktcnt[t], v);
}

__global__ void bucket_scan_kernel(const int* __restrict__ bktcnt, int* __restrict__ bktbase) {
    __shared__ int sd[256];
    int t = threadIdx.x;
    int v = bktcnt[t];
    sd[t] = v; __syncthreads();
    for (int o = 1; o < 256; o <<= 1) {
        int x = (t >= o) ? sd[t - o] : 0;
        __syncthreads();
        sd[t] += x;
        __syncthreads();
    }
    bktbase[t] = sd[t] - v;
}

// partition edges into coarse-bucket-contiguous (dst, edge_id) pairs.
// One global atomic per (block,bucket); per-edge placement via LDS atomics.
__global__ __launch_bounds__(256) void scatter_kernel(const int* __restrict__ ei,
                                                      const int* __restrict__ bktbase,
                                                      int* __restrict__ bktctr,
                                                      int2* __restrict__ sbk) {
    __shared__ int lh[256], lbase[256], lctr[256];
    int t = threadIdx.x;
    lh[t] = 0; lctr[t] = 0;
    __syncthreads();
    int start = blockIdx.x * EDGES_PER_SCAT;
    int end = start + EDGES_PER_SCAT;
    for (int e = start + t; e < end; e += 256) {
        int d = ei[N_EDGES + e];
        atomicAdd(&lh[d >> 9], 1);
    }
    __syncthreads();
    int v = lh[t];
    if (v) lbase[t] = bktbase[t] + atomicAdd(&bktctr[t], v);
    __syncthreads();
    for (int e = start + t; e < end; e += 256) {
        int d = ei[N_EDGES + e];
        int b = d >> 9;
        int r = atomicAdd(&lctr[b], 1);
        sbk[lbase[b] + r] = make_int2(d, e);
    }
}

// per-bucket fine ranking: LDS histogram over 512 local nodes + LDS scan +
// LDS-atomic ranks. Writes pos[e], offs[node], cnt[node]. Zero global atomics.
__global__ __launch_bounds__(512) void fine_rank_kernel(const int2* __restrict__ sbk,
                                                        const int* __restrict__ bktbase,
                                                        const int* __restrict__ bktcnt,
                                                        int* __restrict__ pos,
                                                        int* __restrict__ offs,
                                                        int* __restrict__ cnt) {
    __shared__ int hist[512], scanv[512], ctr[512];
    int b = blockIdx.x;
    int t = threadIdx.x;
    int ebase = bktbase[b];
    int ecount = bktcnt[b];
    hist[t] = 0; ctr[t] = 0;
    __syncthreads();
    for (int i = t; i < ecount; i += 512) {
        int d = sbk[ebase + i].x;
        atomicAdd(&hist[d & 511], 1);
    }
    __syncthreads();
    int v = hist[t];
    scanv[t] = v;
    __syncthreads();
    for (int o = 1; o < 512; o <<= 1) {
        int x = (t >= o) ? scanv[t - o] : 0;
        __syncthreads();
        scanv[t] += x;
        __syncthreads();
    }
    int excl = scanv[t] - v;
    int node = (b << 9) + t;
    if (node < N_NODES) {
        offs[node] = ebase + excl;
        cnt[node]  = v;
    }
    __syncthreads();
    hist[t] = excl;        // reuse as per-node exclusive base
    __syncthreads();
    for (int i = t; i < ecount; i += 512) {
        int2 de = sbk[ebase + i];
        int ld = de.x & 511;
        int r = atomicAdd(&ctr[ld], 1);
        pos[de.y] = ebase + hist[ld] + r;
    }
}

// conv1: PERSISTENT waves; slot = pos[e] (single load, no atomics).
// a2 packed-bf16 LDS (17.4 KB). A bf16-hi only (error averaged by agg1 mean).
__global__ __launch_bounds__(256) void conv1_mfma_kernel(
    const float* __restrict__ h,
    const int* __restrict__ ei, const int* __restrict__ pos,
    const float* __restrict__ w1, const float* __restrict__ b1,
    const float* __restrict__ w2, const float* __restrict__ b2,
    const float* __restrict__ w3, const float* __restrict__ b3,
    float* __restrict__ msg)
{
    __shared__ unsigned a2lds[4][64 * 17];
    int tid = threadIdx.x;
    int wave = tid >> 6, lane = tid & 63;
    int kg = lane >> 4, fr = lane & 15;
    unsigned* lds = &a2lds[wave][0];
    const float4* h4 = reinterpret_cast<const float4*>(h);

    float al[4][8], be[4][8], b1v[8];
    #pragma unroll
    for (int i = 0; i < 8; i++) {
        int k = kg * 8 + i;
        #pragma unroll
        for (int c = 0; c < 4; c++) {
            float wa = w1[c * 32 + k];
            float wb = w1[(4 + c) * 32 + k];
            al[c][i] = wa - wb;
            be[c][i] = wb;
        }
        b1v[i] = b1[k];
    }
    short8 bhi0, blo0, bhi1, blo1;
    #pragma unroll
    for (int i = 0; i < 8; i++) {
        int k = kg * 8 + i;
        float w0 = w2[k * 32 + fr];
        float w1c = w2[k * 32 + fr + 16];
        unsigned short h0 = bf16_rne(w0);
        bhi0[i] = (short)h0; blo0[i] = (short)bf16_rne(w0 - bf16_f32(h0));
        unsigned short h1 = bf16_rne(w1c);
        bhi1[i] = (short)h1; blo1[i] = (short)bf16_rne(w1c - bf16_f32(h1));
    }
    float b2v0 = b2[fr], b2v1 = b2[fr + 16];

    int g = blockIdx.x * 4 + wave;
    if (g >= NGROUPS) return;

    int base = g * 64;
    int dd0, dd1, dd2, dd3, ss0, ss1, ss2, ss3;
    {
        int e0 = base + fr, e1 = base + 16 + fr, e2 = base + 32 + fr, e3 = base + 48 + fr;
        dd0 = ei[N_EDGES + e0]; dd1 = ei[N_EDGES + e1];
        dd2 = ei[N_EDGES + e2]; dd3 = ei[N_EDGES + e3];
        ss0 = ei[e0]; ss1 = ei[e1]; ss2 = ei[e2]; ss3 = ei[e3];
    }
    int slot = pos[base + lane];
    float4 xi0 = h4[dd0], xj0 = h4[ss0];
    float4 xi1 = h4[dd1], xj1 = h4[ss1];
    float4 xi2 = h4[dd2], xj2 = h4[ss2];
    float4 xi3 = h4[dd3], xj3 = h4[ss3];

    while (true) {
        int gn = g + GSTRIDE;
        bool hn = gn < NGROUPS;
        int basen = gn * 64;
        int nslot = 0;
        int ndd0=0,ndd1=0,ndd2=0,ndd3=0,nss0=0,nss1=0,nss2=0,nss3=0;
        if (hn) {
            int f0 = basen + fr, f1 = basen + 16 + fr, f2 = basen + 32 + fr, f3 = basen + 48 + fr;
            ndd0 = ei[N_EDGES + f0]; ndd1 = ei[N_EDGES + f1];
            ndd2 = ei[N_EDGES + f2]; ndd3 = ei[N_EDGES + f3];
            nss0 = ei[f0]; nss1 = ei[f1]; nss2 = ei[f2]; nss3 = ei[f3];
            nslot = pos[basen + lane];
        }

        #pragma unroll
        for (int t = 0; t < 4; t++) {
            float4 xi = t == 0 ? xi0 : t == 1 ? xi1 : t == 2 ? xi2 : xi3;
            float4 xj = t == 0 ? xj0 : t == 1 ? xj1 : t == 2 ? xj2 : xj3;
            float a[8];
            #pragma unroll
            for (int i = 0; i < 8; i++) {
                float pre = b1v[i];
                pre = fmaf(al[0][i], xi.x, pre);
                pre = fmaf(al[1][i], xi.y, pre);
                pre = fmaf(al[2][i], xi.z, pre);
                pre = fmaf(al[3][i], xi.w, pre);
                pre = fmaf(be[0][i], xj.x, pre);
                pre = fmaf(be[1][i], xj.y, pre);
                pre = fmaf(be[2][i], xj.z, pre);
                pre = fmaf(be[3][i], xj.w, pre);
                a[i] = fmaxf(pre, 0.f);
            }
            PackU pu;
            #pragma unroll
            for (int j = 0; j < 4; j++) pu.u[j] = cvtpk_bf16(a[2*j], a[2*j+1]);
            short8 ahi = pu.s;

            f32x4 acc0 = {0.f, 0.f, 0.f, 0.f}, acc1 = {0.f, 0.f, 0.f, 0.f};
            acc0 = __builtin_amdgcn_mfma_f32_16x16x32_bf16(ahi, blo0, acc0, 0, 0, 0);
            acc0 = __builtin_amdgcn_mfma_f32_16x16x32_bf16(ahi, bhi0, acc0, 0, 0, 0);
            acc1 = __builtin_amdgcn_mfma_f32_16x16x32_bf16(ahi, blo1, acc1, 0, 0, 0);
            acc1 = __builtin_amdgcn_mfma_f32_16x16x32_bf16(ahi, bhi1, acc1, 0, 0, 0);
            #pragma unroll
            for (int r = 0; r < 4; r++) {
                int er = t * 16 + kg * 4 + r;
                float a20 = fmaxf(acc0[r] + b2v0, 0.f);
                float a21 = fmaxf(acc1[r] + b2v1, 0.f);
                lds[er * 17 + fr] = cvtpk_bf16(a20, a21);
            }
        }

        if (hn) {
            xi0 = h4[ndd0]; xj0 = h4[nss0];
            xi1 = h4[ndd1]; xj1 = h4[nss1];
            xi2 = h4[ndd2]; xj2 = h4[nss2];
            xi3 = h4[ndd3]; xj3 = h4[nss3];
        }

        asm volatile("s_waitcnt lgkmcnt(0)" ::: "memory");

        float m0 = b3[0], m1 = b3[1];
        #pragma unroll
        for (int j = 0; j < 16; j++) {
            unsigned u = lds[lane * 17 + j];
            float flo = __uint_as_float(u << 16);
            float fhi = __uint_as_float(u & 0xffff0000u);
            m0 = fmaf(flo, w3[2 * j],        m0);
            m1 = fmaf(flo, w3[2 * j + 1],    m1);
            m0 = fmaf(fhi, w3[2 * (j + 16)],     m0);
            m1 = fmaf(fhi, w3[2 * (j + 16) + 1], m1);
        }
        m0 = fmaxf(m0, 0.f); m1 = fmaxf(m1, 0.f);
        reinterpret_cast<float2*>(msg)[slot] = make_float2(m0, m1);

        if (!hn) break;
        slot = nslot; g = gn;
    }
}

__global__ void agg1_kernel(const float* __restrict__ msg, const int* __restrict__ offs,
                            const int* __restrict__ cnt, float* __restrict__ h2) {
    int lane = threadIdx.x & 63;
    int wave = threadIdx.x >> 6;
    int node = blockIdx.x * 8 + wave * 2 + (lane >> 5);
    int sub = lane & 31;
    if (node >= N_NODES) return;
    int base = offs[node];
    int deg  = cnt[node];
    float s0 = 0.f, s1 = 0.f;
    for (int k = sub; k < deg; k += 32) {
        float2 m = reinterpret_cast<const float2*>(msg)[base + k];
        s0 += m.x; s1 += m.y;
    }
    #pragma unroll
    for (int o = 16; o > 0; o >>= 1) {
        s0 += __shfl_down(s0, o, 32);
        s1 += __shfl_down(s1, o, 32);
    }
    if (sub == 0) {
        float c = fmaxf((float)deg, 1.f);
        reinterpret_cast<float2*>(h2)[node] = make_float2(s0 / c, s1 / c);
    }
}

// conv2: persistent; slot = pos[e]; f32 LDS epilogue; A full hi/lo split.
__global__ __launch_bounds__(256) void conv2_mfma_kernel(
    const float* __restrict__ h2,
    const int* __restrict__ ei, const int* __restrict__ pos,
    const float* __restrict__ w1, const float* __restrict__ b1,
    const float* __restrict__ w2, const float* __restrict__ b2,
    const float* __restrict__ w3, const float* __restrict__ b3,
    float* __restrict__ msg)
{
    __shared__ float a2lds[4][64 * 33];
    int tid = threadIdx.x;
    int wave = tid >> 6, lane = tid & 63;
    int kg = lane >> 4, fr = lane & 15;
    float* lds = &a2lds[wave][0];
    const float2* h2v = reinterpret_cast<const float2*>(h2);

    float al0[8], al1[8], be0[8], be1[8], b1v[8];
    #pragma unroll
    for (int i = 0; i < 8; i++) {
        int k = kg * 8 + i;
        float c0a = w1[k], c1a = w1[32 + k];
        float c0b = w1[64 + k], c1b = w1[96 + k];
        al0[i] = c0a - c0b; al1[i] = c1a - c1b;
        be0[i] = c0b; be1[i] = c1b;
        b1v[i] = b1[k];
    }
    short8 bhi0, blo0, bhi1, blo1;
    #pragma unroll
    for (int i = 0; i < 8; i++) {
        int k = kg * 8 + i;
        float w0 = w2[k * 32 + fr];
        float w1c = w2[k * 32 + fr + 16];
        unsigned short h0 = bf16_rne(w0);
        bhi0[i] = (short)h0; blo0[i] = (short)bf16_rne(w0 - bf16_f32(h0));
        unsigned short h1 = bf16_rne(w1c);
        bhi1[i] = (short)h1; blo1[i] = (short)bf16_rne(w1c - bf16_f32(h1));
    }
    float b2v0 = b2[fr], b2v1 = b2[fr + 16];

    int g = blockIdx.x * 4 + wave;
    if (g >= NGROUPS) return;
    int base = g * 64;
    int dd0, dd1, dd2, dd3, ss0, ss1, ss2, ss3;
    {
        int e0 = base + fr, e1 = base + 16 + fr, e2 = base + 32 + fr, e3 = base + 48 + fr;
        dd0 = ei[N_EDGES + e0]; dd1 = ei[N_EDGES + e1];
        dd2 = ei[N_EDGES + e2]; dd3 = ei[N_EDGES + e3];
        ss0 = ei[e0]; ss1 = ei[e1]; ss2 = ei[e2]; ss3 = ei[e3];
    }
    int slot = pos[base + lane];
    float2 yd0 = h2v[dd0], ys0 = h2v[ss0];
    float2 yd1 = h2v[dd1], ys1 = h2v[ss1];
    float2 yd2 = h2v[dd2], ys2 = h2v[ss2];
    float2 yd3 = h2v[dd3], ys3 = h2v[ss3];

    while (true) {
        int gn = g + GSTRIDE;
        bool hn = gn < NGROUPS;
        int basen = gn * 64;
        int nslot = 0;
        int ndd0=0,ndd1=0,ndd2=0,ndd3=0,nss0=0,nss1=0,nss2=0,nss3=0;
        if (hn) {
            int f0 = basen + fr, f1 = basen + 16 + fr, f2 = basen + 32 + fr, f3 = basen + 48 + fr;
            ndd0 = ei[N_EDGES + f0]; ndd1 = ei[N_EDGES + f1];
            ndd2 = ei[N_EDGES + f2]; ndd3 = ei[N_EDGES + f3];
            nss0 = ei[f0]; nss1 = ei[f1]; nss2 = ei[f2]; nss3 = ei[f3];
            nslot = pos[basen + lane];
        }

        #pragma unroll
        for (int t = 0; t < 4; t++) {
            float2 yd = t == 0 ? yd0 : t == 1 ? yd1 : t == 2 ? yd2 : yd3;
            float2 ys = t == 0 ? ys0 : t == 1 ? ys1 : t == 2 ? ys2 : ys3;
            float a[8];
            #pragma unroll
            for (int i = 0; i < 8; i++) {
                float pre = b1v[i];
                pre = fmaf(al0[i], yd.x, pre);
                pre = fmaf(al1[i], yd.y, pre);
                pre = fmaf(be0[i], ys.x, pre);
                pre = fmaf(be1[i], ys.y, pre);
                a[i] = fmaxf(pre, 0.f);
            }
            PackU ph, pl;
            #pragma unroll
            for (int j = 0; j < 4; j++) ph.u[j] = cvtpk_bf16(a[2*j], a[2*j+1]);
            #pragma unroll
            for (int j = 0; j < 4; j++) {
                float hlo = __uint_as_float(ph.u[j] << 16);
                float hhi = __uint_as_float(ph.u[j] & 0xffff0000u);
                pl.u[j] = cvtpk_bf16(a[2*j] - hlo, a[2*j+1] - hhi);
            }
            short8 ahi = ph.s, alo = pl.s;

            f32x4 acc0 = {0.f, 0.f, 0.f, 0.f}, acc1 = {0.f, 0.f, 0.f, 0.f};
            acc0 = __builtin_amdgcn_mfma_f32_16x16x32_bf16(alo, bhi0, acc0, 0, 0, 0);
            acc0 = __builtin_amdgcn_mfma_f32_16x16x32_bf16(ahi, blo0, acc0, 0, 0, 0);
            acc0 = __builtin_amdgcn_mfma_f32_16x16x32_bf16(ahi, bhi0, acc0, 0, 0, 0);
            acc1 = __builtin_amdgcn_mfma_f32_16x16x32_bf16(alo, bhi1, acc1, 0, 0, 0);
            acc1 = __builtin_amdgcn_mfma_f32_16x16x32_bf16(ahi, blo1, acc1, 0, 0, 0);
            acc1 = __builtin_amdgcn_mfma_f32_16x16x32_bf16(ahi, bhi1, acc1, 0, 0, 0);
            #pragma unroll
            for (int r = 0; r < 4; r++) {
                int er = t * 16 + kg * 4 + r;
                lds[er * 33 + fr]      = fmaxf(acc0[r] + b2v0, 0.f);
                lds[er * 33 + fr + 16] = fmaxf(acc1[r] + b2v1, 0.f);
            }
        }

        if (hn) {
            yd0 = h2v[ndd0]; ys0 = h2v[nss0];
            yd1 = h2v[ndd1]; ys1 = h2v[nss1];
            yd2 = h2v[ndd2]; ys2 = h2v[nss2];
            yd3 = h2v[ndd3]; ys3 = h2v[nss3];
        }

        asm volatile("s_waitcnt lgkmcnt(0)" ::: "memory");

        float o0 = b3[0], o1 = b3[1], o2 = b3[2], o3 = b3[3];
        #pragma unroll
        for (int j = 0; j < 32; j++) {
            float aj = lds[lane * 33 + j];
            o0 = fmaf(aj, w3[4 * j],     o0);
            o1 = fmaf(aj, w3[4 * j + 1], o1);
            o2 = fmaf(aj, w3[4 * j + 2], o2);
            o3 = fmaf(aj, w3[4 * j + 3], o3);
        }
        reinterpret_cast<float4*>(msg)[slot] = make_float4(o0, o1, o2, o3);

        if (!hn) break;
        slot = nslot; g = gn;
    }
}

__global__ void agg2_kernel(const float* __restrict__ msg, const int* __restrict__ offs,
                            const int* __restrict__ cnt, float* __restrict__ out) {
    int lane = threadIdx.x & 63;
    int wave = threadIdx.x >> 6;
    int node = blockIdx.x * 8 + wave * 2 + (lane >> 5);
    int sub = lane & 31;
    if (node >= N_NODES) return;
    int base = offs[node];
    int deg  = cnt[node];
    float s0 = 0.f, s1 = 0.f, s2 = 0.f, s3 = 0.f;
    for (int k = sub; k < deg; k += 32) {
        float4 m = reinterpret_cast<const float4*>(msg)[base + k];
        s0 += m.x; s1 += m.y; s2 += m.z; s3 += m.w;
    }
    #pragma unroll
    for (int o = 16; o > 0; o >>= 1) {
        s0 += __shfl_down(s0, o, 32); s1 += __shfl_down(s1, o, 32);
        s2 += __shfl_down(s2, o, 32); s3 += __shfl_down(s3, o, 32);
    }
    if (sub == 0) {
        float c = fmaxf((float)deg, 1.f);
        reinterpret_cast<float4*>(out)[node] = make_float4(s0/c, s1/c, s2/c, s3/c);
    }
}

extern "C" void kernel_launch(void* const* d_in, const int* in_sizes, int n_in,
                              void* d_out, int out_size, void* d_ws, size_t ws_size,
                              hipStream_t stream) {
    const float* x        = (const float*)d_in[0];
    const int*   ei       = (const int*)  d_in[1];
    const float* bn_gamma = (const float*)d_in[2];
    const float* bn_beta  = (const float*)d_in[3];
    const float* enc_w1   = (const float*)d_in[4];
    const float* enc_b1   = (const float*)d_in[5];
    const float* enc_w2   = (const float*)d_in[6];
    const float* enc_b2   = (const float*)d_in[7];
    const float* enc_w3   = (const float*)d_in[8];
    const float* enc_b3   = (const float*)d_in[9];
    const float* dec_w1   = (const float*)d_in[10];
    const float* dec_b1   = (const float*)d_in[11];
    const float* dec_w2   = (const float*)d_in[12];
    const float* dec_b2   = (const float*)d_in[13];
    const float* dec_w3   = (const float*)d_in[14];
    const float* dec_b3   = (const float*)d_in[15];

    float* wsf    = (float*)d_ws;
    int*   wsi    = (int*)d_ws;
    float* stats  = wsf + O_STATS;
    int*   bktcnt = wsi + O_BKTCNT;
    int*   bktctr = wsi + O_BKTCTR;
    int*   bktbase= wsi + O_BKTBASE;
    int*   cnt    = wsi + O_CNT;
    int*   offs   = wsi + O_OFFS;
    int*   pos    = wsi + O_POS;
    int2*  sbk    = (int2*)(wsi + O_SBK);
    float* h      = wsf + O_H;
    float* h2     = wsf + O_H2;
    float* msg    = wsf + O_MSG;
    float* out    = (float*)d_out;

    hipMemsetAsync(d_ws, 0, (size_t)ZERO_WORDS * sizeof(float), stream);

    const int nodeBlocks = (N_NODES + 255) / 256;
    const int aggBlocks  = (N_NODES + 7) / 8;

    bn_stats_kernel<<<STATS_BLOCKS, 256, 0, stream>>>(x, stats);
    bn_apply_kernel<<<nodeBlocks, 256, 0, stream>>>(x, stats, bn_gamma, bn_beta, h);
    bucket_count_kernel<<<SCAT_BLOCKS, 256, 0, stream>>>(ei, bktcnt);
    bucket_scan_kernel<<<1, 256, 0, stream>>>(bktcnt, bktbase);
    scatter_kernel<<<SCAT_BLOCKS, 256, 0, stream>>>(ei, bktbase, bktctr, sbk);
    fine_rank_kernel<<<NBKT, 512, 0, stream>>>(sbk, bktbase, bktcnt, pos, offs, cnt);
    conv1_mfma_kernel<<<CONV_BLOCKS, 256, 0, stream>>>(h, ei, pos,
                                                       enc_w1, enc_b1, enc_w2, enc_b2,
                                                       enc_w3, enc_b3, msg);
    agg1_kernel<<<aggBlocks, 256, 0, stream>>>(msg, offs, cnt, h2);
    conv2_mfma_kernel<<<CONV_BLOCKS, 256, 0, stream>>>(h2, ei, pos,
                                                       dec_w1, dec_b1, dec_w2, dec_b2,
                                                       dec_w3, dec_b3, msg);
    agg2_kernel<<<aggBlocks, 256, 0, stream>>>(msg, offs, cnt, out);
}

// Round 17
// 266.546 us; speedup vs baseline: 1.6689x; 1.1482x over previous
//
#include <hip/hip_runtime.h>

#define N_NODES 100000
#define N_EDGES 3200000
#define BN_EPS 1e-5f
#define STATS_BLOCKS 64
#define CONV_BLOCKS 2048
#define NGROUPS (N_EDGES / 64)        // 50000
#define GSTRIDE (CONV_BLOCKS * 4)     // 8192
#define NBKT 196                      // ceil(100000/512)
#define SCAT_BLOCKS 1024
#define EDGES_PER_SCAT (N_EDGES / SCAT_BLOCKS)   // 3125

typedef __attribute__((ext_vector_type(8))) short short8;
typedef __attribute__((ext_vector_type(4))) float f32x4;
typedef __attribute__((ext_vector_type(4))) unsigned int uint32x4;

// workspace layout (4-byte units). Front section is zeroed each call.
constexpr int O_STATS   = 0;                         // 8 f
constexpr int O_BKTCNT  = 8;                         // 256 int
constexpr int O_BKTCTR  = 264;                       // 256 int
constexpr int O_SUM1    = 520;                       // 2N f
constexpr int O_SUM2    = O_SUM1 + 2 * N_NODES;      // 4N f
constexpr int ZERO_WORDS = O_SUM2 + 4 * N_NODES;     // 520 + 6N
constexpr int O_BKTBASE = ZERO_WORDS;                // 256 int
constexpr int O_CNT     = O_BKTBASE + 256;           // N int
constexpr int O_SBK     = O_CNT + N_NODES;           // 2E int (int2: dst,src)
constexpr int O_SDS     = O_SBK + 2 * N_EDGES;       // 2E int (int2: dst,src, grouped)
constexpr int O_H       = O_SDS + 2 * N_EDGES;       // 4N f
constexpr int O_H2      = O_H + 4 * N_NODES;         // 2N f

__device__ __forceinline__ unsigned short bf16_rne(float f) {
    unsigned u = __float_as_uint(f);
    unsigned r = (u + 0x7fff + ((u >> 16) & 1)) >> 16;
    return (unsigned short)r;
}
__device__ __forceinline__ float bf16_f32(unsigned short h) {
    return __uint_as_float(((unsigned)h) << 16);
}
__device__ __forceinline__ unsigned cvtpk_bf16(float a, float b) {
    unsigned r;
    asm("v_cvt_pk_bf16_f32 %0, %1, %2" : "=v"(r) : "v"(a), "v"(b));
    return r;
}
union PackU { uint32x4 u; short8 s; };

__global__ __launch_bounds__(256) void bn_stats_kernel(const float* __restrict__ x,
                                                       float* __restrict__ stats) {
    __shared__ float red[4][8];
    int tid = threadIdx.x;
    float s0=0.f,s1=0.f,s2=0.f,s3=0.f,q0=0.f,q1=0.f,q2=0.f,q3=0.f;
    for (int i = blockIdx.x * 256 + tid; i < N_NODES; i += STATS_BLOCKS * 256) {
        float4 v = reinterpret_cast<const float4*>(x)[i];
        s0+=v.x; s1+=v.y; s2+=v.z; s3+=v.w;
        q0=fmaf(v.x,v.x,q0); q1=fmaf(v.y,v.y,q1); q2=fmaf(v.z,v.z,q2); q3=fmaf(v.w,v.w,q3);
    }
    #pragma unroll
    for (int off = 32; off > 0; off >>= 1) {
        s0 += __shfl_down(s0, off); s1 += __shfl_down(s1, off);
        s2 += __shfl_down(s2, off); s3 += __shfl_down(s3, off);
        q0 += __shfl_down(q0, off); q1 += __shfl_down(q1, off);
        q2 += __shfl_down(q2, off); q3 += __shfl_down(q3, off);
    }
    int wave = tid >> 6, lane = tid & 63;
    if (lane == 0) {
        red[wave][0]=s0; red[wave][1]=s1; red[wave][2]=s2; red[wave][3]=s3;
        red[wave][4]=q0; red[wave][5]=q1; red[wave][6]=q2; red[wave][7]=q3;
    }
    __syncthreads();
    if (tid < 8) {
        float v = red[0][tid] + red[1][tid] + red[2][tid] + red[3][tid];
        atomicAdd(&stats[tid], v);
    }
}

__global__ void bn_apply_kernel(const float* __restrict__ x,
                                const float* __restrict__ stats,
                                const float* __restrict__ gamma,
                                const float* __restrict__ beta,
                                float* __restrict__ h) {
    int i = blockIdx.x * blockDim.x + threadIdx.x;
    if (i >= N_NODES) return;
    const float inv_n = 1.0f / (float)N_NODES;
    float m0 = stats[0]*inv_n, m1 = stats[1]*inv_n, m2 = stats[2]*inv_n, m3 = stats[3]*inv_n;
    float sc0 = rsqrtf(stats[4]*inv_n - m0*m0 + BN_EPS) * gamma[0];
    float sc1 = rsqrtf(stats[5]*inv_n - m1*m1 + BN_EPS) * gamma[1];
    float sc2 = rsqrtf(stats[6]*inv_n - m2*m2 + BN_EPS) * gamma[2];
    float sc3 = rsqrtf(stats[7]*inv_n - m3*m3 + BN_EPS) * gamma[3];
    float4 v = reinterpret_cast<const float4*>(x)[i];
    float4 o;
    o.x = (v.x - m0) * sc0 + beta[0];
    o.y = (v.y - m1) * sc1 + beta[1];
    o.z = (v.z - m2) * sc2 + beta[2];
    o.w = (v.w - m3) * sc3 + beta[3];
    reinterpret_cast<float4*>(h)[i] = o;
}

__global__ __launch_bounds__(256) void bucket_count_kernel(const int* __restrict__ ei,
                                                           int* __restrict__ bktcnt) {
    __shared__ int lh[256];
    int t = threadIdx.x;
    lh[t] = 0;
    __syncthreads();
    for (int e = blockIdx.x * 256 + t; e < N_EDGES; e += SCAT_BLOCKS * 256) {
        int d = ei[N_EDGES + e];
        atomicAdd(&lh[d >> 9], 1);
    }
    __syncthreads();
    int v = lh[t];
    if (v) atomicAdd(&bktcnt[t], v);
}

__global__ void bucket_scan_kernel(const int* __restrict__ bktcnt, int* __restrict__ bktbase) {
    __shared__ int sd[256];
    int t = threadIdx.x;
    int v = bktcnt[t];
    sd[t] = v; __syncthreads();
    for (int o = 1; o < 256; o <<= 1) {
        int x = (t >= o) ? sd[t - o] : 0;
        __syncthreads();
        sd[t] += x;
        __syncthreads();
    }
    bktbase[t] = sd[t] - v;
}

// partition edges into coarse-bucket-contiguous (dst, src) pairs.
__global__ __launch_bounds__(256) void scatter_kernel(const int* __restrict__ ei,
                                                      const int* __restrict__ bktbase,
                                                      int* __restrict__ bktctr,
                                                      int2* __restrict__ sbk) {
    __shared__ int lh[256], lbase[256], lctr[256];
    int t = threadIdx.x;
    lh[t] = 0; lctr[t] = 0;
    __syncthreads();
    int start = blockIdx.x * EDGES_PER_SCAT;
    int end = start + EDGES_PER_SCAT;
    for (int e = start + t; e < end; e += 256) {
        int d = ei[N_EDGES + e];
        atomicAdd(&lh[d >> 9], 1);
    }
    __syncthreads();
    int v = lh[t];
    if (v) lbase[t] = bktbase[t] + atomicAdd(&bktctr[t], v);
    __syncthreads();
    for (int e = start + t; e < end; e += 256) {
        int d = ei[N_EDGES + e];
        int s = ei[e];
        int b = d >> 9;
        int r = atomicAdd(&lctr[b], 1);
        sbk[lbase[b] + r] = make_int2(d, s);
    }
}

// per-bucket fine grouping: emits dst-grouped (dst,src) list + per-node counts.
__global__ __launch_bounds__(512) void fine_rank_kernel(const int2* __restrict__ sbk,
                                                        const int* __restrict__ bktbase,
                                                        const int* __restrict__ bktcnt,
                                                        int2* __restrict__ sds,
                                                        int* __restrict__ cnt) {
    __shared__ int hist[512], scanv[512], ctr[512];
    int b = blockIdx.x;
    int t = threadIdx.x;
    int ebase = bktbase[b];
    int ecount = bktcnt[b];
    hist[t] = 0; ctr[t] = 0;
    __syncthreads();
    for (int i = t; i < ecount; i += 512) {
        int d = sbk[ebase + i].x;
        atomicAdd(&hist[d & 511], 1);
    }
    __syncthreads();
    int v = hist[t];
    scanv[t] = v;
    __syncthreads();
    for (int o = 1; o < 512; o <<= 1) {
        int x = (t >= o) ? scanv[t - o] : 0;
        __syncthreads();
        scanv[t] += x;
        __syncthreads();
    }
    int excl = scanv[t] - v;
    int node = (b << 9) + t;
    if (node < N_NODES) cnt[node] = v;
    __syncthreads();
    hist[t] = excl;
    __syncthreads();
    for (int i = t; i < ecount; i += 512) {
        int2 de = sbk[ebase + i];
        int ld = de.x & 511;
        int r = atomicAdd(&ctr[ld], 1);
        sds[ebase + hist[ld] + r] = de;
    }
}

// conv1 fused with aggregation: process dst-grouped edges, per-edge MLP msg,
// wave segmented-reduce, tail-lane atomicAdd partials into sum1.
__global__ __launch_bounds__(256) void conv1_mfma_kernel(
    const float* __restrict__ h, const int2* __restrict__ sds,
    const float* __restrict__ w1, const float* __restrict__ b1,
    const float* __restrict__ w2, const float* __restrict__ b2,
    const float* __restrict__ w3, const float* __restrict__ b3,
    float* __restrict__ sum1)
{
    __shared__ unsigned a2lds[4][64 * 17];
    int tid = threadIdx.x;
    int wave = tid >> 6, lane = tid & 63;
    int kg = lane >> 4, fr = lane & 15;
    unsigned* lds = &a2lds[wave][0];
    const float4* h4 = reinterpret_cast<const float4*>(h);

    float al[4][8], be[4][8], b1v[8];
    #pragma unroll
    for (int i = 0; i < 8; i++) {
        int k = kg * 8 + i;
        #pragma unroll
        for (int c = 0; c < 4; c++) {
            float wa = w1[c * 32 + k];
            float wb = w1[(4 + c) * 32 + k];
            al[c][i] = wa - wb;
            be[c][i] = wb;
        }
        b1v[i] = b1[k];
    }
    short8 bhi0, blo0, bhi1, blo1;
    #pragma unroll
    for (int i = 0; i < 8; i++) {
        int k = kg * 8 + i;
        float w0 = w2[k * 32 + fr];
        float w1c = w2[k * 32 + fr + 16];
        unsigned short h0 = bf16_rne(w0);
        bhi0[i] = (short)h0; blo0[i] = (short)bf16_rne(w0 - bf16_f32(h0));
        unsigned short h1 = bf16_rne(w1c);
        bhi1[i] = (short)h1; blo1[i] = (short)bf16_rne(w1c - bf16_f32(h1));
    }
    float b2v0 = b2[fr], b2v1 = b2[fr + 16];

    int g = blockIdx.x * 4 + wave;
    if (g >= NGROUPS) return;

    int base = g * 64;
    int2 p0 = sds[base + fr], p1 = sds[base + 16 + fr];
    int2 p2 = sds[base + 32 + fr], p3 = sds[base + 48 + fr];
    float4 xi0 = h4[p0.x], xj0 = h4[p0.y];
    float4 xi1 = h4[p1.x], xj1 = h4[p1.y];
    float4 xi2 = h4[p2.x], xj2 = h4[p2.y];
    float4 xi3 = h4[p3.x], xj3 = h4[p3.y];

    while (true) {
        int gn = g + GSTRIDE;
        bool hn = gn < NGROUPS;
        int basen = gn * 64;
        int2 q0, q1, q2, q3;
        if (hn) {
            q0 = sds[basen + fr];      q1 = sds[basen + 16 + fr];
            q2 = sds[basen + 32 + fr]; q3 = sds[basen + 48 + fr];
        }

        #pragma unroll
        for (int t = 0; t < 4; t++) {
            float4 xi = t == 0 ? xi0 : t == 1 ? xi1 : t == 2 ? xi2 : xi3;
            float4 xj = t == 0 ? xj0 : t == 1 ? xj1 : t == 2 ? xj2 : xj3;
            float a[8];
            #pragma unroll
            for (int i = 0; i < 8; i++) {
                float pre = b1v[i];
                pre = fmaf(al[0][i], xi.x, pre);
                pre = fmaf(al[1][i], xi.y, pre);
                pre = fmaf(al[2][i], xi.z, pre);
                pre = fmaf(al[3][i], xi.w, pre);
                pre = fmaf(be[0][i], xj.x, pre);
                pre = fmaf(be[1][i], xj.y, pre);
                pre = fmaf(be[2][i], xj.z, pre);
                pre = fmaf(be[3][i], xj.w, pre);
                a[i] = fmaxf(pre, 0.f);
            }
            PackU pu;
            #pragma unroll
            for (int j = 0; j < 4; j++) pu.u[j] = cvtpk_bf16(a[2*j], a[2*j+1]);
            short8 ahi = pu.s;

            f32x4 acc0 = {0.f, 0.f, 0.f, 0.f}, acc1 = {0.f, 0.f, 0.f, 0.f};
            acc0 = __builtin_amdgcn_mfma_f32_16x16x32_bf16(ahi, blo0, acc0, 0, 0, 0);
            acc0 = __builtin_amdgcn_mfma_f32_16x16x32_bf16(ahi, bhi0, acc0, 0, 0, 0);
            acc1 = __builtin_amdgcn_mfma_f32_16x16x32_bf16(ahi, blo1, acc1, 0, 0, 0);
            acc1 = __builtin_amdgcn_mfma_f32_16x16x32_bf16(ahi, bhi1, acc1, 0, 0, 0);
            #pragma unroll
            for (int r = 0; r < 4; r++) {
                int er = t * 16 + kg * 4 + r;
                float a20 = fmaxf(acc0[r] + b2v0, 0.f);
                float a21 = fmaxf(acc1[r] + b2v1, 0.f);
                lds[er * 17 + fr] = cvtpk_bf16(a20, a21);
            }
        }

        if (hn) {
            xi0 = h4[q0.x]; xj0 = h4[q0.y];
            xi1 = h4[q1.x]; xj1 = h4[q1.y];
            xi2 = h4[q2.x]; xj2 = h4[q2.y];
            xi3 = h4[q3.x]; xj3 = h4[q3.y];
        }

        asm volatile("s_waitcnt lgkmcnt(0)" ::: "memory");

        // per-edge message for edge base+lane
        float m0 = b3[0], m1 = b3[1];
        #pragma unroll
        for (int j = 0; j < 16; j++) {
            unsigned u = lds[lane * 17 + j];
            float flo = __uint_as_float(u << 16);
            float fhi = __uint_as_float(u & 0xffff0000u);
            m0 = fmaf(flo, w3[2 * j],        m0);
            m1 = fmaf(flo, w3[2 * j + 1],    m1);
            m0 = fmaf(fhi, w3[2 * (j + 16)],     m0);
            m1 = fmaf(fhi, w3[2 * (j + 16) + 1], m1);
        }
        m0 = fmaxf(m0, 0.f); m1 = fmaxf(m1, 0.f);

        // segmented reduce over dst runs
        int d = kg == 0 ? p0.x : kg == 1 ? p1.x : kg == 2 ? p2.x : p3.x;
        int dprev = __shfl_up(d, 1);
        int dnext = __shfl_down(d, 1);
        bool head = (lane == 0) || (d != dprev);
        bool tail = (lane == 63) || (d != dnext);
        unsigned long long hb = __ballot(head);
        unsigned long long msk = (lane == 63) ? ~0ull : ((1ull << (lane + 1)) - 1ull);
        int seg0 = 63 - __clzll(hb & msk);
        #pragma unroll
        for (int st = 1; st < 64; st <<= 1) {
            float u0 = __shfl_up(m0, st);
            float u1 = __shfl_up(m1, st);
            if (lane - st >= seg0) { m0 += u0; m1 += u1; }
        }
        if (tail) {
            atomicAdd(&sum1[2 * d],     m0);
            atomicAdd(&sum1[2 * d + 1], m1);
        }

        if (!hn) break;
        p0 = q0; p1 = q1; p2 = q2; p3 = q3; g = gn;
    }
}

__global__ void div1_kernel(const float* __restrict__ sum1, const int* __restrict__ cnt,
                            float* __restrict__ h2) {
    int i = blockIdx.x * 256 + threadIdx.x;
    if (i >= N_NODES) return;
    float c = fmaxf((float)cnt[i], 1.f);
    float2 s = reinterpret_cast<const float2*>(sum1)[i];
    reinterpret_cast<float2*>(h2)[i] = make_float2(s.x / c, s.y / c);
}

// conv2 fused with aggregation (4-wide messages, no final relu).
__global__ __launch_bounds__(256) void conv2_mfma_kernel(
    const float* __restrict__ h2, const int2* __restrict__ sds,
    const float* __restrict__ w1, const float* __restrict__ b1,
    const float* __restrict__ w2, const float* __restrict__ b2,
    const float* __restrict__ w3, const float* __restrict__ b3,
    float* __restrict__ sum2)
{
    __shared__ float a2lds[4][64 * 33];
    int tid = threadIdx.x;
    int wave = tid >> 6, lane = tid & 63;
    int kg = lane >> 4, fr = lane & 15;
    float* lds = &a2lds[wave][0];
    const float2* h2v = reinterpret_cast<const float2*>(h2);

    float al0[8], al1[8], be0[8], be1[8], b1v[8];
    #pragma unroll
    for (int i = 0; i < 8; i++) {
        int k = kg * 8 + i;
        float c0a = w1[k], c1a = w1[32 + k];
        float c0b = w1[64 + k], c1b = w1[96 + k];
        al0[i] = c0a - c0b; al1[i] = c1a - c1b;
        be0[i] = c0b; be1[i] = c1b;
        b1v[i] = b1[k];
    }
    short8 bhi0, blo0, bhi1, blo1;
    #pragma unroll
    for (int i = 0; i < 8; i++) {
        int k = kg * 8 + i;
        float w0 = w2[k * 32 + fr];
        float w1c = w2[k * 32 + fr + 16];
        unsigned short h0 = bf16_rne(w0);
        bhi0[i] = (short)h0; blo0[i] = (short)bf16_rne(w0 - bf16_f32(h0));
        unsigned short h1 = bf16_rne(w1c);
        bhi1[i] = (short)h1; blo1[i] = (short)bf16_rne(w1c - bf16_f32(h1));
    }
    float b2v0 = b2[fr], b2v1 = b2[fr + 16];

    int g = blockIdx.x * 4 + wave;
    if (g >= NGROUPS) return;
    int base = g * 64;
    int2 p0 = sds[base + fr], p1 = sds[base + 16 + fr];
    int2 p2 = sds[base + 32 + fr], p3 = sds[base + 48 + fr];
    float2 yd0 = h2v[p0.x], ys0 = h2v[p0.y];
    float2 yd1 = h2v[p1.x], ys1 = h2v[p1.y];
    float2 yd2 = h2v[p2.x], ys2 = h2v[p2.y];
    float2 yd3 = h2v[p3.x], ys3 = h2v[p3.y];

    while (true) {
        int gn = g + GSTRIDE;
        bool hn = gn < NGROUPS;
        int basen = gn * 64;
        int2 q0, q1, q2, q3;
        if (hn) {
            q0 = sds[basen + fr];      q1 = sds[basen + 16 + fr];
            q2 = sds[basen + 32 + fr]; q3 = sds[basen + 48 + fr];
        }

        #pragma unroll
        for (int t = 0; t < 4; t++) {
            float2 yd = t == 0 ? yd0 : t == 1 ? yd1 : t == 2 ? yd2 : yd3;
            float2 ys = t == 0 ? ys0 : t == 1 ? ys1 : t == 2 ? ys2 : ys3;
            float a[8];
            #pragma unroll
            for (int i = 0; i < 8; i++) {
                float pre = b1v[i];
                pre = fmaf(al0[i], yd.x, pre);
                pre = fmaf(al1[i], yd.y, pre);
                pre = fmaf(be0[i], ys.x, pre);
                pre = fmaf(be1[i], ys.y, pre);
                a[i] = fmaxf(pre, 0.f);
            }
            PackU ph, pl;
            #pragma unroll
            for (int j = 0; j < 4; j++) ph.u[j] = cvtpk_bf16(a[2*j], a[2*j+1]);
            #pragma unroll
            for (int j = 0; j < 4; j++) {
                float hlo = __uint_as_float(ph.u[j] << 16);
                float hhi = __uint_as_float(ph.u[j] & 0xffff0000u);
                pl.u[j] = cvtpk_bf16(a[2*j] - hlo, a[2*j+1] - hhi);
            }
            short8 ahi = ph.s, alo = pl.s;

            f32x4 acc0 = {0.f, 0.f, 0.f, 0.f}, acc1 = {0.f, 0.f, 0.f, 0.f};
            acc0 = __builtin_amdgcn_mfma_f32_16x16x32_bf16(alo, bhi0, acc0, 0, 0, 0);
            acc0 = __builtin_amdgcn_mfma_f32_16x16x32_bf16(ahi, blo0, acc0, 0, 0, 0);
            acc0 = __builtin_amdgcn_mfma_f32_16x16x32_bf16(ahi, bhi0, acc0, 0, 0, 0);
            acc1 = __builtin_amdgcn_mfma_f32_16x16x32_bf16(alo, bhi1, acc1, 0, 0, 0);
            acc1 = __builtin_amdgcn_mfma_f32_16x16x32_bf16(ahi, blo1, acc1, 0, 0, 0);
            acc1 = __builtin_amdgcn_mfma_f32_16x16x32_bf16(ahi, bhi1, acc1, 0, 0, 0);
            #pragma unroll
            for (int r = 0; r < 4; r++) {
                int er = t * 16 + kg * 4 + r;
                lds[er * 33 + fr]      = fmaxf(acc0[r] + b2v0, 0.f);
                lds[er * 33 + fr + 16] = fmaxf(acc1[r] + b2v1, 0.f);
            }
        }

        if (hn) {
            yd0 = h2v[q0.x]; ys0 = h2v[q0.y];
            yd1 = h2v[q1.x]; ys1 = h2v[q1.y];
            yd2 = h2v[q2.x]; ys2 = h2v[q2.y];
            yd3 = h2v[q3.x]; ys3 = h2v[q3.y];
        }

        asm volatile("s_waitcnt lgkmcnt(0)" ::: "memory");

        float o0 = b3[0], o1 = b3[1], o2 = b3[2], o3 = b3[3];
        #pragma unroll
        for (int j = 0; j < 32; j++) {
            float aj = lds[lane * 33 + j];
            o0 = fmaf(aj, w3[4 * j],     o0);
            o1 = fmaf(aj, w3[4 * j + 1], o1);
            o2 = fmaf(aj, w3[4 * j + 2], o2);
            o3 = fmaf(aj, w3[4 * j + 3], o3);
        }

        int d = kg == 0 ? p0.x : kg == 1 ? p1.x : kg == 2 ? p2.x : p3.x;
        int dprev = __shfl_up(d, 1);
        int dnext = __shfl_down(d, 1);
        bool head = (lane == 0) || (d != dprev);
        bool tail = (lane == 63) || (d != dnext);
        unsigned long long hb = __ballot(head);
        unsigned long long msk = (lane == 63) ? ~0ull : ((1ull << (lane + 1)) - 1ull);
        int seg0 = 63 - __clzll(hb & msk);
        #pragma unroll
        for (int st = 1; st < 64; st <<= 1) {
            float u0 = __shfl_up(o0, st);
            float u1 = __shfl_up(o1, st);
            float u2 = __shfl_up(o2, st);
            float u3 = __shfl_up(o3, st);
            if (lane - st >= seg0) { o0 += u0; o1 += u1; o2 += u2; o3 += u3; }
        }
        if (tail) {
            atomicAdd(&sum2[4 * d],     o0);
            atomicAdd(&sum2[4 * d + 1], o1);
            atomicAdd(&sum2[4 * d + 2], o2);
            atomicAdd(&sum2[4 * d + 3], o3);
        }

        if (!hn) break;
        p0 = q0; p1 = q1; p2 = q2; p3 = q3; g = gn;
    }
}

__global__ void div2_kernel(const float* __restrict__ sum2, const int* __restrict__ cnt,
                            float* __restrict__ out) {
    int i = blockIdx.x * 256 + threadIdx.x;
    if (i >= N_NODES) return;
    float c = fmaxf((float)cnt[i], 1.f);
    float4 s = reinterpret_cast<const float4*>(sum2)[i];
    reinterpret_cast<float4*>(out)[i] = make_float4(s.x/c, s.y/c, s.z/c, s.w/c);
}

extern "C" void kernel_launch(void* const* d_in, const int* in_sizes, int n_in,
                              void* d_out, int out_size, void* d_ws, size_t ws_size,
                              hipStream_t stream) {
    const float* x        = (const float*)d_in[0];
    const int*   ei       = (const int*)  d_in[1];
    const float* bn_gamma = (const float*)d_in[2];
    const float* bn_beta  = (const float*)d_in[3];
    const float* enc_w1   = (const float*)d_in[4];
    const float* enc_b1   = (const float*)d_in[5];
    const float* enc_w2   = (const float*)d_in[6];
    const float* enc_b2   = (const float*)d_in[7];
    const float* enc_w3   = (const float*)d_in[8];
    const float* enc_b3   = (const float*)d_in[9];
    const float* dec_w1   = (const float*)d_in[10];
    const float* dec_b1   = (const float*)d_in[11];
    const float* dec_w2   = (const float*)d_in[12];
    const float* dec_b2   = (const float*)d_in[13];
    const float* dec_w3   = (const float*)d_in[14];
    const float* dec_b3   = (const float*)d_in[15];

    float* wsf    = (float*)d_ws;
    int*   wsi    = (int*)d_ws;
    float* stats  = wsf + O_STATS;
    int*   bktcnt = wsi + O_BKTCNT;
    int*   bktctr = wsi + O_BKTCTR;
    float* sum1   = wsf + O_SUM1;
    float* sum2   = wsf + O_SUM2;
    int*   bktbase= wsi + O_BKTBASE;
    int*   cnt    = wsi + O_CNT;
    int2*  sbk    = (int2*)(wsi + O_SBK);
    int2*  sds    = (int2*)(wsi + O_SDS);
    float* h      = wsf + O_H;
    float* h2     = wsf + O_H2;
    float* out    = (float*)d_out;

    hipMemsetAsync(d_ws, 0, (size_t)ZERO_WORDS * sizeof(float), stream);

    const int nodeBlocks = (N_NODES + 255) / 256;

    bn_stats_kernel<<<STATS_BLOCKS, 256, 0, stream>>>(x, stats);
    bn_apply_kernel<<<nodeBlocks, 256, 0, stream>>>(x, stats, bn_gamma, bn_beta, h);
    bucket_count_kernel<<<SCAT_BLOCKS, 256, 0, stream>>>(ei, bktcnt);
    bucket_scan_kernel<<<1, 256, 0, stream>>>(bktcnt, bktbase);
    scatter_kernel<<<SCAT_BLOCKS, 256, 0, stream>>>(ei, bktbase, bktctr, sbk);
    fine_rank_kernel<<<NBKT, 512, 0, stream>>>(sbk, bktbase, bktcnt, sds, cnt);
    conv1_mfma_kernel<<<CONV_BLOCKS, 256, 0, stream>>>(h, sds,
                                                       enc_w1, enc_b1, enc_w2, enc_b2,
                                                       enc_w3, enc_b3, sum1);
    div1_kernel<<<nodeBlocks, 256, 0, stream>>>(sum1, cnt, h2);
    conv2_mfma_kernel<<<CONV_BLOCKS, 256, 0, stream>>>(h2, sds,
                                                       dec_w1, dec_b1, dec_w2, dec_b2,
                                                       dec_w3, dec_b3, sum2);
    div2_kernel<<<nodeBlocks, 256, 0, stream>>>(sum2, cnt, out);
}

// Round 18
// 261.368 us; speedup vs baseline: 1.7019x; 1.0198x over previous
//
#include <hip/hip_runtime.h>

#define N_NODES 100000
#define N_EDGES 3200000
#define BN_EPS 1e-5f
#define STATS_BLOCKS 64
#define CONV_BLOCKS 2048
#define NGROUPS (N_EDGES / 64)        // 50000
#define GSTRIDE (CONV_BLOCKS * 4)     // 8192
#define NBKT 196                      // ceil(100000/512)
#define SCAT_BLOCKS 1024
#define EDGES_PER_SCAT (N_EDGES / SCAT_BLOCKS)   // 3125

typedef __attribute__((ext_vector_type(8))) short short8;
typedef __attribute__((ext_vector_type(4))) float f32x4;
typedef __attribute__((ext_vector_type(4))) unsigned int uint32x4;

// workspace layout (4-byte units). Front section is zeroed each call.
constexpr int O_STATS   = 0;                         // 8 f
constexpr int O_BKTCNT  = 8;                         // 256 int
constexpr int O_BKTCTR  = 264;                       // 256 int
constexpr int O_SUM1    = 520;                       // 2N f
constexpr int O_SUM2    = O_SUM1 + 2 * N_NODES;      // 4N f
constexpr int ZERO_WORDS = O_SUM2 + 4 * N_NODES;     // 520 + 6N
constexpr int O_BKTBASE = ZERO_WORDS;                // 256 int
constexpr int O_CNT     = O_BKTBASE + 256;           // N int
constexpr int O_SBK     = O_CNT + N_NODES;           // 2E int (int2: dst,src)
constexpr int O_SDS     = O_SBK + 2 * N_EDGES;       // 2E int (int2: dst,src, grouped)
constexpr int O_H       = O_SDS + 2 * N_EDGES;       // 4N f
constexpr int O_H2      = O_H + 4 * N_NODES;         // 2N f

__device__ __forceinline__ unsigned short bf16_rne(float f) {
    unsigned u = __float_as_uint(f);
    unsigned r = (u + 0x7fff + ((u >> 16) & 1)) >> 16;
    return (unsigned short)r;
}
__device__ __forceinline__ float bf16_f32(unsigned short h) {
    return __uint_as_float(((unsigned)h) << 16);
}
__device__ __forceinline__ unsigned cvtpk_bf16(float a, float b) {
    unsigned r;
    asm("v_cvt_pk_bf16_f32 %0, %1, %2" : "=v"(r) : "v"(a), "v"(b));
    return r;
}
union PackU { uint32x4 u; short8 s; };

__global__ __launch_bounds__(256) void bn_stats_kernel(const float* __restrict__ x,
                                                       float* __restrict__ stats) {
    __shared__ float red[4][8];
    int tid = threadIdx.x;
    float s0=0.f,s1=0.f,s2=0.f,s3=0.f,q0=0.f,q1=0.f,q2=0.f,q3=0.f;
    for (int i = blockIdx.x * 256 + tid; i < N_NODES; i += STATS_BLOCKS * 256) {
        float4 v = reinterpret_cast<const float4*>(x)[i];
        s0+=v.x; s1+=v.y; s2+=v.z; s3+=v.w;
        q0=fmaf(v.x,v.x,q0); q1=fmaf(v.y,v.y,q1); q2=fmaf(v.z,v.z,q2); q3=fmaf(v.w,v.w,q3);
    }
    #pragma unroll
    for (int off = 32; off > 0; off >>= 1) {
        s0 += __shfl_down(s0, off); s1 += __shfl_down(s1, off);
        s2 += __shfl_down(s2, off); s3 += __shfl_down(s3, off);
        q0 += __shfl_down(q0, off); q1 += __shfl_down(q1, off);
        q2 += __shfl_down(q2, off); q3 += __shfl_down(q3, off);
    }
    int wave = tid >> 6, lane = tid & 63;
    if (lane == 0) {
        red[wave][0]=s0; red[wave][1]=s1; red[wave][2]=s2; red[wave][3]=s3;
        red[wave][4]=q0; red[wave][5]=q1; red[wave][6]=q2; red[wave][7]=q3;
    }
    __syncthreads();
    if (tid < 8) {
        float v = red[0][tid] + red[1][tid] + red[2][tid] + red[3][tid];
        atomicAdd(&stats[tid], v);
    }
}

__global__ void bn_apply_kernel(const float* __restrict__ x,
                                const float* __restrict__ stats,
                                const float* __restrict__ gamma,
                                const float* __restrict__ beta,
                                float* __restrict__ h) {
    int i = blockIdx.x * blockDim.x + threadIdx.x;
    if (i >= N_NODES) return;
    const float inv_n = 1.0f / (float)N_NODES;
    float m0 = stats[0]*inv_n, m1 = stats[1]*inv_n, m2 = stats[2]*inv_n, m3 = stats[3]*inv_n;
    float sc0 = rsqrtf(stats[4]*inv_n - m0*m0 + BN_EPS) * gamma[0];
    float sc1 = rsqrtf(stats[5]*inv_n - m1*m1 + BN_EPS) * gamma[1];
    float sc2 = rsqrtf(stats[6]*inv_n - m2*m2 + BN_EPS) * gamma[2];
    float sc3 = rsqrtf(stats[7]*inv_n - m3*m3 + BN_EPS) * gamma[3];
    float4 v = reinterpret_cast<const float4*>(x)[i];
    float4 o;
    o.x = (v.x - m0) * sc0 + beta[0];
    o.y = (v.y - m1) * sc1 + beta[1];
    o.z = (v.z - m2) * sc2 + beta[2];
    o.w = (v.w - m3) * sc3 + beta[3];
    reinterpret_cast<float4*>(h)[i] = o;
}

__global__ __launch_bounds__(256) void bucket_count_kernel(const int* __restrict__ ei,
                                                           int* __restrict__ bktcnt) {
    __shared__ int lh[256];
    int t = threadIdx.x;
    lh[t] = 0;
    __syncthreads();
    for (int e = blockIdx.x * 256 + t; e < N_EDGES; e += SCAT_BLOCKS * 256) {
        int d = ei[N_EDGES + e];
        atomicAdd(&lh[d >> 9], 1);
    }
    __syncthreads();
    int v = lh[t];
    if (v) atomicAdd(&bktcnt[t], v);
}

__global__ void bucket_scan_kernel(const int* __restrict__ bktcnt, int* __restrict__ bktbase) {
    __shared__ int sd[256];
    int t = threadIdx.x;
    int v = bktcnt[t];
    sd[t] = v; __syncthreads();
    for (int o = 1; o < 256; o <<= 1) {
        int x = (t >= o) ? sd[t - o] : 0;
        __syncthreads();
        sd[t] += x;
        __syncthreads();
    }
    bktbase[t] = sd[t] - v;
}

// partition edges into coarse-bucket-contiguous (dst, src) pairs.
__global__ __launch_bounds__(256) void scatter_kernel(const int* __restrict__ ei,
                                                      const int* __restrict__ bktbase,
                                                      int* __restrict__ bktctr,
                                                      int2* __restrict__ sbk) {
    __shared__ int lh[256], lbase[256], lctr[256];
    int t = threadIdx.x;
    lh[t] = 0; lctr[t] = 0;
    __syncthreads();
    int start = blockIdx.x * EDGES_PER_SCAT;
    int end = start + EDGES_PER_SCAT;
    for (int e = start + t; e < end; e += 256) {
        int d = ei[N_EDGES + e];
        atomicAdd(&lh[d >> 9], 1);
    }
    __syncthreads();
    int v = lh[t];
    if (v) lbase[t] = bktbase[t] + atomicAdd(&bktctr[t], v);
    __syncthreads();
    for (int e = start + t; e < end; e += 256) {
        int d = ei[N_EDGES + e];
        int s = ei[e];
        int b = d >> 9;
        int r = atomicAdd(&lctr[b], 1);
        sbk[lbase[b] + r] = make_int2(d, s);
    }
}

// per-bucket fine grouping: emits dst-grouped (dst,src) list + per-node counts.
__global__ __launch_bounds__(512) void fine_rank_kernel(const int2* __restrict__ sbk,
                                                        const int* __restrict__ bktbase,
                                                        const int* __restrict__ bktcnt,
                                                        int2* __restrict__ sds,
                                                        int* __restrict__ cnt) {
    __shared__ int hist[512], scanv[512], ctr[512];
    int b = blockIdx.x;
    int t = threadIdx.x;
    int ebase = bktbase[b];
    int ecount = bktcnt[b];
    hist[t] = 0; ctr[t] = 0;
    __syncthreads();
    for (int i = t; i < ecount; i += 512) {
        int d = sbk[ebase + i].x;
        atomicAdd(&hist[d & 511], 1);
    }
    __syncthreads();
    int v = hist[t];
    scanv[t] = v;
    __syncthreads();
    for (int o = 1; o < 512; o <<= 1) {
        int x = (t >= o) ? scanv[t - o] : 0;
        __syncthreads();
        scanv[t] += x;
        __syncthreads();
    }
    int excl = scanv[t] - v;
    int node = (b << 9) + t;
    if (node < N_NODES) cnt[node] = v;
    __syncthreads();
    hist[t] = excl;
    __syncthreads();
    for (int i = t; i < ecount; i += 512) {
        int2 de = sbk[ebase + i];
        int ld = de.x & 511;
        int r = atomicAdd(&ctr[ld], 1);
        sds[ebase + hist[ld] + r] = de;
    }
}

// conv1 fused with aggregation: process dst-grouped edges, per-edge MLP msg,
// wave segmented-reduce, tail-lane atomicAdd partials into sum1.
__global__ __launch_bounds__(256) void conv1_mfma_kernel(
    const float* __restrict__ h, const int2* __restrict__ sds,
    const float* __restrict__ w1, const float* __restrict__ b1,
    const float* __restrict__ w2, const float* __restrict__ b2,
    const float* __restrict__ w3, const float* __restrict__ b3,
    float* __restrict__ sum1)
{
    __shared__ unsigned a2lds[4][64 * 17];
    int tid = threadIdx.x;
    int wave = tid >> 6, lane = tid & 63;
    int kg = lane >> 4, fr = lane & 15;
    unsigned* lds = &a2lds[wave][0];
    const float4* h4 = reinterpret_cast<const float4*>(h);

    float al[4][8], be[4][8], b1v[8];
    #pragma unroll
    for (int i = 0; i < 8; i++) {
        int k = kg * 8 + i;
        #pragma unroll
        for (int c = 0; c < 4; c++) {
            float wa = w1[c * 32 + k];
            float wb = w1[(4 + c) * 32 + k];
            al[c][i] = wa - wb;
            be[c][i] = wb;
        }
        b1v[i] = b1[k];
    }
    short8 bhi0, blo0, bhi1, blo1;
    #pragma unroll
    for (int i = 0; i < 8; i++) {
        int k = kg * 8 + i;
        float w0 = w2[k * 32 + fr];
        float w1c = w2[k * 32 + fr + 16];
        unsigned short h0 = bf16_rne(w0);
        bhi0[i] = (short)h0; blo0[i] = (short)bf16_rne(w0 - bf16_f32(h0));
        unsigned short h1 = bf16_rne(w1c);
        bhi1[i] = (short)h1; blo1[i] = (short)bf16_rne(w1c - bf16_f32(h1));
    }
    float b2v0 = b2[fr], b2v1 = b2[fr + 16];

    int g = blockIdx.x * 4 + wave;
    if (g >= NGROUPS) return;

    int base = g * 64;
    int2 p0 = sds[base + fr], p1 = sds[base + 16 + fr];
    int2 p2 = sds[base + 32 + fr], p3 = sds[base + 48 + fr];
    float4 xi0 = h4[p0.x], xj0 = h4[p0.y];
    float4 xi1 = h4[p1.x], xj1 = h4[p1.y];
    float4 xi2 = h4[p2.x], xj2 = h4[p2.y];
    float4 xi3 = h4[p3.x], xj3 = h4[p3.y];

    while (true) {
        int gn = g + GSTRIDE;
        bool hn = gn < NGROUPS;
        int basen = gn * 64;
        int2 q0, q1, q2, q3;
        if (hn) {
            q0 = sds[basen + fr];      q1 = sds[basen + 16 + fr];
            q2 = sds[basen + 32 + fr]; q3 = sds[basen + 48 + fr];
        }

        #pragma unroll
        for (int t = 0; t < 4; t++) {
            float4 xi = t == 0 ? xi0 : t == 1 ? xi1 : t == 2 ? xi2 : xi3;
            float4 xj = t == 0 ? xj0 : t == 1 ? xj1 : t == 2 ? xj2 : xj3;
            float a[8];
            #pragma unroll
            for (int i = 0; i < 8; i++) {
                float pre = b1v[i];
                pre = fmaf(al[0][i], xi.x, pre);
                pre = fmaf(al[1][i], xi.y, pre);
                pre = fmaf(al[2][i], xi.z, pre);
                pre = fmaf(al[3][i], xi.w, pre);
                pre = fmaf(be[0][i], xj.x, pre);
                pre = fmaf(be[1][i], xj.y, pre);
                pre = fmaf(be[2][i], xj.z, pre);
                pre = fmaf(be[3][i], xj.w, pre);
                a[i] = fmaxf(pre, 0.f);
            }
            PackU pu;
            #pragma unroll
            for (int j = 0; j < 4; j++) pu.u[j] = cvtpk_bf16(a[2*j], a[2*j+1]);
            short8 ahi = pu.s;

            f32x4 acc0 = {0.f, 0.f, 0.f, 0.f}, acc1 = {0.f, 0.f, 0.f, 0.f};
            acc0 = __builtin_amdgcn_mfma_f32_16x16x32_bf16(ahi, blo0, acc0, 0, 0, 0);
            acc0 = __builtin_amdgcn_mfma_f32_16x16x32_bf16(ahi, bhi0, acc0, 0, 0, 0);
            acc1 = __builtin_amdgcn_mfma_f32_16x16x32_bf16(ahi, blo1, acc1, 0, 0, 0);
            acc1 = __builtin_amdgcn_mfma_f32_16x16x32_bf16(ahi, bhi1, acc1, 0, 0, 0);
            #pragma unroll
            for (int r = 0; r < 4; r++) {
                int er = t * 16 + kg * 4 + r;
                float a20 = fmaxf(acc0[r] + b2v0, 0.f);
                float a21 = fmaxf(acc1[r] + b2v1, 0.f);
                lds[er * 17 + fr] = cvtpk_bf16(a20, a21);
            }
        }

        if (hn) {
            xi0 = h4[q0.x]; xj0 = h4[q0.y];
            xi1 = h4[q1.x]; xj1 = h4[q1.y];
            xi2 = h4[q2.x]; xj2 = h4[q2.y];
            xi3 = h4[q3.x]; xj3 = h4[q3.y];
        }

        asm volatile("s_waitcnt lgkmcnt(0)" ::: "memory");

        // per-edge message for edge base+lane
        float m0 = b3[0], m1 = b3[1];
        #pragma unroll
        for (int j = 0; j < 16; j++) {
            unsigned u = lds[lane * 17 + j];
            float flo = __uint_as_float(u << 16);
            float fhi = __uint_as_float(u & 0xffff0000u);
            m0 = fmaf(flo, w3[2 * j],        m0);
            m1 = fmaf(flo, w3[2 * j + 1],    m1);
            m0 = fmaf(fhi, w3[2 * (j + 16)],     m0);
            m1 = fmaf(fhi, w3[2 * (j + 16) + 1], m1);
        }
        m0 = fmaxf(m0, 0.f); m1 = fmaxf(m1, 0.f);

        // segmented reduce over dst runs
        int d = kg == 0 ? p0.x : kg == 1 ? p1.x : kg == 2 ? p2.x : p3.x;
        int dprev = __shfl_up(d, 1);
        int dnext = __shfl_down(d, 1);
        bool head = (lane == 0) || (d != dprev);
        bool tail = (lane == 63) || (d != dnext);
        unsigned long long hb = __ballot(head);
        unsigned long long msk = (lane == 63) ? ~0ull : ((1ull << (lane + 1)) - 1ull);
        int seg0 = 63 - __clzll(hb & msk);
        #pragma unroll
        for (int st = 1; st < 64; st <<= 1) {
            float u0 = __shfl_up(m0, st);
            float u1 = __shfl_up(m1, st);
            if (lane - st >= seg0) { m0 += u0; m1 += u1; }
        }
        if (tail) {
            atomicAdd(&sum1[2 * d],     m0);
            atomicAdd(&sum1[2 * d + 1], m1);
        }

        if (!hn) break;
        p0 = q0; p1 = q1; p2 = q2; p3 = q3; g = gn;
    }
}

__global__ void div1_kernel(const float* __restrict__ sum1, const int* __restrict__ cnt,
                            float* __restrict__ h2) {
    int i = blockIdx.x * 256 + threadIdx.x;
    if (i >= N_NODES) return;
    float c = fmaxf((float)cnt[i], 1.f);
    float2 s = reinterpret_cast<const float2*>(sum1)[i];
    reinterpret_cast<float2*>(h2)[i] = make_float2(s.x / c, s.y / c);
}

// conv2 fused with aggregation — conv1's proven structure: A bf16-hi only
// (4 MFMA), packed-bf16 a2 LDS (17.4 KB), packed epilogue, segmented reduce.
__global__ __launch_bounds__(256) void conv2_mfma_kernel(
    const float* __restrict__ h2, const int2* __restrict__ sds,
    const float* __restrict__ w1, const float* __restrict__ b1,
    const float* __restrict__ w2, const float* __restrict__ b2,
    const float* __restrict__ w3, const float* __restrict__ b3,
    float* __restrict__ sum2)
{
    __shared__ unsigned a2lds[4][64 * 17];
    int tid = threadIdx.x;
    int wave = tid >> 6, lane = tid & 63;
    int kg = lane >> 4, fr = lane & 15;
    unsigned* lds = &a2lds[wave][0];
    const float2* h2v = reinterpret_cast<const float2*>(h2);

    float al0[8], al1[8], be0[8], be1[8], b1v[8];
    #pragma unroll
    for (int i = 0; i < 8; i++) {
        int k = kg * 8 + i;
        float c0a = w1[k], c1a = w1[32 + k];
        float c0b = w1[64 + k], c1b = w1[96 + k];
        al0[i] = c0a - c0b; al1[i] = c1a - c1b;
        be0[i] = c0b; be1[i] = c1b;
        b1v[i] = b1[k];
    }
    short8 bhi0, blo0, bhi1, blo1;
    #pragma unroll
    for (int i = 0; i < 8; i++) {
        int k = kg * 8 + i;
        float w0 = w2[k * 32 + fr];
        float w1c = w2[k * 32 + fr + 16];
        unsigned short h0 = bf16_rne(w0);
        bhi0[i] = (short)h0; blo0[i] = (short)bf16_rne(w0 - bf16_f32(h0));
        unsigned short h1 = bf16_rne(w1c);
        bhi1[i] = (short)h1; blo1[i] = (short)bf16_rne(w1c - bf16_f32(h1));
    }
    float b2v0 = b2[fr], b2v1 = b2[fr + 16];

    int g = blockIdx.x * 4 + wave;
    if (g >= NGROUPS) return;
    int base = g * 64;
    int2 p0 = sds[base + fr], p1 = sds[base + 16 + fr];
    int2 p2 = sds[base + 32 + fr], p3 = sds[base + 48 + fr];
    float2 yd0 = h2v[p0.x], ys0 = h2v[p0.y];
    float2 yd1 = h2v[p1.x], ys1 = h2v[p1.y];
    float2 yd2 = h2v[p2.x], ys2 = h2v[p2.y];
    float2 yd3 = h2v[p3.x], ys3 = h2v[p3.y];

    while (true) {
        int gn = g + GSTRIDE;
        bool hn = gn < NGROUPS;
        int basen = gn * 64;
        int2 q0, q1, q2, q3;
        if (hn) {
            q0 = sds[basen + fr];      q1 = sds[basen + 16 + fr];
            q2 = sds[basen + 32 + fr]; q3 = sds[basen + 48 + fr];
        }

        #pragma unroll
        for (int t = 0; t < 4; t++) {
            float2 yd = t == 0 ? yd0 : t == 1 ? yd1 : t == 2 ? yd2 : yd3;
            float2 ys = t == 0 ? ys0 : t == 1 ? ys1 : t == 2 ? ys2 : ys3;
            float a[8];
            #pragma unroll
            for (int i = 0; i < 8; i++) {
                float pre = b1v[i];
                pre = fmaf(al0[i], yd.x, pre);
                pre = fmaf(al1[i], yd.y, pre);
                pre = fmaf(be0[i], ys.x, pre);
                pre = fmaf(be1[i], ys.y, pre);
                a[i] = fmaxf(pre, 0.f);
            }
            PackU pu;
            #pragma unroll
            for (int j = 0; j < 4; j++) pu.u[j] = cvtpk_bf16(a[2*j], a[2*j+1]);
            short8 ahi = pu.s;

            f32x4 acc0 = {0.f, 0.f, 0.f, 0.f}, acc1 = {0.f, 0.f, 0.f, 0.f};
            acc0 = __builtin_amdgcn_mfma_f32_16x16x32_bf16(ahi, blo0, acc0, 0, 0, 0);
            acc0 = __builtin_amdgcn_mfma_f32_16x16x32_bf16(ahi, bhi0, acc0, 0, 0, 0);
            acc1 = __builtin_amdgcn_mfma_f32_16x16x32_bf16(ahi, blo1, acc1, 0, 0, 0);
            acc1 = __builtin_amdgcn_mfma_f32_16x16x32_bf16(ahi, bhi1, acc1, 0, 0, 0);
            #pragma unroll
            for (int r = 0; r < 4; r++) {
                int er = t * 16 + kg * 4 + r;
                float a20 = fmaxf(acc0[r] + b2v0, 0.f);
                float a21 = fmaxf(acc1[r] + b2v1, 0.f);
                lds[er * 17 + fr] = cvtpk_bf16(a20, a21);
            }
        }

        if (hn) {
            yd0 = h2v[q0.x]; ys0 = h2v[q0.y];
            yd1 = h2v[q1.x]; ys1 = h2v[q1.y];
            yd2 = h2v[q2.x]; ys2 = h2v[q2.y];
            yd3 = h2v[q3.x]; ys3 = h2v[q3.y];
        }

        asm volatile("s_waitcnt lgkmcnt(0)" ::: "memory");

        float o0 = b3[0], o1 = b3[1], o2 = b3[2], o3 = b3[3];
        #pragma unroll
        for (int j = 0; j < 16; j++) {
            unsigned u = lds[lane * 17 + j];
            float flo = __uint_as_float(u << 16);            // feature j
            float fhi = __uint_as_float(u & 0xffff0000u);    // feature j+16
            o0 = fmaf(flo, w3[4 * j],     o0);
            o1 = fmaf(flo, w3[4 * j + 1], o1);
            o2 = fmaf(flo, w3[4 * j + 2], o2);
            o3 = fmaf(flo, w3[4 * j + 3], o3);
            o0 = fmaf(fhi, w3[4 * (j + 16)],     o0);
            o1 = fmaf(fhi, w3[4 * (j + 16) + 1], o1);
            o2 = fmaf(fhi, w3[4 * (j + 16) + 2], o2);
            o3 = fmaf(fhi, w3[4 * (j + 16) + 3], o3);
        }

        int d = kg == 0 ? p0.x : kg == 1 ? p1.x : kg == 2 ? p2.x : p3.x;
        int dprev = __shfl_up(d, 1);
        int dnext = __shfl_down(d, 1);
        bool head = (lane == 0) || (d != dprev);
        bool tail = (lane == 63) || (d != dnext);
        unsigned long long hb = __ballot(head);
        unsigned long long msk = (lane == 63) ? ~0ull : ((1ull << (lane + 1)) - 1ull);
        int seg0 = 63 - __clzll(hb & msk);
        #pragma unroll
        for (int st = 1; st < 64; st <<= 1) {
            float u0 = __shfl_up(o0, st);
            float u1 = __shfl_up(o1, st);
            float u2 = __shfl_up(o2, st);
            float u3 = __shfl_up(o3, st);
            if (lane - st >= seg0) { o0 += u0; o1 += u1; o2 += u2; o3 += u3; }
        }
        if (tail) {
            atomicAdd(&sum2[4 * d],     o0);
            atomicAdd(&sum2[4 * d + 1], o1);
            atomicAdd(&sum2[4 * d + 2], o2);
            atomicAdd(&sum2[4 * d + 3], o3);
        }

        if (!hn) break;
        p0 = q0; p1 = q1; p2 = q2; p3 = q3; g = gn;
    }
}

__global__ void div2_kernel(const float* __restrict__ sum2, const int* __restrict__ cnt,
                            float* __restrict__ out) {
    int i = blockIdx.x * 256 + threadIdx.x;
    if (i >= N_NODES) return;
    float c = fmaxf((float)cnt[i], 1.f);
    float4 s = reinterpret_cast<const float4*>(sum2)[i];
    reinterpret_cast<float4*>(out)[i] = make_float4(s.x/c, s.y/c, s.z/c, s.w/c);
}

extern "C" void kernel_launch(void* const* d_in, const int* in_sizes, int n_in,
                              void* d_out, int out_size, void* d_ws, size_t ws_size,
                              hipStream_t stream) {
    const float* x        = (const float*)d_in[0];
    const int*   ei       = (const int*)  d_in[1];
    const float* bn_gamma = (const float*)d_in[2];
    const float* bn_beta  = (const float*)d_in[3];
    const float* enc_w1   = (const float*)d_in[4];
    const float* enc_b1   = (const float*)d_in[5];
    const float* enc_w2   = (const float*)d_in[6];
    const float* enc_b2   = (const float*)d_in[7];
    const float* enc_w3   = (const float*)d_in[8];
    const float* enc_b3   = (const float*)d_in[9];
    const float* dec_w1   = (const float*)d_in[10];
    const float* dec_b1   = (const float*)d_in[11];
    const float* dec_w2   = (const float*)d_in[12];
    const float* dec_b2   = (const float*)d_in[13];
    const float* dec_w3   = (const float*)d_in[14];
    const float* dec_b3   = (const float*)d_in[15];

    float* wsf    = (float*)d_ws;
    int*   wsi    = (int*)d_ws;
    float* stats  = wsf + O_STATS;
    int*   bktcnt = wsi + O_BKTCNT;
    int*   bktctr = wsi + O_BKTCTR;
    float* sum1   = wsf + O_SUM1;
    float* sum2   = wsf + O_SUM2;
    int*   bktbase= wsi + O_BKTBASE;
    int*   cnt    = wsi + O_CNT;
    int2*  sbk    = (int2*)(wsi + O_SBK);
    int2*  sds    = (int2*)(wsi + O_SDS);
    float* h      = wsf + O_H;
    float* h2     = wsf + O_H2;
    float* out    = (float*)d_out;

    hipMemsetAsync(d_ws, 0, (size_t)ZERO_WORDS * sizeof(float), stream);

    const int nodeBlocks = (N_NODES + 255) / 256;

    bn_stats_kernel<<<STATS_BLOCKS, 256, 0, stream>>>(x, stats);
    bn_apply_kernel<<<nodeBlocks, 256, 0, stream>>>(x, stats, bn_gamma, bn_beta, h);
    bucket_count_kernel<<<SCAT_BLOCKS, 256, 0, stream>>>(ei, bktcnt);
    bucket_scan_kernel<<<1, 256, 0, stream>>>(bktcnt, bktbase);
    scatter_kernel<<<SCAT_BLOCKS, 256, 0, stream>>>(ei, bktbase, bktctr, sbk);
    fine_rank_kernel<<<NBKT, 512, 0, stream>>>(sbk, bktbase, bktcnt, sds, cnt);
    conv1_mfma_kernel<<<CONV_BLOCKS, 256, 0, stream>>>(h, sds,
                                                       enc_w1, enc_b1, enc_w2, enc_b2,
                                                       enc_w3, enc_b3, sum1);
    div1_kernel<<<nodeBlocks, 256, 0, stream>>>(sum1, cnt, h2);
    conv2_mfma_kernel<<<CONV_BLOCKS, 256, 0, stream>>>(h2, sds,
                                                       dec_w1, dec_b1, dec_w2, dec_b2,
                                                       dec_w3, dec_b3, sum2);
    div2_kernel<<<nodeBlocks, 256, 0, stream>>>(sum2, cnt, out);
}

// Round 19
// 227.113 us; speedup vs baseline: 1.9586x; 1.1508x over previous
//
#include <hip/hip_runtime.h>

#define N_NODES 100000
#define N_EDGES 3200000
#define BN_EPS 1e-5f
#define STATS_BLOCKS 64
#define CONV_BLOCKS 2048
#define NGROUPS (N_EDGES / 64)        // 50000
#define GSTRIDE (CONV_BLOCKS * 4)     // 8192
#define NBKT 196                      // ceil(100000/512)
#define BKT_CAP 18432                 // mean 16384, sigma ~127 -> +16 sigma
#define SCAT_BLOCKS 1024
#define EDGES_PER_SCAT (N_EDGES / SCAT_BLOCKS)   // 3125

typedef __attribute__((ext_vector_type(8))) short short8;
typedef __attribute__((ext_vector_type(4))) float f32x4;
typedef __attribute__((ext_vector_type(4))) unsigned int uint32x4;

// workspace layout (4-byte units). Front section is zeroed each call.
constexpr int O_STATS   = 0;                         // 8 f
constexpr int O_BKTCTR  = 8;                         // 256 int (zeroed)
constexpr int O_SUM1    = 264;                       // 2N f
constexpr int O_SUM2    = O_SUM1 + 2 * N_NODES;      // 4N f
constexpr int ZERO_WORDS = O_SUM2 + 4 * N_NODES;     // 264 + 6N
constexpr int O_BKTBASE = ZERO_WORDS;                // 256 int
constexpr int O_CNT     = O_BKTBASE + 256;           // N int
constexpr int O_SBK     = O_CNT + N_NODES;           // NBKT*BKT_CAP int2
constexpr int O_SDS     = O_SBK + 2 * NBKT * BKT_CAP; // 2E int (dst,src grouped)
constexpr int O_H       = O_SDS + 2 * N_EDGES;       // 4N f
constexpr int O_H2      = O_H + 4 * N_NODES;         // 2N f

__device__ __forceinline__ unsigned short bf16_rne(float f) {
    unsigned u = __float_as_uint(f);
    unsigned r = (u + 0x7fff + ((u >> 16) & 1)) >> 16;
    return (unsigned short)r;
}
__device__ __forceinline__ float bf16_f32(unsigned short h) {
    return __uint_as_float(((unsigned)h) << 16);
}
__device__ __forceinline__ unsigned cvtpk_bf16(float a, float b) {
    unsigned r;
    asm("v_cvt_pk_bf16_f32 %0, %1, %2" : "=v"(r) : "v"(a), "v"(b));
    return r;
}
union PackU { uint32x4 u; short8 s; };

__global__ __launch_bounds__(256) void bn_stats_kernel(const float* __restrict__ x,
                                                       float* __restrict__ stats) {
    __shared__ float red[4][8];
    int tid = threadIdx.x;
    float s0=0.f,s1=0.f,s2=0.f,s3=0.f,q0=0.f,q1=0.f,q2=0.f,q3=0.f;
    for (int i = blockIdx.x * 256 + tid; i < N_NODES; i += STATS_BLOCKS * 256) {
        float4 v = reinterpret_cast<const float4*>(x)[i];
        s0+=v.x; s1+=v.y; s2+=v.z; s3+=v.w;
        q0=fmaf(v.x,v.x,q0); q1=fmaf(v.y,v.y,q1); q2=fmaf(v.z,v.z,q2); q3=fmaf(v.w,v.w,q3);
    }
    #pragma unroll
    for (int off = 32; off > 0; off >>= 1) {
        s0 += __shfl_down(s0, off); s1 += __shfl_down(s1, off);
        s2 += __shfl_down(s2, off); s3 += __shfl_down(s3, off);
        q0 += __shfl_down(q0, off); q1 += __shfl_down(q1, off);
        q2 += __shfl_down(q2, off); q3 += __shfl_down(q3, off);
    }
    int wave = tid >> 6, lane = tid & 63;
    if (lane == 0) {
        red[wave][0]=s0; red[wave][1]=s1; red[wave][2]=s2; red[wave][3]=s3;
        red[wave][4]=q0; red[wave][5]=q1; red[wave][6]=q2; red[wave][7]=q3;
    }
    __syncthreads();
    if (tid < 8) {
        float v = red[0][tid] + red[1][tid] + red[2][tid] + red[3][tid];
        atomicAdd(&stats[tid], v);
    }
}

__global__ void bn_apply_kernel(const float* __restrict__ x,
                                const float* __restrict__ stats,
                                const float* __restrict__ gamma,
                                const float* __restrict__ beta,
                                float* __restrict__ h) {
    int i = blockIdx.x * blockDim.x + threadIdx.x;
    if (i >= N_NODES) return;
    const float inv_n = 1.0f / (float)N_NODES;
    float m0 = stats[0]*inv_n, m1 = stats[1]*inv_n, m2 = stats[2]*inv_n, m3 = stats[3]*inv_n;
    float sc0 = rsqrtf(stats[4]*inv_n - m0*m0 + BN_EPS) * gamma[0];
    float sc1 = rsqrtf(stats[5]*inv_n - m1*m1 + BN_EPS) * gamma[1];
    float sc2 = rsqrtf(stats[6]*inv_n - m2*m2 + BN_EPS) * gamma[2];
    float sc3 = rsqrtf(stats[7]*inv_n - m3*m3 + BN_EPS) * gamma[3];
    float4 v = reinterpret_cast<const float4*>(x)[i];
    float4 o;
    o.x = (v.x - m0) * sc0 + beta[0];
    o.y = (v.y - m1) * sc1 + beta[1];
    o.z = (v.z - m2) * sc2 + beta[2];
    o.w = (v.w - m3) * sc3 + beta[3];
    reinterpret_cast<float4*>(h)[i] = o;
}

// single-pass scatter into fixed-capacity buckets (no pre-count pass).
// dcache holds this block's dst values between phases.
__global__ __launch_bounds__(256) void scatter_kernel(const int* __restrict__ ei,
                                                      int* __restrict__ bktctr,
                                                      int2* __restrict__ sbk) {
    __shared__ int dcache[EDGES_PER_SCAT];
    __shared__ int lh[256], lbase[256], lctr[256];
    int t = threadIdx.x;
    lh[t] = 0; lctr[t] = 0;
    __syncthreads();
    int start = blockIdx.x * EDGES_PER_SCAT;
    for (int k = t; k < EDGES_PER_SCAT; k += 256) {
        int d = ei[N_EDGES + start + k];
        dcache[k] = d;
        atomicAdd(&lh[d >> 9], 1);
    }
    __syncthreads();
    int v = lh[t];
    if (v) lbase[t] = t * BKT_CAP + atomicAdd(&bktctr[t], v);
    __syncthreads();
    for (int k = t; k < EDGES_PER_SCAT; k += 256) {
        int d = dcache[k];
        int s = ei[start + k];
        int b = d >> 9;
        int r = atomicAdd(&lctr[b], 1);
        sbk[lbase[b] + r] = make_int2(d, s);
    }
}

// exclusive scan of actual bucket counts -> dense output offsets
__global__ void ctr_scan_kernel(const int* __restrict__ bktctr, int* __restrict__ bktbase) {
    __shared__ int sd[256];
    int t = threadIdx.x;
    int v = bktctr[t];
    sd[t] = v; __syncthreads();
    for (int o = 1; o < 256; o <<= 1) {
        int x = (t >= o) ? sd[t - o] : 0;
        __syncthreads();
        sd[t] += x;
        __syncthreads();
    }
    bktbase[t] = sd[t] - v;
}

// per-bucket fine grouping: reads from b*BKT_CAP, writes dense dst-grouped sds.
__global__ __launch_bounds__(512) void fine_rank_kernel(const int2* __restrict__ sbk,
                                                        const int* __restrict__ bktctr,
                                                        const int* __restrict__ bktbase,
                                                        int2* __restrict__ sds,
                                                        int* __restrict__ cnt) {
    __shared__ int hist[512], scanv[512], ctr[512];
    int b = blockIdx.x;
    int t = threadIdx.x;
    int ibase = b * BKT_CAP;
    int obase = bktbase[b];
    int ecount = bktctr[b];
    hist[t] = 0; ctr[t] = 0;
    __syncthreads();
    for (int i = t; i < ecount; i += 512) {
        int d = sbk[ibase + i].x;
        atomicAdd(&hist[d & 511], 1);
    }
    __syncthreads();
    int v = hist[t];
    scanv[t] = v;
    __syncthreads();
    for (int o = 1; o < 512; o <<= 1) {
        int x = (t >= o) ? scanv[t - o] : 0;
        __syncthreads();
        scanv[t] += x;
        __syncthreads();
    }
    int excl = scanv[t] - v;
    int node = (b << 9) + t;
    if (node < N_NODES) cnt[node] = v;
    __syncthreads();
    hist[t] = excl;
    __syncthreads();
    for (int i = t; i < ecount; i += 512) {
        int2 de = sbk[ibase + i];
        int ld = de.x & 511;
        int r = atomicAdd(&ctr[ld], 1);
        sds[obase + hist[ld] + r] = de;
    }
}

// conv1 fused with aggregation (unchanged from r18)
__global__ __launch_bounds__(256) void conv1_mfma_kernel(
    const float* __restrict__ h, const int2* __restrict__ sds,
    const float* __restrict__ w1, const float* __restrict__ b1,
    const float* __restrict__ w2, const float* __restrict__ b2,
    const float* __restrict__ w3, const float* __restrict__ b3,
    float* __restrict__ sum1)
{
    __shared__ unsigned a2lds[4][64 * 17];
    int tid = threadIdx.x;
    int wave = tid >> 6, lane = tid & 63;
    int kg = lane >> 4, fr = lane & 15;
    unsigned* lds = &a2lds[wave][0];
    const float4* h4 = reinterpret_cast<const float4*>(h);

    float al[4][8], be[4][8], b1v[8];
    #pragma unroll
    for (int i = 0; i < 8; i++) {
        int k = kg * 8 + i;
        #pragma unroll
        for (int c = 0; c < 4; c++) {
            float wa = w1[c * 32 + k];
            float wb = w1[(4 + c) * 32 + k];
            al[c][i] = wa - wb;
            be[c][i] = wb;
        }
        b1v[i] = b1[k];
    }
    short8 bhi0, blo0, bhi1, blo1;
    #pragma unroll
    for (int i = 0; i < 8; i++) {
        int k = kg * 8 + i;
        float w0 = w2[k * 32 + fr];
        float w1c = w2[k * 32 + fr + 16];
        unsigned short h0 = bf16_rne(w0);
        bhi0[i] = (short)h0; blo0[i] = (short)bf16_rne(w0 - bf16_f32(h0));
        unsigned short h1 = bf16_rne(w1c);
        bhi1[i] = (short)h1; blo1[i] = (short)bf16_rne(w1c - bf16_f32(h1));
    }
    float b2v0 = b2[fr], b2v1 = b2[fr + 16];

    int g = blockIdx.x * 4 + wave;
    if (g >= NGROUPS) return;

    int base = g * 64;
    int2 p0 = sds[base + fr], p1 = sds[base + 16 + fr];
    int2 p2 = sds[base + 32 + fr], p3 = sds[base + 48 + fr];
    float4 xi0 = h4[p0.x], xj0 = h4[p0.y];
    float4 xi1 = h4[p1.x], xj1 = h4[p1.y];
    float4 xi2 = h4[p2.x], xj2 = h4[p2.y];
    float4 xi3 = h4[p3.x], xj3 = h4[p3.y];

    while (true) {
        int gn = g + GSTRIDE;
        bool hn = gn < NGROUPS;
        int basen = gn * 64;
        int2 q0, q1, q2, q3;
        if (hn) {
            q0 = sds[basen + fr];      q1 = sds[basen + 16 + fr];
            q2 = sds[basen + 32 + fr]; q3 = sds[basen + 48 + fr];
        }

        #pragma unroll
        for (int t = 0; t < 4; t++) {
            float4 xi = t == 0 ? xi0 : t == 1 ? xi1 : t == 2 ? xi2 : xi3;
            float4 xj = t == 0 ? xj0 : t == 1 ? xj1 : t == 2 ? xj2 : xj3;
            float a[8];
            #pragma unroll
            for (int i = 0; i < 8; i++) {
                float pre = b1v[i];
                pre = fmaf(al[0][i], xi.x, pre);
                pre = fmaf(al[1][i], xi.y, pre);
                pre = fmaf(al[2][i], xi.z, pre);
                pre = fmaf(al[3][i], xi.w, pre);
                pre = fmaf(be[0][i], xj.x, pre);
                pre = fmaf(be[1][i], xj.y, pre);
                pre = fmaf(be[2][i], xj.z, pre);
                pre = fmaf(be[3][i], xj.w, pre);
                a[i] = fmaxf(pre, 0.f);
            }
            PackU pu;
            #pragma unroll
            for (int j = 0; j < 4; j++) pu.u[j] = cvtpk_bf16(a[2*j], a[2*j+1]);
            short8 ahi = pu.s;

            f32x4 acc0 = {0.f, 0.f, 0.f, 0.f}, acc1 = {0.f, 0.f, 0.f, 0.f};
            acc0 = __builtin_amdgcn_mfma_f32_16x16x32_bf16(ahi, blo0, acc0, 0, 0, 0);
            acc0 = __builtin_amdgcn_mfma_f32_16x16x32_bf16(ahi, bhi0, acc0, 0, 0, 0);
            acc1 = __builtin_amdgcn_mfma_f32_16x16x32_bf16(ahi, blo1, acc1, 0, 0, 0);
            acc1 = __builtin_amdgcn_mfma_f32_16x16x32_bf16(ahi, bhi1, acc1, 0, 0, 0);
            #pragma unroll
            for (int r = 0; r < 4; r++) {
                int er = t * 16 + kg * 4 + r;
                float a20 = fmaxf(acc0[r] + b2v0, 0.f);
                float a21 = fmaxf(acc1[r] + b2v1, 0.f);
                lds[er * 17 + fr] = cvtpk_bf16(a20, a21);
            }
        }

        if (hn) {
            xi0 = h4[q0.x]; xj0 = h4[q0.y];
            xi1 = h4[q1.x]; xj1 = h4[q1.y];
            xi2 = h4[q2.x]; xj2 = h4[q2.y];
            xi3 = h4[q3.x]; xj3 = h4[q3.y];
        }

        asm volatile("s_waitcnt lgkmcnt(0)" ::: "memory");

        float m0 = b3[0], m1 = b3[1];
        #pragma unroll
        for (int j = 0; j < 16; j++) {
            unsigned u = lds[lane * 17 + j];
            float flo = __uint_as_float(u << 16);
            float fhi = __uint_as_float(u & 0xffff0000u);
            m0 = fmaf(flo, w3[2 * j],        m0);
            m1 = fmaf(flo, w3[2 * j + 1],    m1);
            m0 = fmaf(fhi, w3[2 * (j + 16)],     m0);
            m1 = fmaf(fhi, w3[2 * (j + 16) + 1], m1);
        }
        m0 = fmaxf(m0, 0.f); m1 = fmaxf(m1, 0.f);

        int d = kg == 0 ? p0.x : kg == 1 ? p1.x : kg == 2 ? p2.x : p3.x;
        int dprev = __shfl_up(d, 1);
        int dnext = __shfl_down(d, 1);
        bool head = (lane == 0) || (d != dprev);
        bool tail = (lane == 63) || (d != dnext);
        unsigned long long hb = __ballot(head);
        unsigned long long msk = (lane == 63) ? ~0ull : ((1ull << (lane + 1)) - 1ull);
        int seg0 = 63 - __clzll(hb & msk);
        #pragma unroll
        for (int st = 1; st < 64; st <<= 1) {
            float u0 = __shfl_up(m0, st);
            float u1 = __shfl_up(m1, st);
            if (lane - st >= seg0) { m0 += u0; m1 += u1; }
        }
        if (tail) {
            atomicAdd(&sum1[2 * d],     m0);
            atomicAdd(&sum1[2 * d + 1], m1);
        }

        if (!hn) break;
        p0 = q0; p1 = q1; p2 = q2; p3 = q3; g = gn;
    }
}

__global__ void div1_kernel(const float* __restrict__ sum1, const int* __restrict__ cnt,
                            float* __restrict__ h2) {
    int i = blockIdx.x * 256 + threadIdx.x;
    if (i >= N_NODES) return;
    float c = fmaxf((float)cnt[i], 1.f);
    float2 s = reinterpret_cast<const float2*>(sum1)[i];
    reinterpret_cast<float2*>(h2)[i] = make_float2(s.x / c, s.y / c);
}

// conv2 fused with aggregation (unchanged from r18)
__global__ __launch_bounds__(256) void conv2_mfma_kernel(
    const float* __restrict__ h2, const int2* __restrict__ sds,
    const float* __restrict__ w1, const float* __restrict__ b1,
    const float* __restrict__ w2, const float* __restrict__ b2,
    const float* __restrict__ w3, const float* __restrict__ b3,
    float* __restrict__ sum2)
{
    __shared__ unsigned a2lds[4][64 * 17];
    int tid = threadIdx.x;
    int wave = tid >> 6, lane = tid & 63;
    int kg = lane >> 4, fr = lane & 15;
    unsigned* lds = &a2lds[wave][0];
    const float2* h2v = reinterpret_cast<const float2*>(h2);

    float al0[8], al1[8], be0[8], be1[8], b1v[8];
    #pragma unroll
    for (int i = 0; i < 8; i++) {
        int k = kg * 8 + i;
        float c0a = w1[k], c1a = w1[32 + k];
        float c0b = w1[64 + k], c1b = w1[96 + k];
        al0[i] = c0a - c0b; al1[i] = c1a - c1b;
        be0[i] = c0b; be1[i] = c1b;
        b1v[i] = b1[k];
    }
    short8 bhi0, blo0, bhi1, blo1;
    #pragma unroll
    for (int i = 0; i < 8; i++) {
        int k = kg * 8 + i;
        float w0 = w2[k * 32 + fr];
        float w1c = w2[k * 32 + fr + 16];
        unsigned short h0 = bf16_rne(w0);
        bhi0[i] = (short)h0; blo0[i] = (short)bf16_rne(w0 - bf16_f32(h0));
        unsigned short h1 = bf16_rne(w1c);
        bhi1[i] = (short)h1; blo1[i] = (short)bf16_rne(w1c - bf16_f32(h1));
    }
    float b2v0 = b2[fr], b2v1 = b2[fr + 16];

    int g = blockIdx.x * 4 + wave;
    if (g >= NGROUPS) return;
    int base = g * 64;
    int2 p0 = sds[base + fr], p1 = sds[base + 16 + fr];
    int2 p2 = sds[base + 32 + fr], p3 = sds[base + 48 + fr];
    float2 yd0 = h2v[p0.x], ys0 = h2v[p0.y];
    float2 yd1 = h2v[p1.x], ys1 = h2v[p1.y];
    float2 yd2 = h2v[p2.x], ys2 = h2v[p2.y];
    float2 yd3 = h2v[p3.x], ys3 = h2v[p3.y];

    while (true) {
        int gn = g + GSTRIDE;
        bool hn = gn < NGROUPS;
        int basen = gn * 64;
        int2 q0, q1, q2, q3;
        if (hn) {
            q0 = sds[basen + fr];      q1 = sds[basen + 16 + fr];
            q2 = sds[basen + 32 + fr]; q3 = sds[basen + 48 + fr];
        }

        #pragma unroll
        for (int t = 0; t < 4; t++) {
            float2 yd = t == 0 ? yd0 : t == 1 ? yd1 : t == 2 ? yd2 : yd3;
            float2 ys = t == 0 ? ys0 : t == 1 ? ys1 : t == 2 ? ys2 : ys3;
            float a[8];
            #pragma unroll
            for (int i = 0; i < 8; i++) {
                float pre = b1v[i];
                pre = fmaf(al0[i], yd.x, pre);
                pre = fmaf(al1[i], yd.y, pre);
                pre = fmaf(be0[i], ys.x, pre);
                pre = fmaf(be1[i], ys.y, pre);
                a[i] = fmaxf(pre, 0.f);
            }
            PackU pu;
            #pragma unroll
            for (int j = 0; j < 4; j++) pu.u[j] = cvtpk_bf16(a[2*j], a[2*j+1]);
            short8 ahi = pu.s;

            f32x4 acc0 = {0.f, 0.f, 0.f, 0.f}, acc1 = {0.f, 0.f, 0.f, 0.f};
            acc0 = __builtin_amdgcn_mfma_f32_16x16x32_bf16(ahi, blo0, acc0, 0, 0, 0);
            acc0 = __builtin_amdgcn_mfma_f32_16x16x32_bf16(ahi, bhi0, acc0, 0, 0, 0);
            acc1 = __builtin_amdgcn_mfma_f32_16x16x32_bf16(ahi, blo1, acc1, 0, 0, 0);
            acc1 = __builtin_amdgcn_mfma_f32_16x16x32_bf16(ahi, bhi1, acc1, 0, 0, 0);
            #pragma unroll
            for (int r = 0; r < 4; r++) {
                int er = t * 16 + kg * 4 + r;
                float a20 = fmaxf(acc0[r] + b2v0, 0.f);
                float a21 = fmaxf(acc1[r] + b2v1, 0.f);
                lds[er * 17 + fr] = cvtpk_bf16(a20, a21);
            }
        }

        if (hn) {
            yd0 = h2v[q0.x]; ys0 = h2v[q0.y];
            yd1 = h2v[q1.x]; ys1 = h2v[q1.y];
            yd2 = h2v[q2.x]; ys2 = h2v[q2.y];
            yd3 = h2v[q3.x]; ys3 = h2v[q3.y];
        }

        asm volatile("s_waitcnt lgkmcnt(0)" ::: "memory");

        float o0 = b3[0], o1 = b3[1], o2 = b3[2], o3 = b3[3];
        #pragma unroll
        for (int j = 0; j < 16; j++) {
            unsigned u = lds[lane * 17 + j];
            float flo = __uint_as_float(u << 16);
            float fhi = __uint_as_float(u & 0xffff0000u);
            o0 = fmaf(flo, w3[4 * j],     o0);
            o1 = fmaf(flo, w3[4 * j + 1], o1);
            o2 = fmaf(flo, w3[4 * j + 2], o2);
            o3 = fmaf(flo, w3[4 * j + 3], o3);
            o0 = fmaf(fhi, w3[4 * (j + 16)],     o0);
            o1 = fmaf(fhi, w3[4 * (j + 16) + 1], o1);
            o2 = fmaf(fhi, w3[4 * (j + 16) + 2], o2);
            o3 = fmaf(fhi, w3[4 * (j + 16) + 3], o3);
        }

        int d = kg == 0 ? p0.x : kg == 1 ? p1.x : kg == 2 ? p2.x : p3.x;
        int dprev = __shfl_up(d, 1);
        int dnext = __shfl_down(d, 1);
        bool head = (lane == 0) || (d != dprev);
        bool tail = (lane == 63) || (d != dnext);
        unsigned long long hb = __ballot(head);
        unsigned long long msk = (lane == 63) ? ~0ull : ((1ull << (lane + 1)) - 1ull);
        int seg0 = 63 - __clzll(hb & msk);
        #pragma unroll
        for (int st = 1; st < 64; st <<= 1) {
            float u0 = __shfl_up(o0, st);
            float u1 = __shfl_up(o1, st);
            float u2 = __shfl_up(o2, st);
            float u3 = __shfl_up(o3, st);
            if (lane - st >= seg0) { o0 += u0; o1 += u1; o2 += u2; o3 += u3; }
        }
        if (tail) {
            atomicAdd(&sum2[4 * d],     o0);
            atomicAdd(&sum2[4 * d + 1], o1);
            atomicAdd(&sum2[4 * d + 2], o2);
            atomicAdd(&sum2[4 * d + 3], o3);
        }

        if (!hn) break;
        p0 = q0; p1 = q1; p2 = q2; p3 = q3; g = gn;
    }
}

__global__ void div2_kernel(const float* __restrict__ sum2, const int* __restrict__ cnt,
                            float* __restrict__ out) {
    int i = blockIdx.x * 256 + threadIdx.x;
    if (i >= N_NODES) return;
    float c = fmaxf((float)cnt[i], 1.f);
    float4 s = reinterpret_cast<const float4*>(sum2)[i];
    reinterpret_cast<float4*>(out)[i] = make_float4(s.x/c, s.y/c, s.z/c, s.w/c);
}

extern "C" void kernel_launch(void* const* d_in, const int* in_sizes, int n_in,
                              void* d_out, int out_size, void* d_ws, size_t ws_size,
                              hipStream_t stream) {
    const float* x        = (const float*)d_in[0];
    const int*   ei       = (const int*)  d_in[1];
    const float* bn_gamma = (const float*)d_in[2];
    const float* bn_beta  = (const float*)d_in[3];
    const float* enc_w1   = (const float*)d_in[4];
    const float* enc_b1   = (const float*)d_in[5];
    const float* enc_w2   = (const float*)d_in[6];
    const float* enc_b2   = (const float*)d_in[7];
    const float* enc_w3   = (const float*)d_in[8];
    const float* enc_b3   = (const float*)d_in[9];
    const float* dec_w1   = (const float*)d_in[10];
    const float* dec_b1   = (const float*)d_in[11];
    const float* dec_w2   = (const float*)d_in[12];
    const float* dec_b2   = (const float*)d_in[13];
    const float* dec_w3   = (const float*)d_in[14];
    const float* dec_b3   = (const float*)d_in[15];

    float* wsf    = (float*)d_ws;
    int*   wsi    = (int*)d_ws;
    float* stats  = wsf + O_STATS;
    int*   bktctr = wsi + O_BKTCTR;
    float* sum1   = wsf + O_SUM1;
    float* sum2   = wsf + O_SUM2;
    int*   bktbase= wsi + O_BKTBASE;
    int*   cnt    = wsi + O_CNT;
    int2*  sbk    = (int2*)(wsi + O_SBK);
    int2*  sds    = (int2*)(wsi + O_SDS);
    float* h      = wsf + O_H;
    float* h2     = wsf + O_H2;
    float* out    = (float*)d_out;

    hipMemsetAsync(d_ws, 0, (size_t)ZERO_WORDS * sizeof(float), stream);

    const int nodeBlocks = (N_NODES + 255) / 256;

    bn_stats_kernel<<<STATS_BLOCKS, 256, 0, stream>>>(x, stats);
    bn_apply_kernel<<<nodeBlocks, 256, 0, stream>>>(x, stats, bn_gamma, bn_beta, h);
    scatter_kernel<<<SCAT_BLOCKS, 256, 0, stream>>>(ei, bktctr, sbk);
    ctr_scan_kernel<<<1, 256, 0, stream>>>(bktctr, bktbase);
    fine_rank_kernel<<<NBKT, 512, 0, stream>>>(sbk, bktctr, bktbase, sds, cnt);
    conv1_mfma_kernel<<<CONV_BLOCKS, 256, 0, stream>>>(h, sds,
                                                       enc_w1, enc_b1, enc_w2, enc_b2,
                                                       enc_w3, enc_b3, sum1);
    div1_kernel<<<nodeBlocks, 256, 0, stream>>>(sum1, cnt, h2);
    conv2_mfma_kernel<<<CONV_BLOCKS, 256, 0, stream>>>(h2, sds,
                                                       dec_w1, dec_b1, dec_w2, dec_b2,
                                                       dec_w3, dec_b3, sum2);
    div2_kernel<<<nodeBlocks, 256, 0, stream>>>(sum2, cnt, out);
}

// Round 20
// 218.700 us; speedup vs baseline: 2.0340x; 1.0385x over previous
//
#include <hip/hip_runtime.h>

#define N_NODES 100000
#define N_EDGES 3200000
#define BN_EPS 1e-5f
#define STATS_BLOCKS 64
#define CONV_BLOCKS 2048
#define NGROUPS (N_EDGES / 64)        // 50000
#define GSTRIDE (CONV_BLOCKS * 4)     // 8192
#define NBKT 196                      // ceil(100000/512)
#define BKT_CAP 18432                 // mean 16384, sigma ~127 -> +16 sigma
#define SCAT_BLOCKS 1024
#define EDGES_PER_SCAT (N_EDGES / SCAT_BLOCKS)   // 3125

typedef __attribute__((ext_vector_type(8))) short short8;
typedef __attribute__((ext_vector_type(4))) float f32x4;
typedef __attribute__((ext_vector_type(4))) unsigned int uint32x4;

// workspace layout (4-byte units). Front section is zeroed each call.
constexpr int O_STATS   = 0;                         // 8 f
constexpr int O_BKTCTR  = 8;                         // 256 int (zeroed)
constexpr int O_SUM1    = 264;                       // 2N f
constexpr int O_SUM2    = O_SUM1 + 2 * N_NODES;      // 4N f
constexpr int ZERO_WORDS = O_SUM2 + 4 * N_NODES;     // 264 + 6N
constexpr int O_BKTBASE = ZERO_WORDS;                // 256 int
constexpr int O_CNT     = O_BKTBASE + 256;           // N int
constexpr int O_SBK     = O_CNT + N_NODES;           // NBKT*BKT_CAP int2
constexpr int O_SDS     = O_SBK + 2 * NBKT * BKT_CAP; // 2E int (dst,src grouped)
constexpr int O_H       = O_SDS + 2 * N_EDGES;       // 4N f
constexpr int O_H2      = O_H + 4 * N_NODES;         // 2N f

__device__ __forceinline__ unsigned short bf16_rne(float f) {
    unsigned u = __float_as_uint(f);
    unsigned r = (u + 0x7fff + ((u >> 16) & 1)) >> 16;
    return (unsigned short)r;
}
__device__ __forceinline__ float bf16_f32(unsigned short h) {
    return __uint_as_float(((unsigned)h) << 16);
}
__device__ __forceinline__ unsigned cvtpk_bf16(float a, float b) {
    unsigned r;
    asm("v_cvt_pk_bf16_f32 %0, %1, %2" : "=v"(r) : "v"(a), "v"(b));
    return r;
}
union PackU { uint32x4 u; short8 s; };

__global__ __launch_bounds__(256) void bn_stats_kernel(const float* __restrict__ x,
                                                       float* __restrict__ stats) {
    __shared__ float red[4][8];
    int tid = threadIdx.x;
    float s0=0.f,s1=0.f,s2=0.f,s3=0.f,q0=0.f,q1=0.f,q2=0.f,q3=0.f;
    for (int i = blockIdx.x * 256 + tid; i < N_NODES; i += STATS_BLOCKS * 256) {
        float4 v = reinterpret_cast<const float4*>(x)[i];
        s0+=v.x; s1+=v.y; s2+=v.z; s3+=v.w;
        q0=fmaf(v.x,v.x,q0); q1=fmaf(v.y,v.y,q1); q2=fmaf(v.z,v.z,q2); q3=fmaf(v.w,v.w,q3);
    }
    #pragma unroll
    for (int off = 32; off > 0; off >>= 1) {
        s0 += __shfl_down(s0, off); s1 += __shfl_down(s1, off);
        s2 += __shfl_down(s2, off); s3 += __shfl_down(s3, off);
        q0 += __shfl_down(q0, off); q1 += __shfl_down(q1, off);
        q2 += __shfl_down(q2, off); q3 += __shfl_down(q3, off);
    }
    int wave = tid >> 6, lane = tid & 63;
    if (lane == 0) {
        red[wave][0]=s0; red[wave][1]=s1; red[wave][2]=s2; red[wave][3]=s3;
        red[wave][4]=q0; red[wave][5]=q1; red[wave][6]=q2; red[wave][7]=q3;
    }
    __syncthreads();
    if (tid < 8) {
        float v = red[0][tid] + red[1][tid] + red[2][tid] + red[3][tid];
        atomicAdd(&stats[tid], v);
    }
}

__global__ void bn_apply_kernel(const float* __restrict__ x,
                                const float* __restrict__ stats,
                                const float* __restrict__ gamma,
                                const float* __restrict__ beta,
                                float* __restrict__ h) {
    int i = blockIdx.x * blockDim.x + threadIdx.x;
    if (i >= N_NODES) return;
    const float inv_n = 1.0f / (float)N_NODES;
    float m0 = stats[0]*inv_n, m1 = stats[1]*inv_n, m2 = stats[2]*inv_n, m3 = stats[3]*inv_n;
    float sc0 = rsqrtf(stats[4]*inv_n - m0*m0 + BN_EPS) * gamma[0];
    float sc1 = rsqrtf(stats[5]*inv_n - m1*m1 + BN_EPS) * gamma[1];
    float sc2 = rsqrtf(stats[6]*inv_n - m2*m2 + BN_EPS) * gamma[2];
    float sc3 = rsqrtf(stats[7]*inv_n - m3*m3 + BN_EPS) * gamma[3];
    float4 v = reinterpret_cast<const float4*>(x)[i];
    float4 o;
    o.x = (v.x - m0) * sc0 + beta[0];
    o.y = (v.y - m1) * sc1 + beta[1];
    o.z = (v.z - m2) * sc2 + beta[2];
    o.w = (v.w - m3) * sc3 + beta[3];
    reinterpret_cast<float4*>(h)[i] = o;
}

// single-pass scatter with block-local counting sort in LDS -> coalesced writes.
__global__ __launch_bounds__(256) void scatter_kernel(const int* __restrict__ ei,
                                                      int* __restrict__ bktctr,
                                                      int2* __restrict__ sbk) {
    __shared__ int2 stage[EDGES_PER_SCAT];
    __shared__ int dcache[EDGES_PER_SCAT];
    __shared__ int lh[256], lpos[256], gbase[256], lctr[256];
    int t = threadIdx.x;
    lh[t] = 0; lctr[t] = 0;
    __syncthreads();
    int start = blockIdx.x * EDGES_PER_SCAT;
    for (int k = t; k < EDGES_PER_SCAT; k += 256) {
        int d = ei[N_EDGES + start + k];
        dcache[k] = d;
        atomicAdd(&lh[d >> 9], 1);
    }
    __syncthreads();
    // exclusive scan of lh -> lpos (local order base), reserve global range
    {
        int v = lh[t];
        int sv = v;
        __shared__ int sd[256];
        sd[t] = sv; __syncthreads();
        for (int o = 1; o < 256; o <<= 1) {
            int xx = (t >= o) ? sd[t - o] : 0;
            __syncthreads();
            sd[t] += xx;
            __syncthreads();
        }
        lpos[t] = sd[t] - v;
        if (v) gbase[t] = t * BKT_CAP + atomicAdd(&bktctr[t], v);
        __syncthreads();
    }
    // place into LDS stage ordered by bucket
    for (int k = t; k < EDGES_PER_SCAT; k += 256) {
        int d = dcache[k];
        int s = ei[start + k];
        int b = d >> 9;
        int r = atomicAdd(&lctr[b], 1);
        stage[lpos[b] + r] = make_int2(d, s);
    }
    __syncthreads();
    // stream out: consecutive k in same bucket -> consecutive global slots
    for (int k = t; k < EDGES_PER_SCAT; k += 256) {
        int2 v = stage[k];
        int b = v.x >> 9;
        sbk[gbase[b] + (k - lpos[b])] = v;
    }
}

// exclusive scan of actual bucket counts -> dense output offsets
__global__ void ctr_scan_kernel(const int* __restrict__ bktctr, int* __restrict__ bktbase) {
    __shared__ int sd[256];
    int t = threadIdx.x;
    int v = bktctr[t];
    sd[t] = v; __syncthreads();
    for (int o = 1; o < 256; o <<= 1) {
        int x = (t >= o) ? sd[t - o] : 0;
        __syncthreads();
        sd[t] += x;
        __syncthreads();
    }
    bktbase[t] = sd[t] - v;
}

// per-bucket fine grouping: reads from b*BKT_CAP, writes dense dst-grouped sds.
__global__ __launch_bounds__(512) void fine_rank_kernel(const int2* __restrict__ sbk,
                                                        const int* __restrict__ bktctr,
                                                        const int* __restrict__ bktbase,
                                                        int2* __restrict__ sds,
                                                        int* __restrict__ cnt) {
    __shared__ int hist[512], scanv[512], ctr[512];
    int b = blockIdx.x;
    int t = threadIdx.x;
    int ibase = b * BKT_CAP;
    int obase = bktbase[b];
    int ecount = bktctr[b];
    hist[t] = 0; ctr[t] = 0;
    __syncthreads();
    for (int i = t; i < ecount; i += 512) {
        int d = sbk[ibase + i].x;
        atomicAdd(&hist[d & 511], 1);
    }
    __syncthreads();
    int v = hist[t];
    scanv[t] = v;
    __syncthreads();
    for (int o = 1; o < 512; o <<= 1) {
        int x = (t >= o) ? scanv[t - o] : 0;
        __syncthreads();
        scanv[t] += x;
        __syncthreads();
    }
    int excl = scanv[t] - v;
    int node = (b << 9) + t;
    if (node < N_NODES) cnt[node] = v;
    __syncthreads();
    hist[t] = excl;
    __syncthreads();
    for (int i = t; i < ecount; i += 512) {
        int2 de = sbk[ibase + i];
        int ld = de.x & 511;
        int r = atomicAdd(&ctr[ld], 1);
        sds[obase + hist[ld] + r] = de;
    }
}

// conv1 fused with aggregation (unchanged)
__global__ __launch_bounds__(256) void conv1_mfma_kernel(
    const float* __restrict__ h, const int2* __restrict__ sds,
    const float* __restrict__ w1, const float* __restrict__ b1,
    const float* __restrict__ w2, const float* __restrict__ b2,
    const float* __restrict__ w3, const float* __restrict__ b3,
    float* __restrict__ sum1)
{
    __shared__ unsigned a2lds[4][64 * 17];
    int tid = threadIdx.x;
    int wave = tid >> 6, lane = tid & 63;
    int kg = lane >> 4, fr = lane & 15;
    unsigned* lds = &a2lds[wave][0];
    const float4* h4 = reinterpret_cast<const float4*>(h);

    float al[4][8], be[4][8], b1v[8];
    #pragma unroll
    for (int i = 0; i < 8; i++) {
        int k = kg * 8 + i;
        #pragma unroll
        for (int c = 0; c < 4; c++) {
            float wa = w1[c * 32 + k];
            float wb = w1[(4 + c) * 32 + k];
            al[c][i] = wa - wb;
            be[c][i] = wb;
        }
        b1v[i] = b1[k];
    }
    short8 bhi0, blo0, bhi1, blo1;
    #pragma unroll
    for (int i = 0; i < 8; i++) {
        int k = kg * 8 + i;
        float w0 = w2[k * 32 + fr];
        float w1c = w2[k * 32 + fr + 16];
        unsigned short h0 = bf16_rne(w0);
        bhi0[i] = (short)h0; blo0[i] = (short)bf16_rne(w0 - bf16_f32(h0));
        unsigned short h1 = bf16_rne(w1c);
        bhi1[i] = (short)h1; blo1[i] = (short)bf16_rne(w1c - bf16_f32(h1));
    }
    float b2v0 = b2[fr], b2v1 = b2[fr + 16];

    int g = blockIdx.x * 4 + wave;
    if (g >= NGROUPS) return;

    int base = g * 64;
    int2 p0 = sds[base + fr], p1 = sds[base + 16 + fr];
    int2 p2 = sds[base + 32 + fr], p3 = sds[base + 48 + fr];
    float4 xi0 = h4[p0.x], xj0 = h4[p0.y];
    float4 xi1 = h4[p1.x], xj1 = h4[p1.y];
    float4 xi2 = h4[p2.x], xj2 = h4[p2.y];
    float4 xi3 = h4[p3.x], xj3 = h4[p3.y];

    while (true) {
        int gn = g + GSTRIDE;
        bool hn = gn < NGROUPS;
        int basen = gn * 64;
        int2 q0, q1, q2, q3;
        if (hn) {
            q0 = sds[basen + fr];      q1 = sds[basen + 16 + fr];
            q2 = sds[basen + 32 + fr]; q3 = sds[basen + 48 + fr];
        }

        #pragma unroll
        for (int t = 0; t < 4; t++) {
            float4 xi = t == 0 ? xi0 : t == 1 ? xi1 : t == 2 ? xi2 : xi3;
            float4 xj = t == 0 ? xj0 : t == 1 ? xj1 : t == 2 ? xj2 : xj3;
            float a[8];
            #pragma unroll
            for (int i = 0; i < 8; i++) {
                float pre = b1v[i];
                pre = fmaf(al[0][i], xi.x, pre);
                pre = fmaf(al[1][i], xi.y, pre);
                pre = fmaf(al[2][i], xi.z, pre);
                pre = fmaf(al[3][i], xi.w, pre);
                pre = fmaf(be[0][i], xj.x, pre);
                pre = fmaf(be[1][i], xj.y, pre);
                pre = fmaf(be[2][i], xj.z, pre);
                pre = fmaf(be[3][i], xj.w, pre);
                a[i] = fmaxf(pre, 0.f);
            }
            PackU pu;
            #pragma unroll
            for (int j = 0; j < 4; j++) pu.u[j] = cvtpk_bf16(a[2*j], a[2*j+1]);
            short8 ahi = pu.s;

            f32x4 acc0 = {0.f, 0.f, 0.f, 0.f}, acc1 = {0.f, 0.f, 0.f, 0.f};
            acc0 = __builtin_amdgcn_mfma_f32_16x16x32_bf16(ahi, blo0, acc0, 0, 0, 0);
            acc0 = __builtin_amdgcn_mfma_f32_16x16x32_bf16(ahi, bhi0, acc0, 0, 0, 0);
            acc1 = __builtin_amdgcn_mfma_f32_16x16x32_bf16(ahi, blo1, acc1, 0, 0, 0);
            acc1 = __builtin_amdgcn_mfma_f32_16x16x32_bf16(ahi, bhi1, acc1, 0, 0, 0);
            #pragma unroll
            for (int r = 0; r < 4; r++) {
                int er = t * 16 + kg * 4 + r;
                float a20 = fmaxf(acc0[r] + b2v0, 0.f);
                float a21 = fmaxf(acc1[r] + b2v1, 0.f);
                lds[er * 17 + fr] = cvtpk_bf16(a20, a21);
            }
        }

        if (hn) {
            xi0 = h4[q0.x]; xj0 = h4[q0.y];
            xi1 = h4[q1.x]; xj1 = h4[q1.y];
            xi2 = h4[q2.x]; xj2 = h4[q2.y];
            xi3 = h4[q3.x]; xj3 = h4[q3.y];
        }

        asm volatile("s_waitcnt lgkmcnt(0)" ::: "memory");

        float m0 = b3[0], m1 = b3[1];
        #pragma unroll
        for (int j = 0; j < 16; j++) {
            unsigned u = lds[lane * 17 + j];
            float flo = __uint_as_float(u << 16);
            float fhi = __uint_as_float(u & 0xffff0000u);
            m0 = fmaf(flo, w3[2 * j],        m0);
            m1 = fmaf(flo, w3[2 * j + 1],    m1);
            m0 = fmaf(fhi, w3[2 * (j + 16)],     m0);
            m1 = fmaf(fhi, w3[2 * (j + 16) + 1], m1);
        }
        m0 = fmaxf(m0, 0.f); m1 = fmaxf(m1, 0.f);

        int d = kg == 0 ? p0.x : kg == 1 ? p1.x : kg == 2 ? p2.x : p3.x;
        int dprev = __shfl_up(d, 1);
        int dnext = __shfl_down(d, 1);
        bool head = (lane == 0) || (d != dprev);
        bool tail = (lane == 63) || (d != dnext);
        unsigned long long hb = __ballot(head);
        unsigned long long msk = (lane == 63) ? ~0ull : ((1ull << (lane + 1)) - 1ull);
        int seg0 = 63 - __clzll(hb & msk);
        #pragma unroll
        for (int st = 1; st < 64; st <<= 1) {
            float u0 = __shfl_up(m0, st);
            float u1 = __shfl_up(m1, st);
            if (lane - st >= seg0) { m0 += u0; m1 += u1; }
        }
        if (tail) {
            atomicAdd(&sum1[2 * d],     m0);
            atomicAdd(&sum1[2 * d + 1], m1);
        }

        if (!hn) break;
        p0 = q0; p1 = q1; p2 = q2; p3 = q3; g = gn;
    }
}

__global__ void div1_kernel(const float* __restrict__ sum1, const int* __restrict__ cnt,
                            float* __restrict__ h2) {
    int i = blockIdx.x * 256 + threadIdx.x;
    if (i >= N_NODES) return;
    float c = fmaxf((float)cnt[i], 1.f);
    float2 s = reinterpret_cast<const float2*>(sum1)[i];
    reinterpret_cast<float2*>(h2)[i] = make_float2(s.x / c, s.y / c);
}

// conv2 fused with aggregation (unchanged)
__global__ __launch_bounds__(256) void conv2_mfma_kernel(
    const float* __restrict__ h2, const int2* __restrict__ sds,
    const float* __restrict__ w1, const float* __restrict__ b1,
    const float* __restrict__ w2, const float* __restrict__ b2,
    const float* __restrict__ w3, const float* __restrict__ b3,
    float* __restrict__ sum2)
{
    __shared__ unsigned a2lds[4][64 * 17];
    int tid = threadIdx.x;
    int wave = tid >> 6, lane = tid & 63;
    int kg = lane >> 4, fr = lane & 15;
    unsigned* lds = &a2lds[wave][0];
    const float2* h2v = reinterpret_cast<const float2*>(h2);

    float al0[8], al1[8], be0[8], be1[8], b1v[8];
    #pragma unroll
    for (int i = 0; i < 8; i++) {
        int k = kg * 8 + i;
        float c0a = w1[k], c1a = w1[32 + k];
        float c0b = w1[64 + k], c1b = w1[96 + k];
        al0[i] = c0a - c0b; al1[i] = c1a - c1b;
        be0[i] = c0b; be1[i] = c1b;
        b1v[i] = b1[k];
    }
    short8 bhi0, blo0, bhi1, blo1;
    #pragma unroll
    for (int i = 0; i < 8; i++) {
        int k = kg * 8 + i;
        float w0 = w2[k * 32 + fr];
        float w1c = w2[k * 32 + fr + 16];
        unsigned short h0 = bf16_rne(w0);
        bhi0[i] = (short)h0; blo0[i] = (short)bf16_rne(w0 - bf16_f32(h0));
        unsigned short h1 = bf16_rne(w1c);
        bhi1[i] = (short)h1; blo1[i] = (short)bf16_rne(w1c - bf16_f32(h1));
    }
    float b2v0 = b2[fr], b2v1 = b2[fr + 16];

    int g = blockIdx.x * 4 + wave;
    if (g >= NGROUPS) return;
    int base = g * 64;
    int2 p0 = sds[base + fr], p1 = sds[base + 16 + fr];
    int2 p2 = sds[base + 32 + fr], p3 = sds[base + 48 + fr];
    float2 yd0 = h2v[p0.x], ys0 = h2v[p0.y];
    float2 yd1 = h2v[p1.x], ys1 = h2v[p1.y];
    float2 yd2 = h2v[p2.x], ys2 = h2v[p2.y];
    float2 yd3 = h2v[p3.x], ys3 = h2v[p3.y];

    while (true) {
        int gn = g + GSTRIDE;
        bool hn = gn < NGROUPS;
        int basen = gn * 64;
        int2 q0, q1, q2, q3;
        if (hn) {
            q0 = sds[basen + fr];      q1 = sds[basen + 16 + fr];
            q2 = sds[basen + 32 + fr]; q3 = sds[basen + 48 + fr];
        }

        #pragma unroll
        for (int t = 0; t < 4; t++) {
            float2 yd = t == 0 ? yd0 : t == 1 ? yd1 : t == 2 ? yd2 : yd3;
            float2 ys = t == 0 ? ys0 : t == 1 ? ys1 : t == 2 ? ys2 : ys3;
            float a[8];
            #pragma unroll
            for (int i = 0; i < 8; i++) {
                float pre = b1v[i];
                pre = fmaf(al0[i], yd.x, pre);
                pre = fmaf(al1[i], yd.y, pre);
                pre = fmaf(be0[i], ys.x, pre);
                pre = fmaf(be1[i], ys.y, pre);
                a[i] = fmaxf(pre, 0.f);
            }
            PackU pu;
            #pragma unroll
            for (int j = 0; j < 4; j++) pu.u[j] = cvtpk_bf16(a[2*j], a[2*j+1]);
            short8 ahi = pu.s;

            f32x4 acc0 = {0.f, 0.f, 0.f, 0.f}, acc1 = {0.f, 0.f, 0.f, 0.f};
            acc0 = __builtin_amdgcn_mfma_f32_16x16x32_bf16(ahi, blo0, acc0, 0, 0, 0);
            acc0 = __builtin_amdgcn_mfma_f32_16x16x32_bf16(ahi, bhi0, acc0, 0, 0, 0);
            acc1 = __builtin_amdgcn_mfma_f32_16x16x32_bf16(ahi, blo1, acc1, 0, 0, 0);
            acc1 = __builtin_amdgcn_mfma_f32_16x16x32_bf16(ahi, bhi1, acc1, 0, 0, 0);
            #pragma unroll
            for (int r = 0; r < 4; r++) {
                int er = t * 16 + kg * 4 + r;
                float a20 = fmaxf(acc0[r] + b2v0, 0.f);
                float a21 = fmaxf(acc1[r] + b2v1, 0.f);
                lds[er * 17 + fr] = cvtpk_bf16(a20, a21);
            }
        }

        if (hn) {
            yd0 = h2v[q0.x]; ys0 = h2v[q0.y];
            yd1 = h2v[q1.x]; ys1 = h2v[q1.y];
            yd2 = h2v[q2.x]; ys2 = h2v[q2.y];
            yd3 = h2v[q3.x]; ys3 = h2v[q3.y];
        }

        asm volatile("s_waitcnt lgkmcnt(0)" ::: "memory");

        float o0 = b3[0], o1 = b3[1], o2 = b3[2], o3 = b3[3];
        #pragma unroll
        for (int j = 0; j < 16; j++) {
            unsigned u = lds[lane * 17 + j];
            float flo = __uint_as_float(u << 16);
            float fhi = __uint_as_float(u & 0xffff0000u);
            o0 = fmaf(flo, w3[4 * j],     o0);
            o1 = fmaf(flo, w3[4 * j + 1], o1);
            o2 = fmaf(flo, w3[4 * j + 2], o2);
            o3 = fmaf(flo, w3[4 * j + 3], o3);
            o0 = fmaf(fhi, w3[4 * (j + 16)],     o0);
            o1 = fmaf(fhi, w3[4 * (j + 16) + 1], o1);
            o2 = fmaf(fhi, w3[4 * (j + 16) + 2], o2);
            o3 = fmaf(fhi, w3[4 * (j + 16) + 3], o3);
        }

        int d = kg == 0 ? p0.x : kg == 1 ? p1.x : kg == 2 ? p2.x : p3.x;
        int dprev = __shfl_up(d, 1);
        int dnext = __shfl_down(d, 1);
        bool head = (lane == 0) || (d != dprev);
        bool tail = (lane == 63) || (d != dnext);
        unsigned long long hb = __ballot(head);
        unsigned long long msk = (lane == 63) ? ~0ull : ((1ull << (lane + 1)) - 1ull);
        int seg0 = 63 - __clzll(hb & msk);
        #pragma unroll
        for (int st = 1; st < 64; st <<= 1) {
            float u0 = __shfl_up(o0, st);
            float u1 = __shfl_up(o1, st);
            float u2 = __shfl_up(o2, st);
            float u3 = __shfl_up(o3, st);
            if (lane - st >= seg0) { o0 += u0; o1 += u1; o2 += u2; o3 += u3; }
        }
        if (tail) {
            atomicAdd(&sum2[4 * d],     o0);
            atomicAdd(&sum2[4 * d + 1], o1);
            atomicAdd(&sum2[4 * d + 2], o2);
            atomicAdd(&sum2[4 * d + 3], o3);
        }

        if (!hn) break;
        p0 = q0; p1 = q1; p2 = q2; p3 = q3; g = gn;
    }
}

__global__ void div2_kernel(const float* __restrict__ sum2, const int* __restrict__ cnt,
                            float* __restrict__ out) {
    int i = blockIdx.x * 256 + threadIdx.x;
    if (i >= N_NODES) return;
    float c = fmaxf((float)cnt[i], 1.f);
    float4 s = reinterpret_cast<const float4*>(sum2)[i];
    reinterpret_cast<float4*>(out)[i] = make_float4(s.x/c, s.y/c, s.z/c, s.w/c);
}

extern "C" void kernel_launch(void* const* d_in, const int* in_sizes, int n_in,
                              void* d_out, int out_size, void* d_ws, size_t ws_size,
                              hipStream_t stream) {
    const float* x        = (const float*)d_in[0];
    const int*   ei       = (const int*)  d_in[1];
    const float* bn_gamma = (const float*)d_in[2];
    const float* bn_beta  = (const float*)d_in[3];
    const float* enc_w1   = (const float*)d_in[4];
    const float* enc_b1   = (const float*)d_in[5];
    const float* enc_w2   = (const float*)d_in[6];
    const float* enc_b2   = (const float*)d_in[7];
    const float* enc_w3   = (const float*)d_in[8];
    const float* enc_b3   = (const float*)d_in[9];
    const float* dec_w1   = (const float*)d_in[10];
    const float* dec_b1   = (const float*)d_in[11];
    const float* dec_w2   = (const float*)d_in[12];
    const float* dec_b2   = (const float*)d_in[13];
    const float* dec_w3   = (const float*)d_in[14];
    const float* dec_b3   = (const float*)d_in[15];

    float* wsf    = (float*)d_ws;
    int*   wsi    = (int*)d_ws;
    float* stats  = wsf + O_STATS;
    int*   bktctr = wsi + O_BKTCTR;
    float* sum1   = wsf + O_SUM1;
    float* sum2   = wsf + O_SUM2;
    int*   bktbase= wsi + O_BKTBASE;
    int*   cnt    = wsi + O_CNT;
    int2*  sbk    = (int2*)(wsi + O_SBK);
    int2*  sds    = (int2*)(wsi + O_SDS);
    float* h      = wsf + O_H;
    float* h2     = wsf + O_H2;
    float* out    = (float*)d_out;

    hipMemsetAsync(d_ws, 0, (size_t)ZERO_WORDS * sizeof(float), stream);

    const int nodeBlocks = (N_NODES + 255) / 256;

    bn_stats_kernel<<<STATS_BLOCKS, 256, 0, stream>>>(x, stats);
    bn_apply_kernel<<<nodeBlocks, 256, 0, stream>>>(x, stats, bn_gamma, bn_beta, h);
    scatter_kernel<<<SCAT_BLOCKS, 256, 0, stream>>>(ei, bktctr, sbk);
    ctr_scan_kernel<<<1, 256, 0, stream>>>(bktctr, bktbase);
    fine_rank_kernel<<<NBKT, 512, 0, stream>>>(sbk, bktctr, bktbase, sds, cnt);
    conv1_mfma_kernel<<<CONV_BLOCKS, 256, 0, stream>>>(h, sds,
                                                       enc_w1, enc_b1, enc_w2, enc_b2,
                                                       enc_w3, enc_b3, sum1);
    div1_kernel<<<nodeBlocks, 256, 0, stream>>>(sum1, cnt, h2);
    conv2_mfma_kernel<<<CONV_BLOCKS, 256, 0, stream>>>(h2, sds,
                                                       dec_w1, dec_b1, dec_w2, dec_b2,
                                                       dec_w3, dec_b3, sum2);
    div2_kernel<<<nodeBlocks, 256, 0, stream>>>(sum2, cnt, out);
}

// Round 21
// 207.351 us; speedup vs baseline: 2.1453x; 1.0547x over previous
//
#include <hip/hip_runtime.h>

#define N_NODES 100000
#define N_EDGES 3200000
#define BN_EPS 1e-5f
#define STATS_BLOCKS 64
#define CONV_BLOCKS 2048
#define NGROUPS (N_EDGES / 64)        // 50000
#define GSTRIDE (CONV_BLOCKS * 4)     // 8192
#define NBKT 196                      // ceil(100000/512)
#define BKT_CAP 18432                 // mean 16384, sigma ~128 -> +16 sigma
#define SCAT_BLOCKS 1024
#define EDGES_PER_SCAT (N_EDGES / SCAT_BLOCKS)   // 3125

typedef __attribute__((ext_vector_type(8))) short short8;
typedef __attribute__((ext_vector_type(4))) float f32x4;
typedef __attribute__((ext_vector_type(4))) unsigned int uint32x4;

// workspace layout (4-byte units). Front section is zeroed each call.
constexpr int O_STATS   = 0;                         // 8 f
constexpr int O_BKTCTR  = 8;                         // 256 int (zeroed)
constexpr int O_SUM1    = 264;                       // 2N f
constexpr int O_SUM2    = O_SUM1 + 2 * N_NODES;      // 4N f
constexpr int ZERO_WORDS = O_SUM2 + 4 * N_NODES;     // 264 + 6N
constexpr int O_BKTBASE = ZERO_WORDS;                // 256 int
constexpr int O_CNT     = O_BKTBASE + 256;           // N int
constexpr int O_SBK     = O_CNT + N_NODES;           // NBKT*BKT_CAP int2
constexpr int O_SDS     = O_SBK + 2 * NBKT * BKT_CAP; // 2E int (dst,src grouped)
constexpr int O_H       = O_SDS + 2 * N_EDGES;       // 4N f
constexpr int O_H2      = O_H + 4 * N_NODES;         // 2N f

__device__ __forceinline__ unsigned short bf16_rne(float f) {
    unsigned u = __float_as_uint(f);
    unsigned r = (u + 0x7fff + ((u >> 16) & 1)) >> 16;
    return (unsigned short)r;
}
__device__ __forceinline__ float bf16_f32(unsigned short h) {
    return __uint_as_float(((unsigned)h) << 16);
}
__device__ __forceinline__ unsigned cvtpk_bf16(float a, float b) {
    unsigned r;
    asm("v_cvt_pk_bf16_f32 %0, %1, %2" : "=v"(r) : "v"(a), "v"(b));
    return r;
}
union PackU { uint32x4 u; short8 s; };

__global__ __launch_bounds__(256) void bn_stats_kernel(const float* __restrict__ x,
                                                       float* __restrict__ stats) {
    __shared__ float red[4][8];
    int tid = threadIdx.x;
    float s0=0.f,s1=0.f,s2=0.f,s3=0.f,q0=0.f,q1=0.f,q2=0.f,q3=0.f;
    for (int i = blockIdx.x * 256 + tid; i < N_NODES; i += STATS_BLOCKS * 256) {
        float4 v = reinterpret_cast<const float4*>(x)[i];
        s0+=v.x; s1+=v.y; s2+=v.z; s3+=v.w;
        q0=fmaf(v.x,v.x,q0); q1=fmaf(v.y,v.y,q1); q2=fmaf(v.z,v.z,q2); q3=fmaf(v.w,v.w,q3);
    }
    #pragma unroll
    for (int off = 32; off > 0; off >>= 1) {
        s0 += __shfl_down(s0, off); s1 += __shfl_down(s1, off);
        s2 += __shfl_down(s2, off); s3 += __shfl_down(s3, off);
        q0 += __shfl_down(q0, off); q1 += __shfl_down(q1, off);
        q2 += __shfl_down(q2, off); q3 += __shfl_down(q3, off);
    }
    int wave = tid >> 6, lane = tid & 63;
    if (lane == 0) {
        red[wave][0]=s0; red[wave][1]=s1; red[wave][2]=s2; red[wave][3]=s3;
        red[wave][4]=q0; red[wave][5]=q1; red[wave][6]=q2; red[wave][7]=q3;
    }
    __syncthreads();
    if (tid < 8) {
        float v = red[0][tid] + red[1][tid] + red[2][tid] + red[3][tid];
        atomicAdd(&stats[tid], v);
    }
}

__global__ void bn_apply_kernel(const float* __restrict__ x,
                                const float* __restrict__ stats,
                                const float* __restrict__ gamma,
                                const float* __restrict__ beta,
                                float* __restrict__ h) {
    int i = blockIdx.x * blockDim.x + threadIdx.x;
    if (i >= N_NODES) return;
    const float inv_n = 1.0f / (float)N_NODES;
    float m0 = stats[0]*inv_n, m1 = stats[1]*inv_n, m2 = stats[2]*inv_n, m3 = stats[3]*inv_n;
    float sc0 = rsqrtf(stats[4]*inv_n - m0*m0 + BN_EPS) * gamma[0];
    float sc1 = rsqrtf(stats[5]*inv_n - m1*m1 + BN_EPS) * gamma[1];
    float sc2 = rsqrtf(stats[6]*inv_n - m2*m2 + BN_EPS) * gamma[2];
    float sc3 = rsqrtf(stats[7]*inv_n - m3*m3 + BN_EPS) * gamma[3];
    float4 v = reinterpret_cast<const float4*>(x)[i];
    float4 o;
    o.x = (v.x - m0) * sc0 + beta[0];
    o.y = (v.y - m1) * sc1 + beta[1];
    o.z = (v.z - m2) * sc2 + beta[2];
    o.w = (v.w - m3) * sc3 + beta[3];
    reinterpret_cast<float4*>(h)[i] = o;
}

// single-pass scatter with block-local counting sort in LDS -> coalesced writes.
__global__ __launch_bounds__(256) void scatter_kernel(const int* __restrict__ ei,
                                                      int* __restrict__ bktctr,
                                                      int2* __restrict__ sbk) {
    __shared__ int2 stage[EDGES_PER_SCAT];
    __shared__ int dcache[EDGES_PER_SCAT];
    __shared__ int lh[256], lpos[256], gbase[256], lctr[256];
    int t = threadIdx.x;
    lh[t] = 0; lctr[t] = 0;
    __syncthreads();
    int start = blockIdx.x * EDGES_PER_SCAT;
    for (int k = t; k < EDGES_PER_SCAT; k += 256) {
        int d = ei[N_EDGES + start + k];
        dcache[k] = d;
        atomicAdd(&lh[d >> 9], 1);
    }
    __syncthreads();
    {
        int v = lh[t];
        __shared__ int sd[256];
        sd[t] = v; __syncthreads();
        for (int o = 1; o < 256; o <<= 1) {
            int xx = (t >= o) ? sd[t - o] : 0;
            __syncthreads();
            sd[t] += xx;
            __syncthreads();
        }
        lpos[t] = sd[t] - v;
        if (v) gbase[t] = t * BKT_CAP + atomicAdd(&bktctr[t], v);
        __syncthreads();
    }
    for (int k = t; k < EDGES_PER_SCAT; k += 256) {
        int d = dcache[k];
        int s = ei[start + k];
        int b = d >> 9;
        int r = atomicAdd(&lctr[b], 1);
        stage[lpos[b] + r] = make_int2(d, s);
    }
    __syncthreads();
    for (int k = t; k < EDGES_PER_SCAT; k += 256) {
        int2 v = stage[k];
        int b = v.x >> 9;
        sbk[gbase[b] + (k - lpos[b])] = v;
    }
}

// exclusive scan of actual bucket counts -> dense output offsets
__global__ void ctr_scan_kernel(const int* __restrict__ bktctr, int* __restrict__ bktbase) {
    __shared__ int sd[256];
    int t = threadIdx.x;
    int v = bktctr[t];
    sd[t] = v; __syncthreads();
    for (int o = 1; o < 256; o <<= 1) {
        int x = (t >= o) ? sd[t - o] : 0;
        __syncthreads();
        sd[t] += x;
        __syncthreads();
    }
    bktbase[t] = sd[t] - v;
}

// per-bucket fine grouping with FULL LDS OUTPUT STAGING -> coalesced sds writes.
__global__ __launch_bounds__(512, 1) void fine_rank_kernel(const int2* __restrict__ sbk,
                                                           const int* __restrict__ bktctr,
                                                           const int* __restrict__ bktbase,
                                                           int2* __restrict__ sds,
                                                           int* __restrict__ cnt) {
    __shared__ int2 stage[BKT_CAP];               // 147.5 KB
    __shared__ int hist[512], scanv[512], ctr[512];
    int b = blockIdx.x;
    int t = threadIdx.x;
    int ibase = b * BKT_CAP;
    int obase = bktbase[b];
    int ecount = bktctr[b];
    hist[t] = 0; ctr[t] = 0;
    __syncthreads();
    for (int i = t; i < ecount; i += 512) {
        int d = sbk[ibase + i].x;
        atomicAdd(&hist[d & 511], 1);
    }
    __syncthreads();
    int v = hist[t];
    scanv[t] = v;
    __syncthreads();
    for (int o = 1; o < 512; o <<= 1) {
        int x = (t >= o) ? scanv[t - o] : 0;
        __syncthreads();
        scanv[t] += x;
        __syncthreads();
    }
    int excl = scanv[t] - v;
    int node = (b << 9) + t;
    if (node < N_NODES) cnt[node] = v;
    __syncthreads();
    hist[t] = excl;
    __syncthreads();
    // place into LDS stage grouped by node
    for (int i = t; i < ecount; i += 512) {
        int2 de = sbk[ibase + i];
        int ld = de.x & 511;
        int r = atomicAdd(&ctr[ld], 1);
        stage[hist[ld] + r] = de;
    }
    __syncthreads();
    // stream out coalesced
    for (int k = t; k < ecount; k += 512) {
        sds[obase + k] = stage[k];
    }
}

// conv1 fused with aggregation (unchanged)
__global__ __launch_bounds__(256) void conv1_mfma_kernel(
    const float* __restrict__ h, const int2* __restrict__ sds,
    const float* __restrict__ w1, const float* __restrict__ b1,
    const float* __restrict__ w2, const float* __restrict__ b2,
    const float* __restrict__ w3, const float* __restrict__ b3,
    float* __restrict__ sum1)
{
    __shared__ unsigned a2lds[4][64 * 17];
    int tid = threadIdx.x;
    int wave = tid >> 6, lane = tid & 63;
    int kg = lane >> 4, fr = lane & 15;
    unsigned* lds = &a2lds[wave][0];
    const float4* h4 = reinterpret_cast<const float4*>(h);

    float al[4][8], be[4][8], b1v[8];
    #pragma unroll
    for (int i = 0; i < 8; i++) {
        int k = kg * 8 + i;
        #pragma unroll
        for (int c = 0; c < 4; c++) {
            float wa = w1[c * 32 + k];
            float wb = w1[(4 + c) * 32 + k];
            al[c][i] = wa - wb;
            be[c][i] = wb;
        }
        b1v[i] = b1[k];
    }
    short8 bhi0, blo0, bhi1, blo1;
    #pragma unroll
    for (int i = 0; i < 8; i++) {
        int k = kg * 8 + i;
        float w0 = w2[k * 32 + fr];
        float w1c = w2[k * 32 + fr + 16];
        unsigned short h0 = bf16_rne(w0);
        bhi0[i] = (short)h0; blo0[i] = (short)bf16_rne(w0 - bf16_f32(h0));
        unsigned short h1 = bf16_rne(w1c);
        bhi1[i] = (short)h1; blo1[i] = (short)bf16_rne(w1c - bf16_f32(h1));
    }
    float b2v0 = b2[fr], b2v1 = b2[fr + 16];

    int g = blockIdx.x * 4 + wave;
    if (g >= NGROUPS) return;

    int base = g * 64;
    int2 p0 = sds[base + fr], p1 = sds[base + 16 + fr];
    int2 p2 = sds[base + 32 + fr], p3 = sds[base + 48 + fr];
    float4 xi0 = h4[p0.x], xj0 = h4[p0.y];
    float4 xi1 = h4[p1.x], xj1 = h4[p1.y];
    float4 xi2 = h4[p2.x], xj2 = h4[p2.y];
    float4 xi3 = h4[p3.x], xj3 = h4[p3.y];

    while (true) {
        int gn = g + GSTRIDE;
        bool hn = gn < NGROUPS;
        int basen = gn * 64;
        int2 q0, q1, q2, q3;
        if (hn) {
            q0 = sds[basen + fr];      q1 = sds[basen + 16 + fr];
            q2 = sds[basen + 32 + fr]; q3 = sds[basen + 48 + fr];
        }

        #pragma unroll
        for (int t = 0; t < 4; t++) {
            float4 xi = t == 0 ? xi0 : t == 1 ? xi1 : t == 2 ? xi2 : xi3;
            float4 xj = t == 0 ? xj0 : t == 1 ? xj1 : t == 2 ? xj2 : xj3;
            float a[8];
            #pragma unroll
            for (int i = 0; i < 8; i++) {
                float pre = b1v[i];
                pre = fmaf(al[0][i], xi.x, pre);
                pre = fmaf(al[1][i], xi.y, pre);
                pre = fmaf(al[2][i], xi.z, pre);
                pre = fmaf(al[3][i], xi.w, pre);
                pre = fmaf(be[0][i], xj.x, pre);
                pre = fmaf(be[1][i], xj.y, pre);
                pre = fmaf(be[2][i], xj.z, pre);
                pre = fmaf(be[3][i], xj.w, pre);
                a[i] = fmaxf(pre, 0.f);
            }
            PackU pu;
            #pragma unroll
            for (int j = 0; j < 4; j++) pu.u[j] = cvtpk_bf16(a[2*j], a[2*j+1]);
            short8 ahi = pu.s;

            f32x4 acc0 = {0.f, 0.f, 0.f, 0.f}, acc1 = {0.f, 0.f, 0.f, 0.f};
            acc0 = __builtin_amdgcn_mfma_f32_16x16x32_bf16(ahi, blo0, acc0, 0, 0, 0);
            acc0 = __builtin_amdgcn_mfma_f32_16x16x32_bf16(ahi, bhi0, acc0, 0, 0, 0);
            acc1 = __builtin_amdgcn_mfma_f32_16x16x32_bf16(ahi, blo1, acc1, 0, 0, 0);
            acc1 = __builtin_amdgcn_mfma_f32_16x16x32_bf16(ahi, bhi1, acc1, 0, 0, 0);
            #pragma unroll
            for (int r = 0; r < 4; r++) {
                int er = t * 16 + kg * 4 + r;
                float a20 = fmaxf(acc0[r] + b2v0, 0.f);
                float a21 = fmaxf(acc1[r] + b2v1, 0.f);
                lds[er * 17 + fr] = cvtpk_bf16(a20, a21);
            }
        }

        if (hn) {
            xi0 = h4[q0.x]; xj0 = h4[q0.y];
            xi1 = h4[q1.x]; xj1 = h4[q1.y];
            xi2 = h4[q2.x]; xj2 = h4[q2.y];
            xi3 = h4[q3.x]; xj3 = h4[q3.y];
        }

        asm volatile("s_waitcnt lgkmcnt(0)" ::: "memory");

        float m0 = b3[0], m1 = b3[1];
        #pragma unroll
        for (int j = 0; j < 16; j++) {
            unsigned u = lds[lane * 17 + j];
            float flo = __uint_as_float(u << 16);
            float fhi = __uint_as_float(u & 0xffff0000u);
            m0 = fmaf(flo, w3[2 * j],        m0);
            m1 = fmaf(flo, w3[2 * j + 1],    m1);
            m0 = fmaf(fhi, w3[2 * (j + 16)],     m0);
            m1 = fmaf(fhi, w3[2 * (j + 16) + 1], m1);
        }
        m0 = fmaxf(m0, 0.f); m1 = fmaxf(m1, 0.f);

        int d = kg == 0 ? p0.x : kg == 1 ? p1.x : kg == 2 ? p2.x : p3.x;
        int dprev = __shfl_up(d, 1);
        int dnext = __shfl_down(d, 1);
        bool head = (lane == 0) || (d != dprev);
        bool tail = (lane == 63) || (d != dnext);
        unsigned long long hb = __ballot(head);
        unsigned long long msk = (lane == 63) ? ~0ull : ((1ull << (lane + 1)) - 1ull);
        int seg0 = 63 - __clzll(hb & msk);
        #pragma unroll
        for (int st = 1; st < 64; st <<= 1) {
            float u0 = __shfl_up(m0, st);
            float u1 = __shfl_up(m1, st);
            if (lane - st >= seg0) { m0 += u0; m1 += u1; }
        }
        if (tail) {
            atomicAdd(&sum1[2 * d],     m0);
            atomicAdd(&sum1[2 * d + 1], m1);
        }

        if (!hn) break;
        p0 = q0; p1 = q1; p2 = q2; p3 = q3; g = gn;
    }
}

__global__ void div1_kernel(const float* __restrict__ sum1, const int* __restrict__ cnt,
                            float* __restrict__ h2) {
    int i = blockIdx.x * 256 + threadIdx.x;
    if (i >= N_NODES) return;
    float c = fmaxf((float)cnt[i], 1.f);
    float2 s = reinterpret_cast<const float2*>(sum1)[i];
    reinterpret_cast<float2*>(h2)[i] = make_float2(s.x / c, s.y / c);
}

// conv2 fused with aggregation (unchanged)
__global__ __launch_bounds__(256) void conv2_mfma_kernel(
    const float* __restrict__ h2, const int2* __restrict__ sds,
    const float* __restrict__ w1, const float* __restrict__ b1,
    const float* __restrict__ w2, const float* __restrict__ b2,
    const float* __restrict__ w3, const float* __restrict__ b3,
    float* __restrict__ sum2)
{
    __shared__ unsigned a2lds[4][64 * 17];
    int tid = threadIdx.x;
    int wave = tid >> 6, lane = tid & 63;
    int kg = lane >> 4, fr = lane & 15;
    unsigned* lds = &a2lds[wave][0];
    const float2* h2v = reinterpret_cast<const float2*>(h2);

    float al0[8], al1[8], be0[8], be1[8], b1v[8];
    #pragma unroll
    for (int i = 0; i < 8; i++) {
        int k = kg * 8 + i;
        float c0a = w1[k], c1a = w1[32 + k];
        float c0b = w1[64 + k], c1b = w1[96 + k];
        al0[i] = c0a - c0b; al1[i] = c1a - c1b;
        be0[i] = c0b; be1[i] = c1b;
        b1v[i] = b1[k];
    }
    short8 bhi0, blo0, bhi1, blo1;
    #pragma unroll
    for (int i = 0; i < 8; i++) {
        int k = kg * 8 + i;
        float w0 = w2[k * 32 + fr];
        float w1c = w2[k * 32 + fr + 16];
        unsigned short h0 = bf16_rne(w0);
        bhi0[i] = (short)h0; blo0[i] = (short)bf16_rne(w0 - bf16_f32(h0));
        unsigned short h1 = bf16_rne(w1c);
        bhi1[i] = (short)h1; blo1[i] = (short)bf16_rne(w1c - bf16_f32(h1));
    }
    float b2v0 = b2[fr], b2v1 = b2[fr + 16];

    int g = blockIdx.x * 4 + wave;
    if (g >= NGROUPS) return;
    int base = g * 64;
    int2 p0 = sds[base + fr], p1 = sds[base + 16 + fr];
    int2 p2 = sds[base + 32 + fr], p3 = sds[base + 48 + fr];
    float2 yd0 = h2v[p0.x], ys0 = h2v[p0.y];
    float2 yd1 = h2v[p1.x], ys1 = h2v[p1.y];
    float2 yd2 = h2v[p2.x], ys2 = h2v[p2.y];
    float2 yd3 = h2v[p3.x], ys3 = h2v[p3.y];

    while (true) {
        int gn = g + GSTRIDE;
        bool hn = gn < NGROUPS;
        int basen = gn * 64;
        int2 q0, q1, q2, q3;
        if (hn) {
            q0 = sds[basen + fr];      q1 = sds[basen + 16 + fr];
            q2 = sds[basen + 32 + fr]; q3 = sds[basen + 48 + fr];
        }

        #pragma unroll
        for (int t = 0; t < 4; t++) {
            float2 yd = t == 0 ? yd0 : t == 1 ? yd1 : t == 2 ? yd2 : yd3;
            float2 ys = t == 0 ? ys0 : t == 1 ? ys1 : t == 2 ? ys2 : ys3;
            float a[8];
            #pragma unroll
            for (int i = 0; i < 8; i++) {
                float pre = b1v[i];
                pre = fmaf(al0[i], yd.x, pre);
                pre = fmaf(al1[i], yd.y, pre);
                pre = fmaf(be0[i], ys.x, pre);
                pre = fmaf(be1[i], ys.y, pre);
                a[i] = fmaxf(pre, 0.f);
            }
            PackU pu;
            #pragma unroll
            for (int j = 0; j < 4; j++) pu.u[j] = cvtpk_bf16(a[2*j], a[2*j+1]);
            short8 ahi = pu.s;

            f32x4 acc0 = {0.f, 0.f, 0.f, 0.f}, acc1 = {0.f, 0.f, 0.f, 0.f};
            acc0 = __builtin_amdgcn_mfma_f32_16x16x32_bf16(ahi, blo0, acc0, 0, 0, 0);
            acc0 = __builtin_amdgcn_mfma_f32_16x16x32_bf16(ahi, bhi0, acc0, 0, 0, 0);
            acc1 = __builtin_amdgcn_mfma_f32_16x16x32_bf16(ahi, blo1, acc1, 0, 0, 0);
            acc1 = __builtin_amdgcn_mfma_f32_16x16x32_bf16(ahi, bhi1, acc1, 0, 0, 0);
            #pragma unroll
            for (int r = 0; r < 4; r++) {
                int er = t * 16 + kg * 4 + r;
                float a20 = fmaxf(acc0[r] + b2v0, 0.f);
                float a21 = fmaxf(acc1[r] + b2v1, 0.f);
                lds[er * 17 + fr] = cvtpk_bf16(a20, a21);
            }
        }

        if (hn) {
            yd0 = h2v[q0.x]; ys0 = h2v[q0.y];
            yd1 = h2v[q1.x]; ys1 = h2v[q1.y];
            yd2 = h2v[q2.x]; ys2 = h2v[q2.y];
            yd3 = h2v[q3.x]; ys3 = h2v[q3.y];
        }

        asm volatile("s_waitcnt lgkmcnt(0)" ::: "memory");

        float o0 = b3[0], o1 = b3[1], o2 = b3[2], o3 = b3[3];
        #pragma unroll
        for (int j = 0; j < 16; j++) {
            unsigned u = lds[lane * 17 + j];
            float flo = __uint_as_float(u << 16);
            float fhi = __uint_as_float(u & 0xffff0000u);
            o0 = fmaf(flo, w3[4 * j],     o0);
            o1 = fmaf(flo, w3[4 * j + 1], o1);
            o2 = fmaf(flo, w3[4 * j + 2], o2);
            o3 = fmaf(flo, w3[4 * j + 3], o3);
            o0 = fmaf(fhi, w3[4 * (j + 16)],     o0);
            o1 = fmaf(fhi, w3[4 * (j + 16) + 1], o1);
            o2 = fmaf(fhi, w3[4 * (j + 16) + 2], o2);
            o3 = fmaf(fhi, w3[4 * (j + 16) + 3], o3);
        }

        int d = kg == 0 ? p0.x : kg == 1 ? p1.x : kg == 2 ? p2.x : p3.x;
        int dprev = __shfl_up(d, 1);
        int dnext = __shfl_down(d, 1);
        bool head = (lane == 0) || (d != dprev);
        bool tail = (lane == 63) || (d != dnext);
        unsigned long long hb = __ballot(head);
        unsigned long long msk = (lane == 63) ? ~0ull : ((1ull << (lane + 1)) - 1ull);
        int seg0 = 63 - __clzll(hb & msk);
        #pragma unroll
        for (int st = 1; st < 64; st <<= 1) {
            float u0 = __shfl_up(o0, st);
            float u1 = __shfl_up(o1, st);
            float u2 = __shfl_up(o2, st);
            float u3 = __shfl_up(o3, st);
            if (lane - st >= seg0) { o0 += u0; o1 += u1; o2 += u2; o3 += u3; }
        }
        if (tail) {
            atomicAdd(&sum2[4 * d],     o0);
            atomicAdd(&sum2[4 * d + 1], o1);
            atomicAdd(&sum2[4 * d + 2], o2);
            atomicAdd(&sum2[4 * d + 3], o3);
        }

        if (!hn) break;
        p0 = q0; p1 = q1; p2 = q2; p3 = q3; g = gn;
    }
}

__global__ void div2_kernel(const float* __restrict__ sum2, const int* __restrict__ cnt,
                            float* __restrict__ out) {
    int i = blockIdx.x * 256 + threadIdx.x;
    if (i >= N_NODES) return;
    float c = fmaxf((float)cnt[i], 1.f);
    float4 s = reinterpret_cast<const float4*>(sum2)[i];
    reinterpret_cast<float4*>(out)[i] = make_float4(s.x/c, s.y/c, s.z/c, s.w/c);
}

extern "C" void kernel_launch(void* const* d_in, const int* in_sizes, int n_in,
                              void* d_out, int out_size, void* d_ws, size_t ws_size,
                              hipStream_t stream) {
    const float* x        = (const float*)d_in[0];
    const int*   ei       = (const int*)  d_in[1];
    const float* bn_gamma = (const float*)d_in[2];
    const float* bn_beta  = (const float*)d_in[3];
    const float* enc_w1   = (const float*)d_in[4];
    const float* enc_b1   = (const float*)d_in[5];
    const float* enc_w2   = (const float*)d_in[6];
    const float* enc_b2   = (const float*)d_in[7];
    const float* enc_w3   = (const float*)d_in[8];
    const float* enc_b3   = (const float*)d_in[9];
    const float* dec_w1   = (const float*)d_in[10];
    const float* dec_b1   = (const float*)d_in[11];
    const float* dec_w2   = (const float*)d_in[12];
    const float* dec_b2   = (const float*)d_in[13];
    const float* dec_w3   = (const float*)d_in[14];
    const float* dec_b3   = (const float*)d_in[15];

    float* wsf    = (float*)d_ws;
    int*   wsi    = (int*)d_ws;
    float* stats  = wsf + O_STATS;
    int*   bktctr = wsi + O_BKTCTR;
    float* sum1   = wsf + O_SUM1;
    float* sum2   = wsf + O_SUM2;
    int*   bktbase= wsi + O_BKTBASE;
    int*   cnt    = wsi + O_CNT;
    int2*  sbk    = (int2*)(wsi + O_SBK);
    int2*  sds    = (int2*)(wsi + O_SDS);
    float* h      = wsf + O_H;
    float* h2     = wsf + O_H2;
    float* out    = (float*)d_out;

    hipMemsetAsync(d_ws, 0, (size_t)ZERO_WORDS * sizeof(float), stream);

    const int nodeBlocks = (N_NODES + 255) / 256;

    bn_stats_kernel<<<STATS_BLOCKS, 256, 0, stream>>>(x, stats);
    bn_apply_kernel<<<nodeBlocks, 256, 0, stream>>>(x, stats, bn_gamma, bn_beta, h);
    scatter_kernel<<<SCAT_BLOCKS, 256, 0, stream>>>(ei, bktctr, sbk);
    ctr_scan_kernel<<<1, 256, 0, stream>>>(bktctr, bktbase);
    fine_rank_kernel<<<NBKT, 512, 0, stream>>>(sbk, bktctr, bktbase, sds, cnt);
    conv1_mfma_kernel<<<CONV_BLOCKS, 256, 0, stream>>>(h, sds,
                                                       enc_w1, enc_b1, enc_w2, enc_b2,
                                                       enc_w3, enc_b3, sum1);
    div1_kernel<<<nodeBlocks, 256, 0, stream>>>(sum1, cnt, h2);
    conv2_mfma_kernel<<<CONV_BLOCKS, 256, 0, stream>>>(h2, sds,
                                                       dec_w1, dec_b1, dec_w2, dec_b2,
                                                       dec_w3, dec_b3, sum2);
    div2_kernel<<<nodeBlocks, 256, 0, stream>>>(sum2, cnt, out);
}

// Round 22
// 204.601 us; speedup vs baseline: 2.1741x; 1.0134x over previous
//
#include <hip/hip_runtime.h>

#define N_NODES 100000
#define N_EDGES 3200000
#define BN_EPS 1e-5f
#define STATS_BLOCKS 64
#define CONV_BLOCKS 2048
#define NGROUPS (N_EDGES / 64)        // 50000
#define GSTRIDE (CONV_BLOCKS * 4)     // 8192
#define NBKT 196                      // ceil(100000/512)
#define BKT_CAP 18432                 // mean 16384, sigma ~128 -> +16 sigma
#define SCAT_BLOCKS 1024
#define EDGES_PER_SCAT (N_EDGES / SCAT_BLOCKS)   // 3125

typedef __attribute__((ext_vector_type(8))) short short8;
typedef __attribute__((ext_vector_type(4))) float f32x4;
typedef __attribute__((ext_vector_type(4))) unsigned int uint32x4;

// workspace layout (4-byte units). Front section is zeroed each call.
constexpr int O_STATS   = 0;                         // 8 f
constexpr int O_BKTCTR  = 8;                         // 256 int (zeroed)
constexpr int O_SUM1    = 264;                       // 2N f
constexpr int O_SUM2    = O_SUM1 + 2 * N_NODES;      // 4N f
constexpr int ZERO_WORDS = O_SUM2 + 4 * N_NODES;     // 264 + 6N
constexpr int O_BKTBASE = ZERO_WORDS;                // 256 int
constexpr int O_CNT     = O_BKTBASE + 256;           // N int
constexpr int O_SBK     = O_CNT + N_NODES;           // NBKT*BKT_CAP int2
constexpr int O_SDS     = O_SBK + 2 * NBKT * BKT_CAP; // 2E int (dst,src grouped)
constexpr int O_H       = O_SDS + 2 * N_EDGES;       // 4N f
constexpr int O_H2      = O_H + 4 * N_NODES;         // 2N f

__device__ __forceinline__ unsigned short bf16_rne(float f) {
    unsigned u = __float_as_uint(f);
    unsigned r = (u + 0x7fff + ((u >> 16) & 1)) >> 16;
    return (unsigned short)r;
}
__device__ __forceinline__ float bf16_f32(unsigned short h) {
    return __uint_as_float(((unsigned)h) << 16);
}
__device__ __forceinline__ unsigned cvtpk_bf16(float a, float b) {
    unsigned r;
    asm("v_cvt_pk_bf16_f32 %0, %1, %2" : "=v"(r) : "v"(a), "v"(b));
    return r;
}
union PackU { uint32x4 u; short8 s; };

__global__ __launch_bounds__(256) void bn_stats_kernel(const float* __restrict__ x,
                                                       float* __restrict__ stats) {
    __shared__ float red[4][8];
    int tid = threadIdx.x;
    float s0=0.f,s1=0.f,s2=0.f,s3=0.f,q0=0.f,q1=0.f,q2=0.f,q3=0.f;
    for (int i = blockIdx.x * 256 + tid; i < N_NODES; i += STATS_BLOCKS * 256) {
        float4 v = reinterpret_cast<const float4*>(x)[i];
        s0+=v.x; s1+=v.y; s2+=v.z; s3+=v.w;
        q0=fmaf(v.x,v.x,q0); q1=fmaf(v.y,v.y,q1); q2=fmaf(v.z,v.z,q2); q3=fmaf(v.w,v.w,q3);
    }
    #pragma unroll
    for (int off = 32; off > 0; off >>= 1) {
        s0 += __shfl_down(s0, off); s1 += __shfl_down(s1, off);
        s2 += __shfl_down(s2, off); s3 += __shfl_down(s3, off);
        q0 += __shfl_down(q0, off); q1 += __shfl_down(q1, off);
        q2 += __shfl_down(q2, off); q3 += __shfl_down(q3, off);
    }
    int wave = tid >> 6, lane = tid & 63;
    if (lane == 0) {
        red[wave][0]=s0; red[wave][1]=s1; red[wave][2]=s2; red[wave][3]=s3;
        red[wave][4]=q0; red[wave][5]=q1; red[wave][6]=q2; red[wave][7]=q3;
    }
    __syncthreads();
    if (tid < 8) {
        float v = red[0][tid] + red[1][tid] + red[2][tid] + red[3][tid];
        atomicAdd(&stats[tid], v);
    }
}

__global__ void bn_apply_kernel(const float* __restrict__ x,
                                const float* __restrict__ stats,
                                const float* __restrict__ gamma,
                                const float* __restrict__ beta,
                                float* __restrict__ h) {
    int i = blockIdx.x * blockDim.x + threadIdx.x;
    if (i >= N_NODES) return;
    const float inv_n = 1.0f / (float)N_NODES;
    float m0 = stats[0]*inv_n, m1 = stats[1]*inv_n, m2 = stats[2]*inv_n, m3 = stats[3]*inv_n;
    float sc0 = rsqrtf(stats[4]*inv_n - m0*m0 + BN_EPS) * gamma[0];
    float sc1 = rsqrtf(stats[5]*inv_n - m1*m1 + BN_EPS) * gamma[1];
    float sc2 = rsqrtf(stats[6]*inv_n - m2*m2 + BN_EPS) * gamma[2];
    float sc3 = rsqrtf(stats[7]*inv_n - m3*m3 + BN_EPS) * gamma[3];
    float4 v = reinterpret_cast<const float4*>(x)[i];
    float4 o;
    o.x = (v.x - m0) * sc0 + beta[0];
    o.y = (v.y - m1) * sc1 + beta[1];
    o.z = (v.z - m2) * sc2 + beta[2];
    o.w = (v.w - m3) * sc3 + beta[3];
    reinterpret_cast<float4*>(h)[i] = o;
}

// single-pass scatter with block-local counting sort in LDS -> coalesced writes.
// No dcache: phase 2 re-reads dst (L2-warm) -> LDS 30 KB -> better residency.
__global__ __launch_bounds__(256) void scatter_kernel(const int* __restrict__ ei,
                                                      int* __restrict__ bktctr,
                                                      int2* __restrict__ sbk) {
    __shared__ int2 stage[EDGES_PER_SCAT];
    __shared__ int lh[256], lpos[256], gbase[256], lctr[256];
    int t = threadIdx.x;
    lh[t] = 0; lctr[t] = 0;
    __syncthreads();
    int start = blockIdx.x * EDGES_PER_SCAT;
    for (int k = t; k < EDGES_PER_SCAT; k += 256) {
        int d = ei[N_EDGES + start + k];
        atomicAdd(&lh[d >> 9], 1);
    }
    __syncthreads();
    {
        int v = lh[t];
        __shared__ int sd[256];
        sd[t] = v; __syncthreads();
        for (int o = 1; o < 256; o <<= 1) {
            int xx = (t >= o) ? sd[t - o] : 0;
            __syncthreads();
            sd[t] += xx;
            __syncthreads();
        }
        lpos[t] = sd[t] - v;
        if (v) gbase[t] = t * BKT_CAP + atomicAdd(&bktctr[t], v);
        __syncthreads();
    }
    for (int k = t; k < EDGES_PER_SCAT; k += 256) {
        int d = ei[N_EDGES + start + k];
        int s = ei[start + k];
        int b = d >> 9;
        int r = atomicAdd(&lctr[b], 1);
        stage[lpos[b] + r] = make_int2(d, s);
    }
    __syncthreads();
    for (int k = t; k < EDGES_PER_SCAT; k += 256) {
        int2 v = stage[k];
        int b = v.x >> 9;
        sbk[gbase[b] + (k - lpos[b])] = v;
    }
}

// exclusive scan of actual bucket counts -> dense output offsets
__global__ void ctr_scan_kernel(const int* __restrict__ bktctr, int* __restrict__ bktbase) {
    __shared__ int sd[256];
    int t = threadIdx.x;
    int v = bktctr[t];
    sd[t] = v; __syncthreads();
    for (int o = 1; o < 256; o <<= 1) {
        int x = (t >= o) ? sd[t - o] : 0;
        __syncthreads();
        sd[t] += x;
        __syncthreads();
    }
    bktbase[t] = sd[t] - v;
}

// per-bucket fine grouping with FULL LDS OUTPUT STAGING -> coalesced sds writes.
__global__ __launch_bounds__(512, 1) void fine_rank_kernel(const int2* __restrict__ sbk,
                                                           const int* __restrict__ bktctr,
                                                           const int* __restrict__ bktbase,
                                                           int2* __restrict__ sds,
                                                           int* __restrict__ cnt) {
    __shared__ int2 stage[BKT_CAP];               // 147.5 KB
    __shared__ int hist[512], scanv[512], ctr[512];
    int b = blockIdx.x;
    int t = threadIdx.x;
    int ibase = b * BKT_CAP;
    int obase = bktbase[b];
    int ecount = bktctr[b];
    hist[t] = 0; ctr[t] = 0;
    __syncthreads();
    for (int i = t; i < ecount; i += 512) {
        int d = sbk[ibase + i].x;
        atomicAdd(&hist[d & 511], 1);
    }
    __syncthreads();
    int v = hist[t];
    scanv[t] = v;
    __syncthreads();
    for (int o = 1; o < 512; o <<= 1) {
        int x = (t >= o) ? scanv[t - o] : 0;
        __syncthreads();
        scanv[t] += x;
        __syncthreads();
    }
    int excl = scanv[t] - v;
    int node = (b << 9) + t;
    if (node < N_NODES) cnt[node] = v;
    __syncthreads();
    hist[t] = excl;
    __syncthreads();
    for (int i = t; i < ecount; i += 512) {
        int2 de = sbk[ibase + i];
        int ld = de.x & 511;
        int r = atomicAdd(&ctr[ld], 1);
        stage[hist[ld] + r] = de;
    }
    __syncthreads();
    for (int k = t; k < ecount; k += 512) {
        sds[obase + k] = stage[k];
    }
}

// conv1 fused with aggregation (unchanged)
__global__ __launch_bounds__(256) void conv1_mfma_kernel(
    const float* __restrict__ h, const int2* __restrict__ sds,
    const float* __restrict__ w1, const float* __restrict__ b1,
    const float* __restrict__ w2, const float* __restrict__ b2,
    const float* __restrict__ w3, const float* __restrict__ b3,
    float* __restrict__ sum1)
{
    __shared__ unsigned a2lds[4][64 * 17];
    int tid = threadIdx.x;
    int wave = tid >> 6, lane = tid & 63;
    int kg = lane >> 4, fr = lane & 15;
    unsigned* lds = &a2lds[wave][0];
    const float4* h4 = reinterpret_cast<const float4*>(h);

    float al[4][8], be[4][8], b1v[8];
    #pragma unroll
    for (int i = 0; i < 8; i++) {
        int k = kg * 8 + i;
        #pragma unroll
        for (int c = 0; c < 4; c++) {
            float wa = w1[c * 32 + k];
            float wb = w1[(4 + c) * 32 + k];
            al[c][i] = wa - wb;
            be[c][i] = wb;
        }
        b1v[i] = b1[k];
    }
    short8 bhi0, blo0, bhi1, blo1;
    #pragma unroll
    for (int i = 0; i < 8; i++) {
        int k = kg * 8 + i;
        float w0 = w2[k * 32 + fr];
        float w1c = w2[k * 32 + fr + 16];
        unsigned short h0 = bf16_rne(w0);
        bhi0[i] = (short)h0; blo0[i] = (short)bf16_rne(w0 - bf16_f32(h0));
        unsigned short h1 = bf16_rne(w1c);
        bhi1[i] = (short)h1; blo1[i] = (short)bf16_rne(w1c - bf16_f32(h1));
    }
    float b2v0 = b2[fr], b2v1 = b2[fr + 16];

    int g = blockIdx.x * 4 + wave;
    if (g >= NGROUPS) return;

    int base = g * 64;
    int2 p0 = sds[base + fr], p1 = sds[base + 16 + fr];
    int2 p2 = sds[base + 32 + fr], p3 = sds[base + 48 + fr];
    float4 xi0 = h4[p0.x], xj0 = h4[p0.y];
    float4 xi1 = h4[p1.x], xj1 = h4[p1.y];
    float4 xi2 = h4[p2.x], xj2 = h4[p2.y];
    float4 xi3 = h4[p3.x], xj3 = h4[p3.y];

    while (true) {
        int gn = g + GSTRIDE;
        bool hn = gn < NGROUPS;
        int basen = gn * 64;
        int2 q0, q1, q2, q3;
        if (hn) {
            q0 = sds[basen + fr];      q1 = sds[basen + 16 + fr];
            q2 = sds[basen + 32 + fr]; q3 = sds[basen + 48 + fr];
        }

        #pragma unroll
        for (int t = 0; t < 4; t++) {
            float4 xi = t == 0 ? xi0 : t == 1 ? xi1 : t == 2 ? xi2 : xi3;
            float4 xj = t == 0 ? xj0 : t == 1 ? xj1 : t == 2 ? xj2 : xj3;
            float a[8];
            #pragma unroll
            for (int i = 0; i < 8; i++) {
                float pre = b1v[i];
                pre = fmaf(al[0][i], xi.x, pre);
                pre = fmaf(al[1][i], xi.y, pre);
                pre = fmaf(al[2][i], xi.z, pre);
                pre = fmaf(al[3][i], xi.w, pre);
                pre = fmaf(be[0][i], xj.x, pre);
                pre = fmaf(be[1][i], xj.y, pre);
                pre = fmaf(be[2][i], xj.z, pre);
                pre = fmaf(be[3][i], xj.w, pre);
                a[i] = fmaxf(pre, 0.f);
            }
            PackU pu;
            #pragma unroll
            for (int j = 0; j < 4; j++) pu.u[j] = cvtpk_bf16(a[2*j], a[2*j+1]);
            short8 ahi = pu.s;

            f32x4 acc0 = {0.f, 0.f, 0.f, 0.f}, acc1 = {0.f, 0.f, 0.f, 0.f};
            acc0 = __builtin_amdgcn_mfma_f32_16x16x32_bf16(ahi, blo0, acc0, 0, 0, 0);
            acc0 = __builtin_amdgcn_mfma_f32_16x16x32_bf16(ahi, bhi0, acc0, 0, 0, 0);
            acc1 = __builtin_amdgcn_mfma_f32_16x16x32_bf16(ahi, blo1, acc1, 0, 0, 0);
            acc1 = __builtin_amdgcn_mfma_f32_16x16x32_bf16(ahi, bhi1, acc1, 0, 0, 0);
            #pragma unroll
            for (int r = 0; r < 4; r++) {
                int er = t * 16 + kg * 4 + r;
                float a20 = fmaxf(acc0[r] + b2v0, 0.f);
                float a21 = fmaxf(acc1[r] + b2v1, 0.f);
                lds[er * 17 + fr] = cvtpk_bf16(a20, a21);
            }
        }

        if (hn) {
            xi0 = h4[q0.x]; xj0 = h4[q0.y];
            xi1 = h4[q1.x]; xj1 = h4[q1.y];
            xi2 = h4[q2.x]; xj2 = h4[q2.y];
            xi3 = h4[q3.x]; xj3 = h4[q3.y];
        }

        asm volatile("s_waitcnt lgkmcnt(0)" ::: "memory");

        float m0 = b3[0], m1 = b3[1];
        #pragma unroll
        for (int j = 0; j < 16; j++) {
            unsigned u = lds[lane * 17 + j];
            float flo = __uint_as_float(u << 16);
            float fhi = __uint_as_float(u & 0xffff0000u);
            m0 = fmaf(flo, w3[2 * j],        m0);
            m1 = fmaf(flo, w3[2 * j + 1],    m1);
            m0 = fmaf(fhi, w3[2 * (j + 16)],     m0);
            m1 = fmaf(fhi, w3[2 * (j + 16) + 1], m1);
        }
        m0 = fmaxf(m0, 0.f); m1 = fmaxf(m1, 0.f);

        int d = kg == 0 ? p0.x : kg == 1 ? p1.x : kg == 2 ? p2.x : p3.x;
        int dprev = __shfl_up(d, 1);
        int dnext = __shfl_down(d, 1);
        bool head = (lane == 0) || (d != dprev);
        bool tail = (lane == 63) || (d != dnext);
        unsigned long long hb = __ballot(head);
        unsigned long long msk = (lane == 63) ? ~0ull : ((1ull << (lane + 1)) - 1ull);
        int seg0 = 63 - __clzll(hb & msk);
        #pragma unroll
        for (int st = 1; st < 64; st <<= 1) {
            float u0 = __shfl_up(m0, st);
            float u1 = __shfl_up(m1, st);
            if (lane - st >= seg0) { m0 += u0; m1 += u1; }
        }
        if (tail) {
            atomicAdd(&sum1[2 * d],     m0);
            atomicAdd(&sum1[2 * d + 1], m1);
        }

        if (!hn) break;
        p0 = q0; p1 = q1; p2 = q2; p3 = q3; g = gn;
    }
}

__global__ void div1_kernel(const float* __restrict__ sum1, const int* __restrict__ cnt,
                            float* __restrict__ h2) {
    int i = blockIdx.x * 256 + threadIdx.x;
    if (i >= N_NODES) return;
    float c = fmaxf((float)cnt[i], 1.f);
    float2 s = reinterpret_cast<const float2*>(sum1)[i];
    reinterpret_cast<float2*>(h2)[i] = make_float2(s.x / c, s.y / c);
}

// conv2 fused with aggregation (unchanged)
__global__ __launch_bounds__(256) void conv2_mfma_kernel(
    const float* __restrict__ h2, const int2* __restrict__ sds,
    const float* __restrict__ w1, const float* __restrict__ b1,
    const float* __restrict__ w2, const float* __restrict__ b2,
    const float* __restrict__ w3, const float* __restrict__ b3,
    float* __restrict__ sum2)
{
    __shared__ unsigned a2lds[4][64 * 17];
    int tid = threadIdx.x;
    int wave = tid >> 6, lane = tid & 63;
    int kg = lane >> 4, fr = lane & 15;
    unsigned* lds = &a2lds[wave][0];
    const float2* h2v = reinterpret_cast<const float2*>(h2);

    float al0[8], al1[8], be0[8], be1[8], b1v[8];
    #pragma unroll
    for (int i = 0; i < 8; i++) {
        int k = kg * 8 + i;
        float c0a = w1[k], c1a = w1[32 + k];
        float c0b = w1[64 + k], c1b = w1[96 + k];
        al0[i] = c0a - c0b; al1[i] = c1a - c1b;
        be0[i] = c0b; be1[i] = c1b;
        b1v[i] = b1[k];
    }
    short8 bhi0, blo0, bhi1, blo1;
    #pragma unroll
    for (int i = 0; i < 8; i++) {
        int k = kg * 8 + i;
        float w0 = w2[k * 32 + fr];
        float w1c = w2[k * 32 + fr + 16];
        unsigned short h0 = bf16_rne(w0);
        bhi0[i] = (short)h0; blo0[i] = (short)bf16_rne(w0 - bf16_f32(h0));
        unsigned short h1 = bf16_rne(w1c);
        bhi1[i] = (short)h1; blo1[i] = (short)bf16_rne(w1c - bf16_f32(h1));
    }
    float b2v0 = b2[fr], b2v1 = b2[fr + 16];

    int g = blockIdx.x * 4 + wave;
    if (g >= NGROUPS) return;
    int base = g * 64;
    int2 p0 = sds[base + fr], p1 = sds[base + 16 + fr];
    int2 p2 = sds[base + 32 + fr], p3 = sds[base + 48 + fr];
    float2 yd0 = h2v[p0.x], ys0 = h2v[p0.y];
    float2 yd1 = h2v[p1.x], ys1 = h2v[p1.y];
    float2 yd2 = h2v[p2.x], ys2 = h2v[p2.y];
    float2 yd3 = h2v[p3.x], ys3 = h2v[p3.y];

    while (true) {
        int gn = g + GSTRIDE;
        bool hn = gn < NGROUPS;
        int basen = gn * 64;
        int2 q0, q1, q2, q3;
        if (hn) {
            q0 = sds[basen + fr];      q1 = sds[basen + 16 + fr];
            q2 = sds[basen + 32 + fr]; q3 = sds[basen + 48 + fr];
        }

        #pragma unroll
        for (int t = 0; t < 4; t++) {
            float2 yd = t == 0 ? yd0 : t == 1 ? yd1 : t == 2 ? yd2 : yd3;
            float2 ys = t == 0 ? ys0 : t == 1 ? ys1 : t == 2 ? ys2 : ys3;
            float a[8];
            #pragma unroll
            for (int i = 0; i < 8; i++) {
                float pre = b1v[i];
                pre = fmaf(al0[i], yd.x, pre);
                pre = fmaf(al1[i], yd.y, pre);
                pre = fmaf(be0[i], ys.x, pre);
                pre = fmaf(be1[i], ys.y, pre);
                a[i] = fmaxf(pre, 0.f);
            }
            PackU pu;
            #pragma unroll
            for (int j = 0; j < 4; j++) pu.u[j] = cvtpk_bf16(a[2*j], a[2*j+1]);
            short8 ahi = pu.s;

            f32x4 acc0 = {0.f, 0.f, 0.f, 0.f}, acc1 = {0.f, 0.f, 0.f, 0.f};
            acc0 = __builtin_amdgcn_mfma_f32_16x16x32_bf16(ahi, blo0, acc0, 0, 0, 0);
            acc0 = __builtin_amdgcn_mfma_f32_16x16x32_bf16(ahi, bhi0, acc0, 0, 0, 0);
            acc1 = __builtin_amdgcn_mfma_f32_16x16x32_bf16(ahi, blo1, acc1, 0, 0, 0);
            acc1 = __builtin_amdgcn_mfma_f32_16x16x32_bf16(ahi, bhi1, acc1, 0, 0, 0);
            #pragma unroll
            for (int r = 0; r < 4; r++) {
                int er = t * 16 + kg * 4 + r;
                float a20 = fmaxf(acc0[r] + b2v0, 0.f);
                float a21 = fmaxf(acc1[r] + b2v1, 0.f);
                lds[er * 17 + fr] = cvtpk_bf16(a20, a21);
            }
        }

        if (hn) {
            yd0 = h2v[q0.x]; ys0 = h2v[q0.y];
            yd1 = h2v[q1.x]; ys1 = h2v[q1.y];
            yd2 = h2v[q2.x]; ys2 = h2v[q2.y];
            yd3 = h2v[q3.x]; ys3 = h2v[q3.y];
        }

        asm volatile("s_waitcnt lgkmcnt(0)" ::: "memory");

        float o0 = b3[0], o1 = b3[1], o2 = b3[2], o3 = b3[3];
        #pragma unroll
        for (int j = 0; j < 16; j++) {
            unsigned u = lds[lane * 17 + j];
            float flo = __uint_as_float(u << 16);
            float fhi = __uint_as_float(u & 0xffff0000u);
            o0 = fmaf(flo, w3[4 * j],     o0);
            o1 = fmaf(flo, w3[4 * j + 1], o1);
            o2 = fmaf(flo, w3[4 * j + 2], o2);
            o3 = fmaf(flo, w3[4 * j + 3], o3);
            o0 = fmaf(fhi, w3[4 * (j + 16)],     o0);
            o1 = fmaf(fhi, w3[4 * (j + 16) + 1], o1);
            o2 = fmaf(fhi, w3[4 * (j + 16) + 2], o2);
            o3 = fmaf(fhi, w3[4 * (j + 16) + 3], o3);
        }

        int d = kg == 0 ? p0.x : kg == 1 ? p1.x : kg == 2 ? p2.x : p3.x;
        int dprev = __shfl_up(d, 1);
        int dnext = __shfl_down(d, 1);
        bool head = (lane == 0) || (d != dprev);
        bool tail = (lane == 63) || (d != dnext);
        unsigned long long hb = __ballot(head);
        unsigned long long msk = (lane == 63) ? ~0ull : ((1ull << (lane + 1)) - 1ull);
        int seg0 = 63 - __clzll(hb & msk);
        #pragma unroll
        for (int st = 1; st < 64; st <<= 1) {
            float u0 = __shfl_up(o0, st);
            float u1 = __shfl_up(o1, st);
            float u2 = __shfl_up(o2, st);
            float u3 = __shfl_up(o3, st);
            if (lane - st >= seg0) { o0 += u0; o1 += u1; o2 += u2; o3 += u3; }
        }
        if (tail) {
            atomicAdd(&sum2[4 * d],     o0);
            atomicAdd(&sum2[4 * d + 1], o1);
            atomicAdd(&sum2[4 * d + 2], o2);
            atomicAdd(&sum2[4 * d + 3], o3);
        }

        if (!hn) break;
        p0 = q0; p1 = q1; p2 = q2; p3 = q3; g = gn;
    }
}

__global__ void div2_kernel(const float* __restrict__ sum2, const int* __restrict__ cnt,
                            float* __restrict__ out) {
    int i = blockIdx.x * 256 + threadIdx.x;
    if (i >= N_NODES) return;
    float c = fmaxf((float)cnt[i], 1.f);
    float4 s = reinterpret_cast<const float4*>(sum2)[i];
    reinterpret_cast<float4*>(out)[i] = make_float4(s.x/c, s.y/c, s.z/c, s.w/c);
}

extern "C" void kernel_launch(void* const* d_in, const int* in_sizes, int n_in,
                              void* d_out, int out_size, void* d_ws, size_t ws_size,
                              hipStream_t stream) {
    const float* x        = (const float*)d_in[0];
    const int*   ei       = (const int*)  d_in[1];
    const float* bn_gamma = (const float*)d_in[2];
    const float* bn_beta  = (const float*)d_in[3];
    const float* enc_w1   = (const float*)d_in[4];
    const float* enc_b1   = (const float*)d_in[5];
    const float* enc_w2   = (const float*)d_in[6];
    const float* enc_b2   = (const float*)d_in[7];
    const float* enc_w3   = (const float*)d_in[8];
    const float* enc_b3   = (const float*)d_in[9];
    const float* dec_w1   = (const float*)d_in[10];
    const float* dec_b1   = (const float*)d_in[11];
    const float* dec_w2   = (const float*)d_in[12];
    const float* dec_b2   = (const float*)d_in[13];
    const float* dec_w3   = (const float*)d_in[14];
    const float* dec_b3   = (const float*)d_in[15];

    float* wsf    = (float*)d_ws;
    int*   wsi    = (int*)d_ws;
    float* stats  = wsf + O_STATS;
    int*   bktctr = wsi + O_BKTCTR;
    float* sum1   = wsf + O_SUM1;
    float* sum2   = wsf + O_SUM2;
    int*   bktbase= wsi + O_BKTBASE;
    int*   cnt    = wsi + O_CNT;
    int2*  sbk    = (int2*)(wsi + O_SBK);
    int2*  sds    = (int2*)(wsi + O_SDS);
    float* h      = wsf + O_H;
    float* h2     = wsf + O_H2;
    float* out    = (float*)d_out;

    hipMemsetAsync(d_ws, 0, (size_t)ZERO_WORDS * sizeof(float), stream);

    const int nodeBlocks = (N_NODES + 255) / 256;

    bn_stats_kernel<<<STATS_BLOCKS, 256, 0, stream>>>(x, stats);
    bn_apply_kernel<<<nodeBlocks, 256, 0, stream>>>(x, stats, bn_gamma, bn_beta, h);
    scatter_kernel<<<SCAT_BLOCKS, 256, 0, stream>>>(ei, bktctr, sbk);
    ctr_scan_kernel<<<1, 256, 0, stream>>>(bktctr, bktbase);
    fine_rank_kernel<<<NBKT, 512, 0, stream>>>(sbk, bktctr, bktbase, sds, cnt);
    conv1_mfma_kernel<<<CONV_BLOCKS, 256, 0, stream>>>(h, sds,
                                                       enc_w1, enc_b1, enc_w2, enc_b2,
                                                       enc_w3, enc_b3, sum1);
    div1_kernel<<<nodeBlocks, 256, 0, stream>>>(sum1, cnt, h2);
    conv2_mfma_kernel<<<CONV_BLOCKS, 256, 0, stream>>>(h2, sds,
                                                       dec_w1, dec_b1, dec_w2, dec_b2,
                                                       dec_w3, dec_b3, sum2);
    div2_kernel<<<nodeBlocks, 256, 0, stream>>>(sum2, cnt, out);
}